// Round 2
// baseline (1278.743 us; speedup 1.0000x reference)
//
#include <hip/hip_runtime.h>
#include <hip/hip_bf16.h>
#include <stdint.h>

#define DEVINL __device__ __forceinline__

// ---------------- problem dims ----------------
// B=2, C=64, H=W=128, n=16384, HEADS=8, DH=32
// All device buffers are float32 (reference dtype).

// ---------------- workspace layout (float offsets) ----------------
static const size_t O_BUF384 = 0;                  // [2][384][16384] qkv conv out
static const size_t O_WCAT   = 12582912;           // [384][64][9]
static const size_t O_WFOLD  = O_WCAT  + 221184;   // [64][64][9]
static const size_t O_G      = O_WFOLD + 36864;    // [2][384][384]
static const size_t O_T1     = O_G     + 294912;   // [2][256][128]
static const size_t O_UL     = O_T1    + 65536;    // [2][256][64]
static const size_t O_UK     = O_UL    + 32768;    // [2][512][128]
static const size_t O_T1H    = O_UK    + 131072;   // [2][768][128]
static const size_t O_UH     = O_T1H   + 196608;   // [2][768][192]
static const size_t O_NORMS  = O_UH    + 294912;   // [2][1536]
static const size_t O_ATTL   = O_NORMS + 3072;     // [2][8][32][64]
static const size_t O_ATTH   = O_ATTL  + 32768;    // [2][8][96][64]
static const size_t O_WEFFL  = O_ATTH  + 98304;    // [2][256][128]
static const size_t O_WEFFH  = O_WEFFL + 65536;    // [2][768][128]
static const size_t O_ACAT   = O_WEFFH + 196608;   // [2][256][128]
static const size_t O_TSUM   = O_ACAT  + 65536;    // [2][64][9]
static const size_t O_ATTB   = O_TSUM  + 1152;     // [2][64]
static const size_t O_HCAT   = O_ATTB  + 128;      // [2][256*16384] ; ALSO aliases GPART
static const size_t O_GPART  = O_HCAT;             // [16][2][384][384] = 4,718,592 < 8,388,608
static const size_t O_MID    = O_HCAT  + 8388608;  // [2][64][16384]
static const size_t O_HOUT   = O_MID   + 2097152;  // [2][64][16384]
static const size_t O_OUT1   = O_HOUT  + 2097152;  // [2][64][16384]
static const size_t WS_FLOATS= O_OUT1  + 2097152;  // ~116 MB (ran in round 1, so ws_size is sufficient)

// ================= weight prep =================
__global__ void k_wcat(const float* __restrict__ wd, const float* __restrict__ wm,
                       const float* __restrict__ wu, float* __restrict__ dst) {
  int i = blockIdx.x * 256 + threadIdx.x;
  if (i >= 384 * 64 * 9) return;
  int oc = i / 576, r = i % 576;
  float v;
  if (oc < 64)       v = wd[oc * 576 + r];
  else if (oc < 192) v = wm[(oc - 64) * 576 + r];
  else               v = wu[(oc - 192) * 576 + r];
  dst[i] = v;
}

// Wfold[o][i][tap] = sum_m c31_w3[o][m] * c31_w2[m][i][tap]
__global__ void k_wfold(const float* __restrict__ w3, const float* __restrict__ w2,
                        float* __restrict__ wf) {
  int i = blockIdx.x * 256 + threadIdx.x;
  if (i >= 36864) return;
  int o = i / 576, r = i % 576, ic = r / 9, tap = r % 9;
  float s = 0.f;
  for (int m = 0; m < 64; m++)
    s = fmaf(w3[o * 64 + m], w2[(m * 64 + ic) * 9 + tap], s);
  wf[i] = s;
}

// ================= direct 3x3 conv (NCHW 128x128) =================
// tile: 16 rows x 64 cols, 256 thr (tx=t&15 -> 4 cols, ty=t>>4 -> row), OCB outs/thread
// EPI: 0 none, 1 prelu(scalar), 2 final (acc + hout*att + x)
template<int REFLECT, int OCB, int EPI>
__global__ __launch_bounds__(256) void k_conv3x3(
    const float* __restrict__ in, const float* __restrict__ w, float* __restrict__ out,
    int Cin, int Cout,
    const float* __restrict__ prelu_a,
    const float* __restrict__ hout, const float* __restrict__ attb,
    const float* __restrict__ xres)
{
  __shared__ float sIn[8 * 18 * 66];
  __shared__ float sW[8 * 9 * OCB];
  const int t = threadIdx.x;
  const int tx = t & 15, ty = t >> 4;
  const int col0 = blockIdx.x * 64, row0 = blockIdx.y * 16;
  const int ocg_cnt = Cout / OCB;
  const int ocg = blockIdx.z % ocg_cnt, b = blockIdx.z / ocg_cnt;

  float acc[OCB][4];
#pragma unroll
  for (int o = 0; o < OCB; o++)
#pragma unroll
    for (int i = 0; i < 4; i++) acc[o][i] = 0.f;

  for (int icb = 0; icb < Cin; icb += 8) {
    for (int idx = t; idx < 8 * 9 * OCB; idx += 256) {
      int ic = idx / (9 * OCB), r = idx % (9 * OCB), tap = r / OCB, o = r % OCB;
      sW[idx] = w[((size_t)(ocg * OCB + o) * Cin + icb + ic) * 9 + tap];
    }
    for (int idx = t; idx < 8 * 18 * 66; idx += 256) {
      int ic = idx / (18 * 66), r2 = idx % (18 * 66), iy = r2 / 66, ix = r2 % 66;
      int gy = row0 + iy - 1, gx = col0 + ix - 1;
      float v;
      if (REFLECT) {
        gy = gy < 0 ? 1 : (gy > 127 ? 126 : gy);
        gx = gx < 0 ? 1 : (gx > 127 ? 126 : gx);
        v = in[(((size_t)(b * Cin + icb + ic)) << 14) + (gy << 7) + gx];
      } else {
        bool ok = (gy >= 0) & (gy < 128) & (gx >= 0) & (gx < 128);
        v = ok ? in[(((size_t)(b * Cin + icb + ic)) << 14) + (gy << 7) + gx] : 0.f;
      }
      sIn[idx] = v;
    }
    __syncthreads();
#pragma unroll
    for (int ic = 0; ic < 8; ic++) {
#pragma unroll
      for (int ky = 0; ky < 3; ky++) {
        const float* rp = &sIn[(ic * 18 + ty + ky) * 66 + tx * 4];
        float inv[6];
#pragma unroll
        for (int j = 0; j < 6; j++) inv[j] = rp[j];
#pragma unroll
        for (int kx = 0; kx < 3; kx++) {
          const float* wp = &sW[(ic * 9 + ky * 3 + kx) * OCB];
#pragma unroll
          for (int o = 0; o < OCB; o++) {
            float wv = wp[o];
#pragma unroll
            for (int i = 0; i < 4; i++) acc[o][i] = fmaf(wv, inv[i + kx], acc[o][i]);
          }
        }
      }
    }
    __syncthreads();
  }

  const int y = row0 + ty, x0 = col0 + tx * 4;
  float aP = 0.f;
  if (EPI == 1) aP = prelu_a[0];
#pragma unroll
  for (int o = 0; o < OCB; o++) {
    int oc = ocg * OCB + o;
    size_t obase = (((size_t)(b * Cout + oc)) << 14) + (y << 7) + x0;
    float v[4];
#pragma unroll
    for (int i = 0; i < 4; i++) v[i] = acc[o][i];
    if (EPI == 1) {
#pragma unroll
      for (int i = 0; i < 4; i++) v[i] = v[i] > 0.f ? v[i] : aP * v[i];
    }
    if (EPI == 2) {
      float av = attb[b * 64 + oc];
#pragma unroll
      for (int i = 0; i < 4; i++)
        v[i] += hout[obase + i] * av + xres[obase + i];
    }
    float4 f4 = make_float4(v[0], v[1], v[2], v[3]);
    *(float4*)&out[obase] = f4;
  }
}

// ================= Gram: G[b] = Z Z^T, Z=[384,16384] =================
__global__ __launch_bounds__(256) void k_gram(const float* __restrict__ Z,
                                              float* __restrict__ Gp) {
  // grid: x = 21 (ti<=tj pairs), y = 16 k-chunks, z = batch
  int rem = blockIdx.x, ti = 0;
  while (rem >= 6 - ti) { rem -= 6 - ti; ti++; }
  const int tj = ti + rem;
  const int t = threadIdx.x, tx = t & 15, ty = t >> 4;
  const int b = blockIdx.z, k0 = blockIdx.y * 1024;

  __shared__ float sA[32 * 68];
  __shared__ float sB[32 * 68];
  float acc[4][4] = {};

  const int r = t >> 2;            // 0..63 row
  const int kp = (t & 3) * 8;      // 0,8,16,24
  const float* Za = Z + (((size_t)(b * 384 + ti * 64 + r)) << 14) + k0;
  const float* Zb = Z + (((size_t)(b * 384 + tj * 64 + r)) << 14) + k0;

  for (int kk = 0; kk < 1024; kk += 32) {
#pragma unroll
    for (int u = 0; u < 8; u++) {
      sA[(kp + u) * 68 + r] = Za[kk + kp + u];
      sB[(kp + u) * 68 + r] = Zb[kk + kp + u];
    }
    __syncthreads();
#pragma unroll
    for (int k = 0; k < 32; k++) {
      float4 a4 = *(const float4*)&sA[k * 68 + ty * 4];
      float4 b4 = *(const float4*)&sB[k * 68 + tx * 4];
      float av[4] = {a4.x, a4.y, a4.z, a4.w};
      float bv[4] = {b4.x, b4.y, b4.z, b4.w};
#pragma unroll
      for (int i = 0; i < 4; i++)
#pragma unroll
        for (int j = 0; j < 4; j++) acc[i][j] = fmaf(av[i], bv[j], acc[i][j]);
    }
    __syncthreads();
  }

  float* gp = Gp + ((size_t)(blockIdx.y * 2 + b)) * 147456;
#pragma unroll
  for (int i = 0; i < 4; i++)
#pragma unroll
    for (int j = 0; j < 4; j++)
      gp[(size_t)(ti * 64 + ty * 4 + i) * 384 + (tj * 64 + tx * 4 + j)] = acc[i][j];
  if (ti != tj) {
#pragma unroll
    for (int i = 0; i < 4; i++)
#pragma unroll
      for (int j = 0; j < 4; j++)
        gp[(size_t)(tj * 64 + tx * 4 + j) * 384 + (ti * 64 + ty * 4 + i)] = acc[i][j];
  }
}

__global__ void k_gred(const float* __restrict__ Gp, float* __restrict__ G) {
  int i = blockIdx.x * 256 + threadIdx.x;
  if (i >= 294912) return;
  int b = i / 147456, e = i % 147456;
  float s = 0.f;
#pragma unroll
  for (int c = 0; c < 16; c++) s += Gp[(size_t)(c * 2 + b) * 147456 + e];
  G[i] = s;
}

// ================= small GEMM: C = A[M,K] * B[K,N] =================
__global__ __launch_bounds__(256) void k_sgemm(
    const float* __restrict__ A, const float* __restrict__ B, float* __restrict__ C,
    int K, int lda, int ldb, int ldc, long sA_, long sB_, long sC_)
{
  __shared__ float sa[16][17];
  __shared__ float sb[16][17];
  const int tx = threadIdx.x & 15, ty = threadIdx.x >> 4;
  const float* Ap = A + (size_t)blockIdx.z * sA_;
  const float* Bp = B + (size_t)blockIdx.z * sB_;
  const int m = blockIdx.y * 16 + ty, n = blockIdx.x * 16 + tx;
  float acc = 0.f;
  for (int k0 = 0; k0 < K; k0 += 16) {
    sa[ty][tx] = Ap[(size_t)m * lda + k0 + tx];
    sb[ty][tx] = Bp[(size_t)(k0 + ty) * ldb + n];
    __syncthreads();
#pragma unroll
    for (int kk = 0; kk < 16; kk++) acc = fmaf(sa[ty][kk], sb[kk][tx], acc);
    __syncthreads();
  }
  C[(size_t)blockIdx.z * sC_ + (size_t)m * ldc + n] = acc;
}

// ================= norms =================
__global__ void k_norms(const float* __restrict__ UL, const float* __restrict__ UK,
                        const float* __restrict__ UH,
                        const float* __restrict__ wql, const float* __restrict__ wkm,
                        const float* __restrict__ wqh, float* __restrict__ norms) {
  int id = blockIdx.x * 256 + threadIdx.x;
  if (id >= 3072) return;
  int b = id / 1536, r = id % 1536;
  const float* u; const float* wv; int K;
  if (r < 256)      { K = 64;  u = UL + (size_t)(b * 256 + r) * 64;          wv = wql + (size_t)r * 64; }
  else if (r < 768) { int e = r - 256; K = 128; u = UK + (size_t)(b * 512 + e) * 128; wv = wkm + (size_t)e * 128; }
  else              { int d = r - 768; K = 192; u = UH + (size_t)(b * 768 + d) * 192; wv = wqh + (size_t)d * 192; }
  float s = 0.f;
  for (int k = 0; k < K; k++) s = fmaf(u[k], wv[k], s);
  norms[b * 1536 + r] = fmaxf(sqrtf(fmaxf(s, 0.f)), 1e-12f);
}

// ================= attention logits + softmax =================
__global__ __launch_bounds__(256) void k_attn(
    const float* __restrict__ T1, const float* __restrict__ T1H,
    const float* __restrict__ wkm, const float* __restrict__ norms,
    const float* __restrict__ rescale,
    float* __restrict__ attL, float* __restrict__ attH)
{
  // grid: x=h(8), y=chunk(4: 0->L rows0..31, 1..3 -> H rows (c-1)*32..), z=b
  const int h = blockIdx.x, cy = blockIdx.y, b = blockIdx.z;
  const int t = threadIdx.x;
  __shared__ float sK[64 * 129];
  __shared__ float sQ[32 * 129];
  __shared__ float sNk[64];
  const int isL = (cy == 0);
  const int rbase = isL ? 0 : (cy - 1) * 32;
  const float* TQ = isL ? (T1 + (size_t)(b * 256 + h * 32) * 128)
                        : (T1H + (size_t)(b * 768 + h * 96 + rbase) * 128);
  for (int idx = t; idx < 8192; idx += 256) {
    int e = idx >> 7, k = idx & 127;
    sK[e * 129 + k] = wkm[(size_t)(h * 64 + e) * 128 + k];
  }
  for (int idx = t; idx < 4096; idx += 256) {
    int r = idx >> 7, k = idx & 127;
    sQ[r * 129 + k] = TQ[(size_t)r * 128 + k];
  }
  if (t < 64) sNk[t] = norms[b * 1536 + 256 + h * 64 + t];
  __syncthreads();

  const int w = t >> 6, lane = t & 63;
  const float rs = rescale[h];
  for (int r = w; r < 32; r += 4) {
    float s = 0.f;
    for (int k = 0; k < 128; k++) s = fmaf(sQ[r * 129 + k], sK[lane * 129 + k], s);
    float nq = norms[b * 1536 + (isL ? (h * 32 + r) : (768 + h * 96 + rbase + r))];
    float logit = s / (nq * sNk[lane]) * rs;
    float m = logit;
#pragma unroll
    for (int o = 32; o; o >>= 1) m = fmaxf(m, __shfl_xor(m, o));
    float p = __expf(logit - m);
    float den = p;
#pragma unroll
    for (int o = 32; o; o >>= 1) den += __shfl_xor(den, o);
    float av = p / den;
    if (isL) attL[((size_t)(b * 8 + h) * 32 + r) * 64 + lane] = av;
    else     attH[((size_t)(b * 8 + h) * 96 + rbase + r) * 64 + lane] = av;
  }
}

// ================= Weff = attn @ wv (per head) =================
__global__ __launch_bounds__(256) void k_weff(
    const float* __restrict__ attL, const float* __restrict__ attH,
    const float* __restrict__ wvm,
    float* __restrict__ WeL, float* __restrict__ WeH)
{
  // grid: x=h, y=branch(0=L,1=H), z=b
  const int h = blockIdx.x, br = blockIdx.y, b = blockIdx.z;
  const int M = br ? 96 : 32;
  __shared__ float sAt[96 * 64];
  __shared__ float sV[64 * 132];
  const int t = threadIdx.x;
  const float* asrc = br ? attH + (size_t)(b * 8 + h) * 96 * 64
                         : attL + (size_t)(b * 8 + h) * 32 * 64;
  for (int idx = t; idx < M * 64; idx += 256) sAt[idx] = asrc[idx];
  for (int idx = t; idx < 8192; idx += 256) {
    int e = idx >> 7, k = idx & 127;
    sV[e * 132 + k] = wvm[(size_t)(h * 64 + e) * 128 + k];
  }
  __syncthreads();
  const int jg = t & 31, rw = t >> 5;
  float* dst = br ? WeH + (size_t)(b * 768 + h * 96) * 128
                  : WeL + (size_t)(b * 256 + h * 32) * 128;
  for (int r = rw; r < M; r += 8) {
    float4 acc = make_float4(0.f, 0.f, 0.f, 0.f);
    for (int e = 0; e < 64; e++) {
      float a = sAt[r * 64 + e];
      float4 v4 = *(const float4*)&sV[e * 132 + jg * 4];
      acc.x = fmaf(a, v4.x, acc.x);
      acc.y = fmaf(a, v4.y, acc.y);
      acc.z = fmaf(a, v4.z, acc.z);
      acc.w = fmaf(a, v4.w, acc.w);
    }
    *(float4*)&dst[(size_t)r * 128 + jg * 4] = acc;
  }
}

// ================= per-pixel map: Hcat = xM @ Acat^T + bias =================
__global__ __launch_bounds__(256) void k_pixmap(
    const float* __restrict__ Z, const float* __restrict__ Acat,
    const float* __restrict__ bl, const float* __restrict__ bh,
    float* __restrict__ hcat)
{
  // grid: x = 256 pixel tiles (64 px), y = 4 oc tiles (64 oc), z = b
  const int t = threadIdx.x, tx = t & 15, ty = t >> 4;
  const int p0 = blockIdx.x * 64, oc0 = blockIdx.y * 64, b = blockIdx.z;
  __shared__ float sX[32 * 68];  // [k][px]
  __shared__ float sA[32 * 68];  // [k][oc]
  float acc[4][4] = {};

  for (int k0 = 0; k0 < 128; k0 += 32) {
    {
      int kk = t >> 3, pp = (t & 7) * 8;
      const float* src = Z + (((size_t)(b * 384 + 64 + k0 + kk)) << 14) + p0 + pp;
#pragma unroll
      for (int u = 0; u < 8; u++) sX[kk * 68 + pp + u] = src[u];
    }
    {
      int o = t >> 2, kq = (t & 3) * 8;
      const float* src = Acat + (size_t)(b * 256 + oc0 + o) * 128 + k0 + kq;
#pragma unroll
      for (int u = 0; u < 8; u++) sA[(kq + u) * 68 + o] = src[u];
    }
    __syncthreads();
#pragma unroll
    for (int k = 0; k < 32; k++) {
      float4 xv = *(const float4*)&sX[k * 68 + tx * 4];
      float4 av = *(const float4*)&sA[k * 68 + ty * 4];
      float xa[4] = {xv.x, xv.y, xv.z, xv.w};
      float aa[4] = {av.x, av.y, av.z, av.w};
#pragma unroll
      for (int j = 0; j < 4; j++)
#pragma unroll
        for (int i = 0; i < 4; i++) acc[j][i] = fmaf(aa[j], xa[i], acc[j][i]);
    }
    __syncthreads();
  }

  size_t hbase = (size_t)b * 4194304;
#pragma unroll
  for (int j = 0; j < 4; j++) {
    int oc = oc0 + ty * 4 + j;
    float bias = (oc < 64) ? bl[oc] : bh[oc - 64];
#pragma unroll
    for (int i = 0; i < 4; i++) {
      int p = p0 + tx * 4 + i;
      float v = acc[j][i] + bias;
      size_t addr = (oc < 64) ? hbase + (size_t)p * 64 + oc
                              : hbase + 1048576 + (size_t)p * 192 + (oc - 64);
      hcat[addr] = v;
    }
  }
}

// ================= QCO: reflected 3x3 tap sums =================
__global__ __launch_bounds__(256) void k_tsum(const float* __restrict__ Z,
                                              float* __restrict__ Tsum) {
  const int c = blockIdx.x & 63, b = blockIdx.x >> 6;
  const float* src = Z + (((size_t)(b * 384 + c)) << 14);
  const int t = threadIdx.x;
  float s[9] = {};
  for (int p = t; p < 16384; p += 256) {
    int y = p >> 7, x = p & 127;
#pragma unroll
    for (int dy = 0; dy < 3; dy++) {
      int ry = y + dy - 1; ry = ry < 0 ? 1 : (ry > 127 ? 126 : ry);
#pragma unroll
      for (int dx = 0; dx < 3; dx++) {
        int rx = x + dx - 1; rx = rx < 0 ? 1 : (rx > 127 ? 126 : rx);
        s[dy * 3 + dx] += src[(ry << 7) + rx];
      }
    }
  }
  __shared__ float red[4][9];
#pragma unroll
  for (int q = 0; q < 9; q++)
#pragma unroll
    for (int o = 32; o; o >>= 1) s[q] += __shfl_xor(s[q], o);
  int w = t >> 6, lane = t & 63;
  if (lane == 0)
#pragma unroll
    for (int q = 0; q < 9; q++) red[w][q] = s[q];
  __syncthreads();
  if (t < 9) Tsum[blockIdx.x * 9 + t] = red[0][t] + red[1][t] + red[2][t] + red[3][t];
}

// ================= QCO tail (per batch, 64 threads) =================
__global__ __launch_bounds__(64) void k_qco(
    const float* __restrict__ Tsum, const float* __restrict__ w1,
    const float* __restrict__ scaw, const float* __restrict__ scab,
    const float* __restrict__ t1w, const float* __restrict__ t1b,
    const float* __restrict__ t2w, const float* __restrict__ t2b,
    float* __restrict__ attb)
{
  const int b = blockIdx.x, c = threadIdx.x;
  __shared__ float sm[64], sxq[64], scat[128], sh1[64];
  float acc = 0.f;
  for (int j = 0; j < 64; j++) {
#pragma unroll
    for (int tap = 0; tap < 9; tap++)
      acc = fmaf(w1[(c * 64 + j) * 9 + tap], Tsum[(b * 64 + j) * 9 + tap], acc);
  }
  sm[c] = acc * (1.f / 16384.f);
  __syncthreads();
  float xa = scab[c];
  for (int j = 0; j < 64; j++) xa = fmaf(scaw[c * 64 + j], sm[j], xa);
  sxq[c] = xa;
  __syncthreads();
  float mn = xa, mx = xa;
#pragma unroll
  for (int o = 32; o; o >>= 1) {
    mn = fminf(mn, __shfl_xor(mn, o));
    mx = fmaxf(mx, __shfl_xor(mx, o));
  }
  float inter = (mx - mn) * (1.f / 64.f);
  float ql = (2.f * c + 1.f) / 128.f * (mx - mn) + mn;
  float sta = 0.f;
  for (int j = 0; j < 64; j++) {
    float q = 1.f - fabsf(ql - sxq[j]);
    sta += (q > 1.f - inter) ? q : 0.f;
  }
  float tot = sta;
#pragma unroll
  for (int o = 32; o; o >>= 1) tot += __shfl_xor(tot, o);
  sta = sta / fmaxf(tot, 1e-30f);
  scat[c] = sta; scat[64 + c] = xa;
  __syncthreads();
  float h = t1b[c];
  for (int j = 0; j < 128; j++) h = fmaf(t1w[c * 128 + j], scat[j], h);
  h = fmaxf(h, 0.f);
  sh1[c] = h;
  __syncthreads();
  float o2 = t2b[c];
  for (int j = 0; j < 64; j++) o2 = fmaf(t2w[c * 64 + j], sh1[j], o2);
  attb[b * 64 + c] = fmaxf(o2, 0.f);
}

// ================= fused double-FF block (lane = channel) =================
DEVINL float bcastl(float x, int l) {
  return __int_as_float(__builtin_amdgcn_readlane(__float_as_int(x), l));
}
DEVINL float wsum64(float x) {
#pragma unroll
  for (int o = 32; o; o >>= 1) x += __shfl_xor(x, o);
  return x;
}
DEVINL float mm64(const float* Wm, int lane, float xin, float bias) {
  float acc = bias;
#pragma unroll
  for (int ig = 0; ig < 16; ig++) {
    const float4 w4 = *(const float4*)&Wm[lane * 68 + ig * 4];
    acc = fmaf(w4.x, bcastl(xin, ig * 4 + 0), acc);
    acc = fmaf(w4.y, bcastl(xin, ig * 4 + 1), acc);
    acc = fmaf(w4.z, bcastl(xin, ig * 4 + 2), acc);
    acc = fmaf(w4.w, bcastl(xin, ig * 4 + 3), acc);
  }
  return acc;
}

__global__ __launch_bounds__(256) void k_ff(const float* __restrict__ out1,
    const float* g1, const float* be1, const float* w11, const float* b11,
    const float* w12, const float* b12,
    const float* g2, const float* be2, const float* w21, const float* b21,
    const float* w22, const float* b22,
    float* __restrict__ outp)
{
  __shared__ float sW[4 * 64 * 68];
  const int t = threadIdx.x;
  for (int idx = t; idx < 4096; idx += 256) {
    int j = idx >> 6, i = idx & 63;
    sW[0 * 4352 + j * 68 + i] = w11[idx];
    sW[1 * 4352 + j * 68 + i] = w12[idx];
    sW[2 * 4352 + j * 68 + i] = w21[idx];
    sW[3 * 4352 + j * 68 + i] = w22[idx];
  }
  __syncthreads();
  const int w = t >> 6, lane = t & 63;
  const float g1v = g1[lane], be1v = be1[lane];
  const float b11v = b11[lane], b12v = b12[lane];
  const float g2v = g2[lane], be2v = be2[lane];
  const float b21v = b21[lane], b22v = b22[lane];
  const int gp0 = blockIdx.x * 64 + w * 16;
  const int b = gp0 >> 14, p0 = gp0 & 16383;
  const size_t base = ((size_t)(b * 64 + lane)) << 14;
  for (int pi = 0; pi < 16; pi++) {
    const int p = p0 + pi;
    const float v = out1[base + p];
    // LN1 + ff1
    float mu = wsum64(v) * (1.f / 64.f);
    float d = v - mu;
    float var = wsum64(d * d) * (1.f / 64.f);
    float yn = d * (1.f / sqrtf(var + 1e-5f)) * g1v + be1v;
    float h = mm64(&sW[0], lane, yn, b11v);
    h = h > 0.f ? h : 0.01f * h;
    float f = mm64(&sW[4352], lane, h, b12v);
    float o2 = f + v;
    // LN2 + ff2
    float mu2 = wsum64(o2) * (1.f / 64.f);
    float d2 = o2 - mu2;
    float var2 = wsum64(d2 * d2) * (1.f / 64.f);
    float yn2 = d2 * (1.f / sqrtf(var2 + 1e-5f)) * g2v + be2v;
    float h2 = mm64(&sW[2 * 4352], lane, yn2, b21v);
    h2 = h2 > 0.f ? h2 : 0.01f * h2;
    float f2 = mm64(&sW[3 * 4352], lane, h2, b22v);
    outp[base + p] = f2 + v;
  }
}

// ================= launcher =================
extern "C" void kernel_launch(void* const* d_in, const int* in_sizes, int n_in,
                              void* d_out, int out_size, void* d_ws, size_t ws_size,
                              hipStream_t stream)
{
  if (ws_size < WS_FLOATS * sizeof(float)) return;  // need ~116 MB scratch
  float* ws = (float*)d_ws;

  const float* x       = (const float*)d_in[0];
  const float* w_down  = (const float*)d_in[1];
  const float* w_mid   = (const float*)d_in[2];
  const float* w_up    = (const float*)d_in[3];
  const float* wq_l    = (const float*)d_in[4];
  const float* wk_m    = (const float*)d_in[5];
  const float* wv_m    = (const float*)d_in[6];
  const float* wq_h    = (const float*)d_in[7];
  const float* rescale = (const float*)d_in[8];
  const float* w_proj_l= (const float*)d_in[9];
  const float* b_proj_l= (const float*)d_in[10];
  const float* w_proj_h= (const float*)d_in[11];
  const float* b_proj_h= (const float*)d_in[12];
  const float* qco_w1  = (const float*)d_in[13];
  const float* qsca_w  = (const float*)d_in[14];
  const float* qsca_b  = (const float*)d_in[15];
  const float* qt1_w   = (const float*)d_in[16];
  const float* qt1_b   = (const float*)d_in[17];
  const float* qt2_w   = (const float*)d_in[18];
  const float* qt2_b   = (const float*)d_in[19];
  const float* rsp_w1  = (const float*)d_in[20];
  const float* rsp_pr  = (const float*)d_in[21];
  const float* rsp_w2  = (const float*)d_in[22];
  const float* c31_w1  = (const float*)d_in[23];
  const float* c31_pr  = (const float*)d_in[24];
  const float* c31_w2  = (const float*)d_in[25];
  const float* c31_w3  = (const float*)d_in[26];
  const float* ln1_g   = (const float*)d_in[27];
  const float* ln1_b   = (const float*)d_in[28];
  const float* ff1_w1  = (const float*)d_in[29];
  const float* ff1_b1  = (const float*)d_in[30];
  const float* ff1_w2  = (const float*)d_in[31];
  const float* ff1_b2  = (const float*)d_in[32];
  const float* ln2_g   = (const float*)d_in[33];
  const float* ln2_b   = (const float*)d_in[34];
  const float* ff2_w1  = (const float*)d_in[35];
  const float* ff2_b1  = (const float*)d_in[36];
  const float* ff2_w2  = (const float*)d_in[37];
  const float* ff2_b2  = (const float*)d_in[38];

  float* buf384 = ws + O_BUF384;
  float* wcat   = ws + O_WCAT;
  float* wfold  = ws + O_WFOLD;
  float* G      = ws + O_G;
  float* T1     = ws + O_T1;
  float* UL     = ws + O_UL;
  float* UK     = ws + O_UK;
  float* T1H    = ws + O_T1H;
  float* UH     = ws + O_UH;
  float* norms  = ws + O_NORMS;
  float* attL   = ws + O_ATTL;
  float* attH   = ws + O_ATTH;
  float* WeL    = ws + O_WEFFL;
  float* WeH    = ws + O_WEFFH;
  float* Acat   = ws + O_ACAT;
  float* tsum   = ws + O_TSUM;
  float* attb   = ws + O_ATTB;
  float* hcat   = ws + O_HCAT;
  float* gpart  = ws + O_GPART;
  float* mid    = ws + O_MID;
  float* hout   = ws + O_HOUT;
  float* out1   = ws + O_OUT1;

  // 0) weight prep (concat, fold)
  k_wcat<<<dim3(864), 256, 0, stream>>>(w_down, w_mid, w_up, wcat);
  k_wfold<<<dim3(144), 256, 0, stream>>>(c31_w3, c31_w2, wfold);

  // 1) fused QKV conv 64->384, zero pad
  k_conv3x3<0, 8, 0><<<dim3(2, 8, 96), 256, 0, stream>>>(
      x, wcat, buf384, 64, 384, nullptr, nullptr, nullptr, nullptr);

  // 2) Gram G[b] = Z Z^T (k-split partials + reduce)
  k_gram<<<dim3(21, 16, 2), 256, 0, stream>>>(buf384, gpart);
  k_gred<<<dim3(1152), 256, 0, stream>>>(gpart, G);

  // 3) attention solve on Gram blocks
  k_sgemm<<<dim3(8, 16, 2), 256, 0, stream>>>(wq_l, G + 64, T1, 64, 64, 384, 128, 0, 147456, 32768);
  k_sgemm<<<dim3(4, 16, 2), 256, 0, stream>>>(wq_l, G, UL, 64, 64, 384, 64, 0, 147456, 16384);
  k_sgemm<<<dim3(8, 32, 2), 256, 0, stream>>>(wk_m, G + 64 * 384 + 64, UK, 128, 128, 384, 128, 0, 147456, 65536);
  k_sgemm<<<dim3(8, 48, 2), 256, 0, stream>>>(wq_h, G + 192 * 384 + 64, T1H, 192, 192, 384, 128, 0, 147456, 98304);
  k_sgemm<<<dim3(12, 48, 2), 256, 0, stream>>>(wq_h, G + 192 * 384 + 192, UH, 192, 192, 384, 192, 0, 147456, 147456);
  k_norms<<<dim3(12), 256, 0, stream>>>(UL, UK, UH, wq_l, wk_m, wq_h, norms);
  k_attn<<<dim3(8, 4, 2), 256, 0, stream>>>(T1, T1H, wk_m, norms, rescale, attL, attH);
  k_weff<<<dim3(8, 2, 2), 256, 0, stream>>>(attL, attH, wv_m, WeL, WeH);
  k_sgemm<<<dim3(8, 4, 2), 256, 0, stream>>>(w_proj_l, WeL, Acat, 256, 256, 128, 128, 0, 32768, 32768);
  k_sgemm<<<dim3(8, 12, 2), 256, 0, stream>>>(w_proj_h, WeH, Acat + 8192, 768, 768, 128, 128, 0, 98304, 32768);

  // 4) per-pixel linear map -> Hcat (view-quirk layout)
  k_pixmap<<<dim3(256, 4, 2), 256, 0, stream>>>(buf384, Acat, b_proj_l, b_proj_h, hcat);

  // 5) ReshapeBlock: reflect conv 256->64 + prelu, then 64->64
  k_conv3x3<1, 4, 1><<<dim3(2, 8, 32), 256, 0, stream>>>(
      hcat, rsp_w1, mid, 256, 64, rsp_pr, nullptr, nullptr, nullptr);
  k_conv3x3<1, 4, 0><<<dim3(2, 8, 32), 256, 0, stream>>>(
      mid, rsp_w2, hout, 64, 64, nullptr, nullptr, nullptr, nullptr);

  // 6) QCO -> att_before
  k_tsum<<<dim3(128), 256, 0, stream>>>(buf384, tsum);
  k_qco<<<dim3(2), 64, 0, stream>>>(tsum, qco_w1, qsca_w, qsca_b, qt1_w, qt1_b, qt2_w, qt2_b, attb);

  // 7) Conv3_1 (w3 folded into w2) + combine -> out1
  k_conv3x3<1, 4, 1><<<dim3(2, 8, 32), 256, 0, stream>>>(
      hout, c31_w1, mid, 64, 64, c31_pr, nullptr, nullptr, nullptr);
  k_conv3x3<1, 4, 2><<<dim3(2, 8, 32), 256, 0, stream>>>(
      mid, wfold, out1, 64, 64, nullptr, hout, attb, x);

  // 8) fused double-FF -> d_out (f32)
  k_ff<<<dim3(512), 256, 0, stream>>>(out1,
      ln1_g, ln1_b, ff1_w1, ff1_b1, ff1_w2, ff1_b2,
      ln2_g, ln2_b, ff2_w1, ff2_b1, ff2_w2, ff2_b2,
      (float*)d_out);
}

// Round 3
// 535.193 us; speedup vs baseline: 2.3893x; 2.3893x over previous
//
#include <hip/hip_runtime.h>
#include <hip/hip_bf16.h>
#include <stdint.h>

typedef __hip_bfloat16 bf16;
typedef __attribute__((ext_vector_type(8))) __bf16 bf8v;
typedef __attribute__((ext_vector_type(8))) short short8;
typedef __attribute__((ext_vector_type(4))) float f32x4;
#define DEVINL __device__ __forceinline__
#define MFMA16(a,b,c) __builtin_amdgcn_mfma_f32_16x16x32_bf16((a),(b),(c),0,0,0)

// ---------------- problem dims ----------------
// B=2, C=64, H=W=128, n=16384, HEADS=8, DH=32. All device I/O buffers are f32.

// ---------------- workspace layout (BYTE offsets) ----------------
static const size_t OFF_ZBF   = 0;          // [2][384][16384] bf16 (QKV conv out)
static const size_t OFF_XBF   = 25165824;   // [2][64][16384] bf16
static const size_t OFF_WTQ   = 29360128;   // [9][384][64] bf16
static const size_t OFF_WTR1  = 29802496;   // [9][64][256] bf16
static const size_t OFF_WTR2  = 30097408;   // [9][64][64] bf16
static const size_t OFF_WTC1  = 30171136;   // [9][64][64] bf16
static const size_t OFF_WTF   = 30244864;   // [9][64][64] bf16 (folded c31 w3@w2)
static const size_t OFF_WF32  = 30318592;   // [64][64][9] f32 temp
static const size_t OFF_G     = 30466048;   // [2][384][384] f32
static const size_t OFF_GPART = 31645696;   // [8][2][384][384] f32
static const size_t OFF_T1    = 41082880;   // [2][256][128] f32
static const size_t OFF_UL    = 41345024;   // [2][256][64] f32
static const size_t OFF_UK    = 41476096;   // [2][512][128] f32
static const size_t OFF_T1H   = 42000384;   // [2][768][128] f32
static const size_t OFF_UH    = 42786816;   // [2][768][192] f32
static const size_t OFF_NORMS = 43966464;   // [2][1536] f32
static const size_t OFF_ATTL  = 43978752;   // [2][8][32][64] f32
static const size_t OFF_ATTH  = 44109824;   // [2][8][96][64] f32
static const size_t OFF_WEL   = 44503040;   // [2][256][128] f32
static const size_t OFF_WEH   = 44765184;   // [2][768][128] f32
static const size_t OFF_ACAT  = 45551616;   // [2][256][128] f32
static const size_t OFF_ACATB = 45813760;   // [2][256][128] bf16
static const size_t OFF_TSUM  = 45944832;   // [2][64][9] f32
static const size_t OFF_ATTB  = 45949440;   // [2][64] f32
static const size_t OFF_HCATB = 45949952;   // [2][4194304] bf16 (view-quirk layout)
static const size_t OFF_MIDB  = 62727168;   // [2][64][16384] bf16
static const size_t OFF_HOUTB = 66921472;   // [2][64][16384] bf16
static const size_t OFF_OUT1  = 71115776;   // [2][64][16384] f32
static const size_t WS_BYTES  = 79504384;

// ================= prep kernels =================
__global__ void k_cvtb(const float* __restrict__ src, bf16* __restrict__ dst, int n) {
  int i = blockIdx.x * 256 + threadIdx.x;
  if (i < n) dst[i] = __float2bfloat16(src[i]);
}

__global__ void k_prep_wqkv(const float* __restrict__ wd, const float* __restrict__ wm,
                            const float* __restrict__ wu, bf16* __restrict__ dst) {
  int i = blockIdx.x * 256 + threadIdx.x;
  if (i >= 221184) return;
  int tap = i / 24576, r = i % 24576, oc = r >> 6, ic = r & 63;
  float v;
  if (oc < 64)       v = wd[(oc * 64 + ic) * 9 + tap];
  else if (oc < 192) v = wm[((oc - 64) * 64 + ic) * 9 + tap];
  else               v = wu[((oc - 192) * 64 + ic) * 9 + tap];
  dst[i] = __float2bfloat16(v);
}

// W[oc][ic][tap] f32 -> Wt[tap][oc][ic] bf16
__global__ void k_prep_gen(const float* __restrict__ w, bf16* __restrict__ dst,
                           int Cout, int Cin) {
  int i = blockIdx.x * 256 + threadIdx.x;
  int tot = 9 * Cout * Cin;
  if (i >= tot) return;
  int tap = i / (Cout * Cin), r = i % (Cout * Cin), oc = r / Cin, ic = r % Cin;
  dst[i] = __float2bfloat16(w[(oc * Cin + ic) * 9 + tap]);
}

// Wfold[o][i][tap] = sum_m c31_w3[o][m] * c31_w2[m][i][tap]  (f32)
__global__ void k_wfold(const float* __restrict__ w3, const float* __restrict__ w2,
                        float* __restrict__ wf) {
  int i = blockIdx.x * 256 + threadIdx.x;
  if (i >= 36864) return;
  int o = i / 576, r = i % 576, ic = r / 9, tap = r % 9;
  float s = 0.f;
  for (int m = 0; m < 64; m++)
    s = fmaf(w3[o * 64 + m], w2[(m * 64 + ic) * 9 + tap], s);
  wf[i] = s;
}

// ================= MFMA implicit-GEMM 3x3 conv =================
// Block: OCT out-channels x one image row (128 px). 4 waves: wo=oc-half, wp=px-half.
// in: bf16 [B][Cin][128][128]; Wt: bf16 [9][Cout][Cin].
// EPI: 0 plain->bf16, 1 prelu->bf16, 2 final(acc + hout*attb + x)->f32
template<int OCT, int REFLECT, int EPI>
__global__ __launch_bounds__(256) void k_convm(
    const short* __restrict__ in, const short* __restrict__ Wt,
    bf16* __restrict__ outb, float* __restrict__ outf,
    const int Cin, const int Cout,
    const float* __restrict__ prelu_a,
    const bf16* __restrict__ hout, const float* __restrict__ attb,
    const float* __restrict__ xres)
{
  constexpr int MT = OCT / 32;              // 16x16 oc-tiles per wave
  constexpr int WST = (OCT == 64) ? 9 : 1;  // taps resident in LDS at once
  __shared__ short sX[3][130][72];          // [dy][x+1 (halo)][ic(64)+pad]
  __shared__ short sW[WST * OCT][72];

  const int t = threadIdx.x, lane = t & 63, wv = t >> 6;
  const int wo = wv & 1, wp = wv >> 1;
  const int y = blockIdx.x, ocg = blockIdx.y, b = blockIdx.z;

  const f32x4 zero = {0.f, 0.f, 0.f, 0.f};
  f32x4 acc[MT][4];
#pragma unroll
  for (int m = 0; m < MT; m++)
#pragma unroll
    for (int n = 0; n < 4; n++) acc[m][n] = zero;

  for (int icb = 0; icb < Cin; icb += 64) {
    __syncthreads();
    // stage X: 3 rows x 130 cols x 8 ic-octets (transpose to [px][ic], pack-8)
    for (int i = t; i < 3120; i += 256) {
      int col = i % 130, rr = i / 130;
      int row = rr % 3, ko = rr / 3;
      int gy = y + row - 1, gx = col - 1;
      short8 vv;
      bool ok = true;
      if (REFLECT) {
        gy = gy < 0 ? 1 : (gy > 127 ? 126 : gy);
        gx = gx < 0 ? 1 : (gx > 127 ? 126 : gx);
      } else {
        ok = (gy >= 0) & (gy < 128) & (gx >= 0) & (gx < 128);
      }
      if (ok) {
        const short* src = in + (((size_t)(b * Cin + icb + ko * 8)) << 14) + (gy << 7) + gx;
#pragma unroll
        for (int u = 0; u < 8; u++) vv[u] = src[(size_t)u << 14];
      } else {
#pragma unroll
        for (int u = 0; u < 8; u++) vv[u] = 0;
      }
      *(short8*)&sX[row][col][ko * 8] = vv;
    }
    if (WST == 9) {
      for (int i = t; i < 9 * OCT * 8; i += 256) {
        int ko = i & 7, oc = (i >> 3) % OCT, tap = (i >> 3) / OCT;
        *(short8*)&sW[tap * OCT + oc][ko * 8] =
            *(const short8*)&Wt[((size_t)tap * Cout + ocg * OCT + oc) * Cin + icb + ko * 8];
      }
      __syncthreads();
#pragma unroll
      for (int tap = 0; tap < 9; tap++) {
        const int ky = tap / 3, kx = tap % 3;
#pragma unroll
        for (int kk = 0; kk < 2; kk++) {
          const int kb = kk * 32 + (lane >> 4) * 8;
          bf8v bfr[4];
#pragma unroll
          for (int n = 0; n < 4; n++)
            bfr[n] = *(const bf8v*)&sX[ky][wp * 64 + n * 16 + (lane & 15) + kx][kb];
#pragma unroll
          for (int m = 0; m < MT; m++) {
            bf8v afr = *(const bf8v*)&sW[tap * OCT + wo * (OCT / 2) + m * 16 + (lane & 15)][kb];
#pragma unroll
            for (int n = 0; n < 4; n++)
              acc[m][n] = MFMA16(afr, bfr[n], acc[m][n]);
          }
        }
      }
    } else {
      for (int tap = 0; tap < 9; tap++) {
        __syncthreads();
        for (int i = t; i < OCT * 8; i += 256) {
          int ko = i & 7, oc = i >> 3;
          *(short8*)&sW[oc][ko * 8] =
              *(const short8*)&Wt[((size_t)tap * Cout + ocg * OCT + oc) * Cin + icb + ko * 8];
        }
        __syncthreads();
        const int ky = tap / 3, kx = tap % 3;
#pragma unroll
        for (int kk = 0; kk < 2; kk++) {
          const int kb = kk * 32 + (lane >> 4) * 8;
          bf8v bfr[4];
#pragma unroll
          for (int n = 0; n < 4; n++)
            bfr[n] = *(const bf8v*)&sX[ky][wp * 64 + n * 16 + (lane & 15) + kx][kb];
#pragma unroll
          for (int m = 0; m < MT; m++) {
            bf8v afr = *(const bf8v*)&sW[wo * (OCT / 2) + m * 16 + (lane & 15)][kb];
#pragma unroll
            for (int n = 0; n < 4; n++)
              acc[m][n] = MFMA16(afr, bfr[n], acc[m][n]);
          }
        }
      }
    }
  }
  // epilogue: D row=(lane>>4)*4+r (oc), col=lane&15 (px)   [m89-verified]
  const float aP = (EPI == 1) ? prelu_a[0] : 0.f;
#pragma unroll
  for (int m = 0; m < MT; m++) {
    const int oc = ocg * OCT + wo * (OCT / 2) + m * 16 + ((lane >> 4) << 2);
#pragma unroll
    for (int n = 0; n < 4; n++) {
      const int px = wp * 64 + n * 16 + (lane & 15);
      const size_t base = (((size_t)(b * Cout + oc)) << 14) + (y << 7) + px;
#pragma unroll
      for (int r = 0; r < 4; r++) {
        float v = acc[m][n][r];
        const size_t idx = base + ((size_t)r << 14);
        if (EPI == 1) v = v > 0.f ? v : aP * v;
        if (EPI == 2) {
          v += __bfloat162float(hout[idx]) * attb[b * 64 + oc + r] + xres[idx];
          outf[idx] = v;
        } else {
          outb[idx] = __float2bfloat16(v);
        }
      }
    }
  }
}

// ================= Gram via MFMA: G[b] = Z Z^T =================
__global__ __launch_bounds__(256) void k_gramm(const short* __restrict__ Z,
                                               float* __restrict__ Gp) {
  // grid: x = 9 (3x3 128-row tile pairs), y = 8 k-chunks(2048), z = b
  const int ti = blockIdx.x / 3, tj = blockIdx.x % 3;
  const int kc = blockIdx.y, b = blockIdx.z;
  __shared__ short sA[128][72];
  __shared__ short sB[128][72];
  const int t = threadIdx.x, lane = t & 63, wv = t >> 6;
  const int wo = wv & 1, wp = wv >> 1;
  const f32x4 zero = {0.f, 0.f, 0.f, 0.f};
  f32x4 acc[4][4];
#pragma unroll
  for (int m = 0; m < 4; m++)
#pragma unroll
    for (int n = 0; n < 4; n++) acc[m][n] = zero;
  const size_t zb = (size_t)b * 6291456;
  const int k0 = kc * 2048;
  for (int ks = 0; ks < 2048; ks += 64) {
    __syncthreads();
    for (int i = t; i < 1024; i += 256) {
      int r = i >> 3, ko = i & 7;
      *(short8*)&sA[r][ko * 8] =
          *(const short8*)&Z[zb + ((size_t)(ti * 128 + r) << 14) + k0 + ks + ko * 8];
      *(short8*)&sB[r][ko * 8] =
          *(const short8*)&Z[zb + ((size_t)(tj * 128 + r) << 14) + k0 + ks + ko * 8];
    }
    __syncthreads();
#pragma unroll
    for (int kk = 0; kk < 2; kk++) {
      const int kb = kk * 32 + (lane >> 4) * 8;
      bf8v bfr[4];
#pragma unroll
      for (int n = 0; n < 4; n++)
        bfr[n] = *(const bf8v*)&sB[wp * 64 + n * 16 + (lane & 15)][kb];
#pragma unroll
      for (int m = 0; m < 4; m++) {
        bf8v afr = *(const bf8v*)&sA[wo * 64 + m * 16 + (lane & 15)][kb];
#pragma unroll
        for (int n = 0; n < 4; n++)
          acc[m][n] = MFMA16(afr, bfr[n], acc[m][n]);
      }
    }
  }
  float* gp = Gp + ((size_t)(kc * 2 + b)) * 147456;
#pragma unroll
  for (int m = 0; m < 4; m++)
#pragma unroll
    for (int n = 0; n < 4; n++)
#pragma unroll
      for (int r = 0; r < 4; r++)
        gp[(size_t)(ti * 128 + wo * 64 + m * 16 + ((lane >> 4) << 2) + r) * 384 +
           tj * 128 + wp * 64 + n * 16 + (lane & 15)] = acc[m][n][r];
}

__global__ void k_gred(const float* __restrict__ Gp, float* __restrict__ G) {
  int i = blockIdx.x * 256 + threadIdx.x;
  if (i >= 294912) return;
  int b = i / 147456, e = i % 147456;
  float s = 0.f;
#pragma unroll
  for (int c = 0; c < 8; c++) s += Gp[(size_t)(c * 2 + b) * 147456 + e];
  G[i] = s;
}

// ================= per-pixel map via MFMA (view-quirk output) =================
__global__ __launch_bounds__(256) void k_pixm(
    const short* __restrict__ Z, const short* __restrict__ Acatb,
    const float* __restrict__ bl, const float* __restrict__ bh,
    bf16* __restrict__ hcat)
{
  // grid: x = 256 (64-px tiles), y = 4 (64-oc groups), z = b ; K=128 (xM channels)
  const int p0 = blockIdx.x * 64, ocg = blockIdx.y, b = blockIdx.z;
  __shared__ short sA[64][136];   // [oc][k]
  __shared__ short sB[64][136];   // [px][k]
  const int t = threadIdx.x, lane = t & 63, wv = t >> 6;
  for (int i = t; i < 1024; i += 256) {
    int oc = i >> 4, ko = i & 15;
    *(short8*)&sA[oc][ko * 8] =
        *(const short8*)&Acatb[((size_t)(b * 256 + ocg * 64 + oc)) * 128 + ko * 8];
  }
  for (int i = t; i < 1024; i += 256) {
    int px = i & 63, ko = i >> 6;
    short8 vv;
#pragma unroll
    for (int u = 0; u < 8; u++)
      vv[u] = Z[((size_t)(b * 384 + 64 + ko * 8 + u) << 14) + p0 + px];
    *(short8*)&sB[px][ko * 8] = vv;
  }
  __syncthreads();
  const f32x4 zero = {0.f, 0.f, 0.f, 0.f};
  f32x4 acc[4] = {zero, zero, zero, zero};
#pragma unroll
  for (int kk = 0; kk < 4; kk++) {
    const int kb = kk * 32 + (lane >> 4) * 8;
    bf8v afr = *(const bf8v*)&sA[wv * 16 + (lane & 15)][kb];
#pragma unroll
    for (int n = 0; n < 4; n++) {
      bf8v bfr = *(const bf8v*)&sB[n * 16 + (lane & 15)][kb];
      acc[n] = MFMA16(afr, bfr, acc[n]);
    }
  }
  const size_t hbase = (size_t)b * 4194304;
#pragma unroll
  for (int n = 0; n < 4; n++) {
    const int px = p0 + n * 16 + (lane & 15);
#pragma unroll
    for (int r = 0; r < 4; r++) {
      const int oc = ocg * 64 + wv * 16 + ((lane >> 4) << 2) + r;
      float v = acc[n][r] + (oc < 64 ? bl[oc] : bh[oc - 64]);
      size_t addr = (oc < 64) ? hbase + (size_t)px * 64 + oc
                              : hbase + 1048576 + (size_t)px * 192 + (oc - 64);
      hcat[addr] = __float2bfloat16(v);
    }
  }
}

// ================= small GEMM: C = A[M,K] * B[K,N]  (f32, unchanged) =================
__global__ __launch_bounds__(256) void k_sgemm(
    const float* __restrict__ A, const float* __restrict__ B, float* __restrict__ C,
    int K, int lda, int ldb, int ldc, long sA_, long sB_, long sC_)
{
  __shared__ float sa[16][17];
  __shared__ float sb[16][17];
  const int tx = threadIdx.x & 15, ty = threadIdx.x >> 4;
  const float* Ap = A + (size_t)blockIdx.z * sA_;
  const float* Bp = B + (size_t)blockIdx.z * sB_;
  const int m = blockIdx.y * 16 + ty, n = blockIdx.x * 16 + tx;
  float acc = 0.f;
  for (int k0 = 0; k0 < K; k0 += 16) {
    sa[ty][tx] = Ap[(size_t)m * lda + k0 + tx];
    sb[ty][tx] = Bp[(size_t)(k0 + ty) * ldb + n];
    __syncthreads();
#pragma unroll
    for (int kk = 0; kk < 16; kk++) acc = fmaf(sa[ty][kk], sb[kk][tx], acc);
    __syncthreads();
  }
  C[(size_t)blockIdx.z * sC_ + (size_t)m * ldc + n] = acc;
}

// ================= norms =================
__global__ void k_norms(const float* __restrict__ UL, const float* __restrict__ UK,
                        const float* __restrict__ UH,
                        const float* __restrict__ wql, const float* __restrict__ wkm,
                        const float* __restrict__ wqh, float* __restrict__ norms) {
  int id = blockIdx.x * 256 + threadIdx.x;
  if (id >= 3072) return;
  int b = id / 1536, r = id % 1536;
  const float* u; const float* wv; int K;
  if (r < 256)      { K = 64;  u = UL + (size_t)(b * 256 + r) * 64;          wv = wql + (size_t)r * 64; }
  else if (r < 768) { int e = r - 256; K = 128; u = UK + (size_t)(b * 512 + e) * 128; wv = wkm + (size_t)e * 128; }
  else              { int d = r - 768; K = 192; u = UH + (size_t)(b * 768 + d) * 192; wv = wqh + (size_t)d * 192; }
  float s = 0.f;
  for (int k = 0; k < K; k++) s = fmaf(u[k], wv[k], s);
  norms[b * 1536 + r] = fmaxf(sqrtf(fmaxf(s, 0.f)), 1e-12f);
}

// ================= attention logits + softmax =================
__global__ __launch_bounds__(256) void k_attn(
    const float* __restrict__ T1, const float* __restrict__ T1H,
    const float* __restrict__ wkm, const float* __restrict__ norms,
    const float* __restrict__ rescale,
    float* __restrict__ attL, float* __restrict__ attH)
{
  const int h = blockIdx.x, cy = blockIdx.y, b = blockIdx.z;
  const int t = threadIdx.x;
  __shared__ float sK[64 * 129];
  __shared__ float sQ[32 * 129];
  __shared__ float sNk[64];
  const int isL = (cy == 0);
  const int rbase = isL ? 0 : (cy - 1) * 32;
  const float* TQ = isL ? (T1 + (size_t)(b * 256 + h * 32) * 128)
                        : (T1H + (size_t)(b * 768 + h * 96 + rbase) * 128);
  for (int idx = t; idx < 8192; idx += 256) {
    int e = idx >> 7, k = idx & 127;
    sK[e * 129 + k] = wkm[(size_t)(h * 64 + e) * 128 + k];
  }
  for (int idx = t; idx < 4096; idx += 256) {
    int r = idx >> 7, k = idx & 127;
    sQ[r * 129 + k] = TQ[(size_t)r * 128 + k];
  }
  if (t < 64) sNk[t] = norms[b * 1536 + 256 + h * 64 + t];
  __syncthreads();

  const int w = t >> 6, lane = t & 63;
  const float rs = rescale[h];
  for (int r = w; r < 32; r += 4) {
    float s = 0.f;
    for (int k = 0; k < 128; k++) s = fmaf(sQ[r * 129 + k], sK[lane * 129 + k], s);
    float nq = norms[b * 1536 + (isL ? (h * 32 + r) : (768 + h * 96 + rbase + r))];
    float logit = s / (nq * sNk[lane]) * rs;
    float m = logit;
#pragma unroll
    for (int o = 32; o; o >>= 1) m = fmaxf(m, __shfl_xor(m, o));
    float p = __expf(logit - m);
    float den = p;
#pragma unroll
    for (int o = 32; o; o >>= 1) den += __shfl_xor(den, o);
    float av = p / den;
    if (isL) attL[((size_t)(b * 8 + h) * 32 + r) * 64 + lane] = av;
    else     attH[((size_t)(b * 8 + h) * 96 + rbase + r) * 64 + lane] = av;
  }
}

// ================= Weff = attn @ wv (per head) =================
__global__ __launch_bounds__(256) void k_weff(
    const float* __restrict__ attL, const float* __restrict__ attH,
    const float* __restrict__ wvm,
    float* __restrict__ WeL, float* __restrict__ WeH)
{
  const int h = blockIdx.x, br = blockIdx.y, b = blockIdx.z;
  const int M = br ? 96 : 32;
  __shared__ float sAt[96 * 64];
  __shared__ float sV[64 * 132];
  const int t = threadIdx.x;
  const float* asrc = br ? attH + (size_t)(b * 8 + h) * 96 * 64
                         : attL + (size_t)(b * 8 + h) * 32 * 64;
  for (int idx = t; idx < M * 64; idx += 256) sAt[idx] = asrc[idx];
  for (int idx = t; idx < 8192; idx += 256) {
    int e = idx >> 7, k = idx & 127;
    sV[e * 132 + k] = wvm[(size_t)(h * 64 + e) * 128 + k];
  }
  __syncthreads();
  const int jg = t & 31, rw = t >> 5;
  float* dst = br ? WeH + (size_t)(b * 768 + h * 96) * 128
                  : WeL + (size_t)(b * 256 + h * 32) * 128;
  for (int r = rw; r < M; r += 8) {
    float4 acc = make_float4(0.f, 0.f, 0.f, 0.f);
    for (int e = 0; e < 64; e++) {
      float a = sAt[r * 64 + e];
      float4 v4 = *(const float4*)&sV[e * 132 + jg * 4];
      acc.x = fmaf(a, v4.x, acc.x);
      acc.y = fmaf(a, v4.y, acc.y);
      acc.z = fmaf(a, v4.z, acc.z);
      acc.w = fmaf(a, v4.w, acc.w);
    }
    *(float4*)&dst[(size_t)r * 128 + jg * 4] = acc;
  }
}

// ================= QCO: reflected 3x3 tap sums (bf16 input) =================
__global__ __launch_bounds__(256) void k_tsumb(const bf16* __restrict__ Z,
                                               float* __restrict__ Tsum) {
  const int c = blockIdx.x & 63, b = blockIdx.x >> 6;
  const bf16* src = Z + (((size_t)(b * 384 + c)) << 14);
  const int t = threadIdx.x;
  float s[9] = {};
  for (int p = t; p < 16384; p += 256) {
    int y = p >> 7, x = p & 127;
#pragma unroll
    for (int dy = 0; dy < 3; dy++) {
      int ry = y + dy - 1; ry = ry < 0 ? 1 : (ry > 127 ? 126 : ry);
#pragma unroll
      for (int dx = 0; dx < 3; dx++) {
        int rx = x + dx - 1; rx = rx < 0 ? 1 : (rx > 127 ? 126 : rx);
        s[dy * 3 + dx] += __bfloat162float(src[(ry << 7) + rx]);
      }
    }
  }
  __shared__ float red[4][9];
#pragma unroll
  for (int q = 0; q < 9; q++)
#pragma unroll
    for (int o = 32; o; o >>= 1) s[q] += __shfl_xor(s[q], o);
  int w = t >> 6, lane = t & 63;
  if (lane == 0)
#pragma unroll
    for (int q = 0; q < 9; q++) red[w][q] = s[q];
  __syncthreads();
  if (t < 9) Tsum[blockIdx.x * 9 + t] = red[0][t] + red[1][t] + red[2][t] + red[3][t];
}

// ================= QCO tail (per batch, 64 threads) =================
__global__ __launch_bounds__(64) void k_qco(
    const float* __restrict__ Tsum, const float* __restrict__ w1,
    const float* __restrict__ scaw, const float* __restrict__ scab,
    const float* __restrict__ t1w, const float* __restrict__ t1b,
    const float* __restrict__ t2w, const float* __restrict__ t2b,
    float* __restrict__ attb)
{
  const int b = blockIdx.x, c = threadIdx.x;
  __shared__ float sm[64], sxq[64], scat[128], sh1[64];
  float acc = 0.f;
  for (int j = 0; j < 64; j++) {
#pragma unroll
    for (int tap = 0; tap < 9; tap++)
      acc = fmaf(w1[(c * 64 + j) * 9 + tap], Tsum[(b * 64 + j) * 9 + tap], acc);
  }
  sm[c] = acc * (1.f / 16384.f);
  __syncthreads();
  float xa = scab[c];
  for (int j = 0; j < 64; j++) xa = fmaf(scaw[c * 64 + j], sm[j], xa);
  sxq[c] = xa;
  __syncthreads();
  float mn = xa, mx = xa;
#pragma unroll
  for (int o = 32; o; o >>= 1) {
    mn = fminf(mn, __shfl_xor(mn, o));
    mx = fmaxf(mx, __shfl_xor(mx, o));
  }
  float inter = (mx - mn) * (1.f / 64.f);
  float ql = (2.f * c + 1.f) / 128.f * (mx - mn) + mn;
  float sta = 0.f;
  for (int j = 0; j < 64; j++) {
    float q = 1.f - fabsf(ql - sxq[j]);
    sta += (q > 1.f - inter) ? q : 0.f;
  }
  float tot = sta;
#pragma unroll
  for (int o = 32; o; o >>= 1) tot += __shfl_xor(tot, o);
  sta = sta / fmaxf(tot, 1e-30f);
  scat[c] = sta; scat[64 + c] = xa;
  __syncthreads();
  float h = t1b[c];
  for (int j = 0; j < 128; j++) h = fmaf(t1w[c * 128 + j], scat[j], h);
  h = fmaxf(h, 0.f);
  sh1[c] = h;
  __syncthreads();
  float o2 = t2b[c];
  for (int j = 0; j < 64; j++) o2 = fmaf(t2w[c * 64 + j], sh1[j], o2);
  attb[b * 64 + c] = fmaxf(o2, 0.f);
}

// ================= fused double-FF block (lane = channel) =================
DEVINL float bcastl(float x, int l) {
  return __int_as_float(__builtin_amdgcn_readlane(__float_as_int(x), l));
}
DEVINL float wsum64(float x) {
#pragma unroll
  for (int o = 32; o; o >>= 1) x += __shfl_xor(x, o);
  return x;
}
DEVINL float mm64(const float* Wm, int lane, float xin, float bias) {
  float acc = bias;
#pragma unroll
  for (int ig = 0; ig < 16; ig++) {
    const float4 w4 = *(const float4*)&Wm[lane * 68 + ig * 4];
    acc = fmaf(w4.x, bcastl(xin, ig * 4 + 0), acc);
    acc = fmaf(w4.y, bcastl(xin, ig * 4 + 1), acc);
    acc = fmaf(w4.z, bcastl(xin, ig * 4 + 2), acc);
    acc = fmaf(w4.w, bcastl(xin, ig * 4 + 3), acc);
  }
  return acc;
}

__global__ __launch_bounds__(256) void k_ff(const float* __restrict__ out1,
    const float* g1, const float* be1, const float* w11, const float* b11,
    const float* w12, const float* b12,
    const float* g2, const float* be2, const float* w21, const float* b21,
    const float* w22, const float* b22,
    float* __restrict__ outp)
{
  __shared__ float sW[4 * 64 * 68];
  const int t = threadIdx.x;
  for (int idx = t; idx < 4096; idx += 256) {
    int j = idx >> 6, i = idx & 63;
    sW[0 * 4352 + j * 68 + i] = w11[idx];
    sW[1 * 4352 + j * 68 + i] = w12[idx];
    sW[2 * 4352 + j * 68 + i] = w21[idx];
    sW[3 * 4352 + j * 68 + i] = w22[idx];
  }
  __syncthreads();
  const int w = t >> 6, lane = t & 63;
  const float g1v = g1[lane], be1v = be1[lane];
  const float b11v = b11[lane], b12v = b12[lane];
  const float g2v = g2[lane], be2v = be2[lane];
  const float b21v = b21[lane], b22v = b22[lane];
  const int gp0 = blockIdx.x * 64 + w * 16;
  const int b = gp0 >> 14, p0 = gp0 & 16383;
  const size_t base = ((size_t)(b * 64 + lane)) << 14;
  for (int pi = 0; pi < 16; pi++) {
    const int p = p0 + pi;
    const float v = out1[base + p];
    float mu = wsum64(v) * (1.f / 64.f);
    float d = v - mu;
    float var = wsum64(d * d) * (1.f / 64.f);
    float yn = d * (1.f / sqrtf(var + 1e-5f)) * g1v + be1v;
    float h = mm64(&sW[0], lane, yn, b11v);
    h = h > 0.f ? h : 0.01f * h;
    float f = mm64(&sW[4352], lane, h, b12v);
    float o2 = f + v;
    float mu2 = wsum64(o2) * (1.f / 64.f);
    float d2 = o2 - mu2;
    float var2 = wsum64(d2 * d2) * (1.f / 64.f);
    float yn2 = d2 * (1.f / sqrtf(var2 + 1e-5f)) * g2v + be2v;
    float h2 = mm64(&sW[2 * 4352], lane, yn2, b21v);
    h2 = h2 > 0.f ? h2 : 0.01f * h2;
    float f2 = mm64(&sW[3 * 4352], lane, h2, b22v);
    outp[base + p] = f2 + v;
  }
}

// ================= launcher =================
extern "C" void kernel_launch(void* const* d_in, const int* in_sizes, int n_in,
                              void* d_out, int out_size, void* d_ws, size_t ws_size,
                              hipStream_t stream)
{
  if (ws_size < WS_BYTES) return;
  char* ws = (char*)d_ws;

  const float* x       = (const float*)d_in[0];
  const float* w_down  = (const float*)d_in[1];
  const float* w_mid   = (const float*)d_in[2];
  const float* w_up    = (const float*)d_in[3];
  const float* wq_l    = (const float*)d_in[4];
  const float* wk_m    = (const float*)d_in[5];
  const float* wv_m    = (const float*)d_in[6];
  const float* wq_h    = (const float*)d_in[7];
  const float* rescale = (const float*)d_in[8];
  const float* w_proj_l= (const float*)d_in[9];
  const float* b_proj_l= (const float*)d_in[10];
  const float* w_proj_h= (const float*)d_in[11];
  const float* b_proj_h= (const float*)d_in[12];
  const float* qco_w1  = (const float*)d_in[13];
  const float* qsca_w  = (const float*)d_in[14];
  const float* qsca_b  = (const float*)d_in[15];
  const float* qt1_w   = (const float*)d_in[16];
  const float* qt1_b   = (const float*)d_in[17];
  const float* qt2_w   = (const float*)d_in[18];
  const float* qt2_b   = (const float*)d_in[19];
  const float* rsp_w1  = (const float*)d_in[20];
  const float* rsp_pr  = (const float*)d_in[21];
  const float* rsp_w2  = (const float*)d_in[22];
  const float* c31_w1  = (const float*)d_in[23];
  const float* c31_pr  = (const float*)d_in[24];
  const float* c31_w2  = (const float*)d_in[25];
  const float* c31_w3  = (const float*)d_in[26];
  const float* ln1_g   = (const float*)d_in[27];
  const float* ln1_b   = (const float*)d_in[28];
  const float* ff1_w1  = (const float*)d_in[29];
  const float* ff1_b1  = (const float*)d_in[30];
  const float* ff1_w2  = (const float*)d_in[31];
  const float* ff1_b2  = (const float*)d_in[32];
  const float* ln2_g   = (const float*)d_in[33];
  const float* ln2_b   = (const float*)d_in[34];
  const float* ff2_w1  = (const float*)d_in[35];
  const float* ff2_b1  = (const float*)d_in[36];
  const float* ff2_w2  = (const float*)d_in[37];
  const float* ff2_b2  = (const float*)d_in[38];

  bf16*  zbf   = (bf16*)(ws + OFF_ZBF);
  bf16*  xbf   = (bf16*)(ws + OFF_XBF);
  bf16*  wtq   = (bf16*)(ws + OFF_WTQ);
  bf16*  wtr1  = (bf16*)(ws + OFF_WTR1);
  bf16*  wtr2  = (bf16*)(ws + OFF_WTR2);
  bf16*  wtc1  = (bf16*)(ws + OFF_WTC1);
  bf16*  wtf   = (bf16*)(ws + OFF_WTF);
  float* wf32  = (float*)(ws + OFF_WF32);
  float* G     = (float*)(ws + OFF_G);
  float* gpart = (float*)(ws + OFF_GPART);
  float* T1    = (float*)(ws + OFF_T1);
  float* UL    = (float*)(ws + OFF_UL);
  float* UK    = (float*)(ws + OFF_UK);
  float* T1H   = (float*)(ws + OFF_T1H);
  float* UH    = (float*)(ws + OFF_UH);
  float* norms = (float*)(ws + OFF_NORMS);
  float* attL  = (float*)(ws + OFF_ATTL);
  float* attH  = (float*)(ws + OFF_ATTH);
  float* WeL   = (float*)(ws + OFF_WEL);
  float* WeH   = (float*)(ws + OFF_WEH);
  float* Acat  = (float*)(ws + OFF_ACAT);
  bf16*  acatb = (bf16*)(ws + OFF_ACATB);
  float* tsum  = (float*)(ws + OFF_TSUM);
  float* attb  = (float*)(ws + OFF_ATTB);
  bf16*  hcatb = (bf16*)(ws + OFF_HCATB);
  bf16*  midb  = (bf16*)(ws + OFF_MIDB);
  bf16*  houtb = (bf16*)(ws + OFF_HOUTB);
  float* out1  = (float*)(ws + OFF_OUT1);

  // 0) prep: cvt + weight transforms
  k_cvtb<<<dim3(8192), 256, 0, stream>>>(x, xbf, 2097152);
  k_prep_wqkv<<<dim3(864), 256, 0, stream>>>(w_down, w_mid, w_up, wtq);
  k_prep_gen<<<dim3(576), 256, 0, stream>>>(rsp_w1, wtr1, 64, 256);
  k_prep_gen<<<dim3(144), 256, 0, stream>>>(rsp_w2, wtr2, 64, 64);
  k_prep_gen<<<dim3(144), 256, 0, stream>>>(c31_w1, wtc1, 64, 64);
  k_wfold<<<dim3(144), 256, 0, stream>>>(c31_w3, c31_w2, wf32);
  k_prep_gen<<<dim3(144), 256, 0, stream>>>(wf32, wtf, 64, 64);

  // 1) fused QKV conv 64->384 (zero pad) -> Z bf16
  k_convm<128, 0, 0><<<dim3(128, 3, 2), 256, 0, stream>>>(
      (const short*)xbf, (const short*)wtq, zbf, nullptr, 64, 384,
      nullptr, nullptr, nullptr, nullptr);

  // 2) Gram G[b] = Z Z^T (MFMA, k-split partials + reduce)
  k_gramm<<<dim3(9, 8, 2), 256, 0, stream>>>((const short*)zbf, gpart);
  k_gred<<<dim3(1152), 256, 0, stream>>>(gpart, G);

  // 3) attention solve on Gram blocks (f32, small)
  k_sgemm<<<dim3(8, 16, 2), 256, 0, stream>>>(wq_l, G + 64, T1, 64, 64, 384, 128, 0, 147456, 32768);
  k_sgemm<<<dim3(4, 16, 2), 256, 0, stream>>>(wq_l, G, UL, 64, 64, 384, 64, 0, 147456, 16384);
  k_sgemm<<<dim3(8, 32, 2), 256, 0, stream>>>(wk_m, G + 64 * 384 + 64, UK, 128, 128, 384, 128, 0, 147456, 65536);
  k_sgemm<<<dim3(8, 48, 2), 256, 0, stream>>>(wq_h, G + 192 * 384 + 64, T1H, 192, 192, 384, 128, 0, 147456, 98304);
  k_sgemm<<<dim3(12, 48, 2), 256, 0, stream>>>(wq_h, G + 192 * 384 + 192, UH, 192, 192, 384, 192, 0, 147456, 147456);
  k_norms<<<dim3(12), 256, 0, stream>>>(UL, UK, UH, wq_l, wk_m, wq_h, norms);
  k_attn<<<dim3(8, 4, 2), 256, 0, stream>>>(T1, T1H, wk_m, norms, rescale, attL, attH);
  k_weff<<<dim3(8, 2, 2), 256, 0, stream>>>(attL, attH, wv_m, WeL, WeH);
  k_sgemm<<<dim3(8, 4, 2), 256, 0, stream>>>(w_proj_l, WeL, Acat, 256, 256, 128, 128, 0, 32768, 32768);
  k_sgemm<<<dim3(8, 12, 2), 256, 0, stream>>>(w_proj_h, WeH, Acat + 8192, 768, 768, 128, 128, 0, 98304, 32768);
  k_cvtb<<<dim3(256), 256, 0, stream>>>(Acat, acatb, 65536);

  // 4) per-pixel linear map -> Hcat bf16 (view-quirk layout)
  k_pixm<<<dim3(256, 4, 2), 256, 0, stream>>>((const short*)zbf, (const short*)acatb,
                                              b_proj_l, b_proj_h, hcatb);

  // 5) ReshapeBlock: reflect conv 256->64 + prelu, then 64->64
  k_convm<64, 1, 1><<<dim3(128, 1, 2), 256, 0, stream>>>(
      (const short*)hcatb, (const short*)wtr1, midb, nullptr, 256, 64,
      rsp_pr, nullptr, nullptr, nullptr);
  k_convm<64, 1, 0><<<dim3(128, 1, 2), 256, 0, stream>>>(
      (const short*)midb, (const short*)wtr2, houtb, nullptr, 64, 64,
      nullptr, nullptr, nullptr, nullptr);

  // 6) QCO -> att_before
  k_tsumb<<<dim3(128), 256, 0, stream>>>(zbf, tsum);
  k_qco<<<dim3(2), 64, 0, stream>>>(tsum, qco_w1, qsca_w, qsca_b, qt1_w, qt1_b, qt2_w, qt2_b, attb);

  // 7) Conv3_1 (w3 folded) + final combine -> out1 f32
  k_convm<64, 1, 1><<<dim3(128, 1, 2), 256, 0, stream>>>(
      (const short*)houtb, (const short*)wtc1, midb, nullptr, 64, 64,
      c31_pr, nullptr, nullptr, nullptr);
  k_convm<64, 1, 2><<<dim3(128, 1, 2), 256, 0, stream>>>(
      (const short*)midb, (const short*)wtf, nullptr, out1, 64, 64,
      nullptr, houtb, attb, x);

  // 8) fused double-FF -> d_out (f32)
  k_ff<<<dim3(512), 256, 0, stream>>>(out1,
      ln1_g, ln1_b, ff1_w1, ff1_b1, ff1_w2, ff1_b2,
      ln2_g, ln2_b, ff2_w1, ff2_b1, ff2_w2, ff2_b2,
      (float*)d_out);
}

// Round 4
// 428.691 us; speedup vs baseline: 2.9829x; 1.2484x over previous
//
#include <hip/hip_runtime.h>
#include <hip/hip_bf16.h>
#include <stdint.h>

typedef __hip_bfloat16 bf16;
typedef __attribute__((ext_vector_type(8))) __bf16 bf8v;
typedef __attribute__((ext_vector_type(8))) short short8;
typedef __attribute__((ext_vector_type(4))) short short4v;
typedef __attribute__((ext_vector_type(4))) float f32x4;
#define DEVINL __device__ __forceinline__
#define MFMA16(a,b,c) __builtin_amdgcn_mfma_f32_16x16x32_bf16((a),(b),(c),0,0,0)

DEVINL short f2bs(float f) { bf16 h = __float2bfloat16(f); return *reinterpret_cast<short*>(&h); }

// ---------------- problem dims ----------------
// B=2, C=64, H=W=128, n=16384, HEADS=8, DH=32. All device I/O buffers are f32.

// ---------------- workspace layout (BYTE offsets) ----------------
static const size_t OFF_ZBF   = 0;          // [2][384][16384] bf16 (QKV conv out)
static const size_t OFF_XBF   = 25165824;   // (unused)
static const size_t OFF_WTQ   = 29360128;   // [9][384][64] bf16
static const size_t OFF_WTR1  = 29802496;   // [9][64][256] bf16
static const size_t OFF_WTR2  = 30097408;   // [9][64][64] bf16
static const size_t OFF_WTC1  = 30171136;   // [9][64][64] bf16
static const size_t OFF_WTF   = 30244864;   // [9][64][64] bf16 (folded c31 w3@w2)
static const size_t OFF_WF32  = 30318592;   // [64][64][9] f32 temp
static const size_t OFF_G     = 30466048;   // [2][384][384] f32
static const size_t OFF_T1    = 41082880;   // [2][256][128] f32
static const size_t OFF_UL    = 41345024;   // [2][256][64] f32
static const size_t OFF_UK    = 41476096;   // [2][512][128] f32
static const size_t OFF_T1H   = 42000384;   // [2][768][128] f32
static const size_t OFF_UH    = 42786816;   // [2][768][192] f32
static const size_t OFF_NORMS = 43966464;   // [2][1536] f32
static const size_t OFF_ATTL  = 43978752;   // [2][8][32][64] f32
static const size_t OFF_ATTH  = 44109824;   // [2][8][96][64] f32
static const size_t OFF_WEL   = 44503040;   // [2][256][128] f32
static const size_t OFF_WEH   = 44765184;   // [2][768][128] f32
static const size_t OFF_ACAT  = 45551616;   // [2][256][128] f32
static const size_t OFF_ACATB = 45813760;   // [2][256][128] bf16
static const size_t OFF_TSUM  = 45944832;   // [2][64][9] f32
static const size_t OFF_ATTB  = 45949440;   // [2][64] f32
static const size_t OFF_HCATB = 45949952;   // [2][4194304] bf16 (view-quirk layout)
static const size_t OFF_MIDB  = 62727168;   // [2][64][16384] bf16
static const size_t OFF_HOUTB = 66921472;   // [2][64][16384] bf16
static const size_t OFF_OUT1  = 71115776;   // [2][64][16384] f32
static const size_t OFF_GPART = 79504384;   // [16][2][384][384] f32
static const size_t OFF_XT    = 98378752;   // [2][16384][64] bf16 (x transposed)
static const size_t WS_BYTES  = 102573056;

// ================= prep kernels =================
__global__ void k_cvtb(const float* __restrict__ src, bf16* __restrict__ dst, int n) {
  int i = blockIdx.x * 256 + threadIdx.x;
  if (i < n) dst[i] = __float2bfloat16(src[i]);
}

// x [b][64][16384] f32 -> xt [b][16384][64] bf16
__global__ __launch_bounds__(256) void k_transp(const float* __restrict__ x,
                                                short* __restrict__ xt) {
  __shared__ short sT[64][72];
  const int t = threadIdx.x, b = blockIdx.z, p0 = blockIdx.x * 64;
  for (int i = t; i < 1024; i += 256) {
    int c = i >> 4, p4 = (i & 15) * 4;
    float4 g = *(const float4*)&x[(((size_t)(b * 64 + c)) << 14) + p0 + p4];
    sT[p4 + 0][c] = f2bs(g.x);
    sT[p4 + 1][c] = f2bs(g.y);
    sT[p4 + 2][c] = f2bs(g.z);
    sT[p4 + 3][c] = f2bs(g.w);
  }
  __syncthreads();
  for (int i = t; i < 512; i += 256) {
    int p = i >> 3, co = (i & 7) * 8;
    *(short8*)&xt[((((size_t)b << 14) + p0 + p)) * 64 + co] = *(short8*)&sT[p][co];
  }
}

__global__ void k_prep_wqkv(const float* __restrict__ wd, const float* __restrict__ wm,
                            const float* __restrict__ wu, bf16* __restrict__ dst) {
  int i = blockIdx.x * 256 + threadIdx.x;
  if (i >= 221184) return;
  int tap = i / 24576, r = i % 24576, oc = r >> 6, ic = r & 63;
  float v;
  if (oc < 64)       v = wd[(oc * 64 + ic) * 9 + tap];
  else if (oc < 192) v = wm[((oc - 64) * 64 + ic) * 9 + tap];
  else               v = wu[((oc - 192) * 64 + ic) * 9 + tap];
  dst[i] = __float2bfloat16(v);
}

// W[oc][ic][tap] f32 -> Wt[tap][oc][ic] bf16
__global__ void k_prep_gen(const float* __restrict__ w, bf16* __restrict__ dst,
                           int Cout, int Cin) {
  int i = blockIdx.x * 256 + threadIdx.x;
  int tot = 9 * Cout * Cin;
  if (i >= tot) return;
  int tap = i / (Cout * Cin), r = i % (Cout * Cin), oc = r / Cin, ic = r % Cin;
  dst[i] = __float2bfloat16(w[(oc * Cin + ic) * 9 + tap]);
}

// Wfold[o][i][tap] = sum_m c31_w3[o][m] * c31_w2[m][i][tap]  (f32)
__global__ void k_wfold(const float* __restrict__ w3, const float* __restrict__ w2,
                        float* __restrict__ wf) {
  int i = blockIdx.x * 256 + threadIdx.x;
  if (i >= 36864) return;
  int o = i / 576, r = i % 576, ic = r / 9, tap = r % 9;
  float s = 0.f;
  for (int m = 0; m < 64; m++)
    s = fmaf(w3[o * 64 + m], w2[(m * 64 + ic) * 9 + tap], s);
  wf[i] = s;
}

// ================= MFMA implicit-GEMM 3x3 conv =================
// Block: OCT out-channels x one image row (128 px). 4 waves: wo=oc-half, wp=px-half.
// in: bf16 NCHW [B][Cin][128][128] (XT=0) or [B][16384][64] px-major (XT=1, Cin=64 only).
// Wt: bf16 [9][Cout][Cin].
// EPI: 0 plain->bf16, 1 prelu->bf16, 2 final(acc + hout*attb + x)->f32
template<int OCT, int REFLECT, int EPI, int XT = 0>
__global__ __launch_bounds__(256) void k_convm(
    const short* __restrict__ in, const short* __restrict__ Wt,
    bf16* __restrict__ outb, float* __restrict__ outf,
    const int Cin, const int Cout,
    const float* __restrict__ prelu_a,
    const bf16* __restrict__ hout, const float* __restrict__ attb,
    const float* __restrict__ xres)
{
  constexpr int MT = OCT / 32;              // 16x16 oc-tiles per wave
  constexpr int WST = (OCT == 64) ? 9 : 1;  // taps resident in LDS at once
  __shared__ short sX[3][130][72];          // [dy][x+1 (halo)][ic(64)+pad]
  __shared__ short sW[WST * OCT][72];

  const int t = threadIdx.x, lane = t & 63, wv = t >> 6;
  const int wo = wv & 1, wp = wv >> 1;
  const int y = blockIdx.x, ocg = blockIdx.y, b = blockIdx.z;

  const f32x4 zero = {0.f, 0.f, 0.f, 0.f};
  f32x4 acc[MT][4];
#pragma unroll
  for (int m = 0; m < MT; m++)
#pragma unroll
    for (int n = 0; n < 4; n++) acc[m][n] = zero;

  for (int icb = 0; icb < Cin; icb += 64) {
    __syncthreads();
    // stage X: 3 rows x 130 cols x 8 ic-octets
    for (int i = t; i < 3120; i += 256) {
      int col = i % 130, rr = i / 130;
      int row = rr % 3, ko = rr / 3;
      int gy = y + row - 1, gx = col - 1;
      short8 vv;
      bool ok = true;
      if (REFLECT) {
        gy = gy < 0 ? 1 : (gy > 127 ? 126 : gy);
        gx = gx < 0 ? 1 : (gx > 127 ? 126 : gx);
      } else {
        ok = (gy >= 0) & (gy < 128) & (gx >= 0) & (gx < 128);
      }
      if (ok) {
        if (XT) {
          vv = *(const short8*)&in[((((size_t)b << 14) + (gy << 7) + gx)) * 64 + ko * 8];
        } else {
          const short* src = in + (((size_t)(b * Cin + icb + ko * 8)) << 14) + (gy << 7) + gx;
#pragma unroll
          for (int u = 0; u < 8; u++) vv[u] = src[(size_t)u << 14];
        }
      } else {
#pragma unroll
        for (int u = 0; u < 8; u++) vv[u] = 0;
      }
      *(short8*)&sX[row][col][ko * 8] = vv;
    }
    if (WST == 9) {
      for (int i = t; i < 9 * OCT * 8; i += 256) {
        int ko = i & 7, oc = (i >> 3) % OCT, tap = (i >> 3) / OCT;
        *(short8*)&sW[tap * OCT + oc][ko * 8] =
            *(const short8*)&Wt[((size_t)tap * Cout + ocg * OCT + oc) * Cin + icb + ko * 8];
      }
      __syncthreads();
#pragma unroll
      for (int tap = 0; tap < 9; tap++) {
        const int ky = tap / 3, kx = tap % 3;
#pragma unroll
        for (int kk = 0; kk < 2; kk++) {
          const int kb = kk * 32 + (lane >> 4) * 8;
          bf8v bfr[4];
#pragma unroll
          for (int n = 0; n < 4; n++)
            bfr[n] = *(const bf8v*)&sX[ky][wp * 64 + n * 16 + (lane & 15) + kx][kb];
#pragma unroll
          for (int m = 0; m < MT; m++) {
            bf8v afr = *(const bf8v*)&sW[tap * OCT + wo * (OCT / 2) + m * 16 + (lane & 15)][kb];
#pragma unroll
            for (int n = 0; n < 4; n++)
              acc[m][n] = MFMA16(afr, bfr[n], acc[m][n]);
          }
        }
      }
    } else {
      for (int tap = 0; tap < 9; tap++) {
        __syncthreads();
        for (int i = t; i < OCT * 8; i += 256) {
          int ko = i & 7, oc = i >> 3;
          *(short8*)&sW[oc][ko * 8] =
              *(const short8*)&Wt[((size_t)tap * Cout + ocg * OCT + oc) * Cin + icb + ko * 8];
        }
        __syncthreads();
        const int ky = tap / 3, kx = tap % 3;
#pragma unroll
        for (int kk = 0; kk < 2; kk++) {
          const int kb = kk * 32 + (lane >> 4) * 8;
          bf8v bfr[4];
#pragma unroll
          for (int n = 0; n < 4; n++)
            bfr[n] = *(const bf8v*)&sX[ky][wp * 64 + n * 16 + (lane & 15) + kx][kb];
#pragma unroll
          for (int m = 0; m < MT; m++) {
            bf8v afr = *(const bf8v*)&sW[wo * (OCT / 2) + m * 16 + (lane & 15)][kb];
#pragma unroll
            for (int n = 0; n < 4; n++)
              acc[m][n] = MFMA16(afr, bfr[n], acc[m][n]);
          }
        }
      }
    }
  }
  // epilogue: D row=(lane>>4)*4+r (oc), col=lane&15 (px)
  const float aP = (EPI == 1) ? prelu_a[0] : 0.f;
#pragma unroll
  for (int m = 0; m < MT; m++) {
    const int oc = ocg * OCT + wo * (OCT / 2) + m * 16 + ((lane >> 4) << 2);
#pragma unroll
    for (int n = 0; n < 4; n++) {
      const int px = wp * 64 + n * 16 + (lane & 15);
      const size_t base = (((size_t)(b * Cout + oc)) << 14) + (y << 7) + px;
#pragma unroll
      for (int r = 0; r < 4; r++) {
        float v = acc[m][n][r];
        const size_t idx = base + ((size_t)r << 14);
        if (EPI == 1) v = v > 0.f ? v : aP * v;
        if (EPI == 2) {
          v += __bfloat162float(hout[idx]) * attb[b * 64 + oc + r] + xres[idx];
          outf[idx] = v;
        } else {
          outb[idx] = __float2bfloat16(v);
        }
      }
    }
  }
}

// ================= Gram via MFMA: G[b] = Z Z^T =================
__global__ __launch_bounds__(256) void k_gramm(const short* __restrict__ Z,
                                               float* __restrict__ Gp) {
  // grid: x = 9 (3x3 128-row tile pairs), y = 16 k-chunks(1024), z = b
  const int ti = blockIdx.x / 3, tj = blockIdx.x % 3;
  const int kc = blockIdx.y, b = blockIdx.z;
  __shared__ short sA[128][72];
  __shared__ short sB[128][72];
  const int t = threadIdx.x, lane = t & 63, wv = t >> 6;
  const int wo = wv & 1, wp = wv >> 1;
  const f32x4 zero = {0.f, 0.f, 0.f, 0.f};
  f32x4 acc[4][4];
#pragma unroll
  for (int m = 0; m < 4; m++)
#pragma unroll
    for (int n = 0; n < 4; n++) acc[m][n] = zero;
  const size_t zb = (size_t)b * 6291456;
  const int k0 = kc * 1024;
  for (int ks = 0; ks < 1024; ks += 64) {
    __syncthreads();
    for (int i = t; i < 1024; i += 256) {
      int r = i >> 3, ko = i & 7;
      *(short8*)&sA[r][ko * 8] =
          *(const short8*)&Z[zb + ((size_t)(ti * 128 + r) << 14) + k0 + ks + ko * 8];
      *(short8*)&sB[r][ko * 8] =
          *(const short8*)&Z[zb + ((size_t)(tj * 128 + r) << 14) + k0 + ks + ko * 8];
    }
    __syncthreads();
#pragma unroll
    for (int kk = 0; kk < 2; kk++) {
      const int kb = kk * 32 + (lane >> 4) * 8;
      bf8v bfr[4];
#pragma unroll
      for (int n = 0; n < 4; n++)
        bfr[n] = *(const bf8v*)&sB[wp * 64 + n * 16 + (lane & 15)][kb];
#pragma unroll
      for (int m = 0; m < 4; m++) {
        bf8v afr = *(const bf8v*)&sA[wo * 64 + m * 16 + (lane & 15)][kb];
#pragma unroll
        for (int n = 0; n < 4; n++)
          acc[m][n] = MFMA16(afr, bfr[n], acc[m][n]);
      }
    }
  }
  float* gp = Gp + ((size_t)(kc * 2 + b)) * 147456;
#pragma unroll
  for (int m = 0; m < 4; m++)
#pragma unroll
    for (int n = 0; n < 4; n++)
#pragma unroll
      for (int r = 0; r < 4; r++)
        gp[(size_t)(ti * 128 + wo * 64 + m * 16 + ((lane >> 4) << 2) + r) * 384 +
           tj * 128 + wp * 64 + n * 16 + (lane & 15)] = acc[m][n][r];
}

__global__ void k_gred(const float* __restrict__ Gp, float* __restrict__ G) {
  int i = blockIdx.x * 256 + threadIdx.x;
  if (i >= 294912) return;
  int b = i / 147456, e = i % 147456;
  float s = 0.f;
#pragma unroll
  for (int c = 0; c < 16; c++) s += Gp[(size_t)(c * 2 + b) * 147456 + e];
  G[i] = s;
}

// ================= per-pixel map via MFMA (view-quirk output) =================
__global__ __launch_bounds__(256) void k_pixm(
    const short* __restrict__ Z, const short* __restrict__ Acatb,
    const float* __restrict__ bl, const float* __restrict__ bh,
    bf16* __restrict__ hcat)
{
  const int p0 = blockIdx.x * 64, ocg = blockIdx.y, b = blockIdx.z;
  __shared__ short sA[64][136];   // [oc][k]
  __shared__ short sB[64][136];   // [px][k]
  const int t = threadIdx.x, lane = t & 63, wv = t >> 6;
  for (int i = t; i < 1024; i += 256) {
    int oc = i >> 4, ko = i & 15;
    *(short8*)&sA[oc][ko * 8] =
        *(const short8*)&Acatb[((size_t)(b * 256 + ocg * 64 + oc)) * 128 + ko * 8];
  }
  for (int i = t; i < 1024; i += 256) {
    int px = i & 63, ko = i >> 6;
    short8 vv;
#pragma unroll
    for (int u = 0; u < 8; u++)
      vv[u] = Z[((size_t)(b * 384 + 64 + ko * 8 + u) << 14) + p0 + px];
    *(short8*)&sB[px][ko * 8] = vv;
  }
  __syncthreads();
  const f32x4 zero = {0.f, 0.f, 0.f, 0.f};
  f32x4 acc[4] = {zero, zero, zero, zero};
#pragma unroll
  for (int kk = 0; kk < 4; kk++) {
    const int kb = kk * 32 + (lane >> 4) * 8;
    bf8v afr = *(const bf8v*)&sA[wv * 16 + (lane & 15)][kb];
#pragma unroll
    for (int n = 0; n < 4; n++) {
      bf8v bfr = *(const bf8v*)&sB[n * 16 + (lane & 15)][kb];
      acc[n] = MFMA16(afr, bfr, acc[n]);
    }
  }
  const size_t hbase = (size_t)b * 4194304;
#pragma unroll
  for (int n = 0; n < 4; n++) {
    const int px = p0 + n * 16 + (lane & 15);
#pragma unroll
    for (int r = 0; r < 4; r++) {
      const int oc = ocg * 64 + wv * 16 + ((lane >> 4) << 2) + r;
      float v = acc[n][r] + (oc < 64 ? bl[oc] : bh[oc - 64]);
      size_t addr = (oc < 64) ? hbase + (size_t)px * 64 + oc
                              : hbase + 1048576 + (size_t)px * 192 + (oc - 64);
      hcat[addr] = __float2bfloat16(v);
    }
  }
}

// ================= small GEMM: C = A[M,K] * B[K,N]  (f32) =================
__global__ __launch_bounds__(256) void k_sgemm(
    const float* __restrict__ A, const float* __restrict__ B, float* __restrict__ C,
    int K, int lda, int ldb, int ldc, long sA_, long sB_, long sC_)
{
  __shared__ float sa[16][17];
  __shared__ float sb[16][17];
  const int tx = threadIdx.x & 15, ty = threadIdx.x >> 4;
  const float* Ap = A + (size_t)blockIdx.z * sA_;
  const float* Bp = B + (size_t)blockIdx.z * sB_;
  const int m = blockIdx.y * 16 + ty, n = blockIdx.x * 16 + tx;
  float acc = 0.f;
  for (int k0 = 0; k0 < K; k0 += 16) {
    sa[ty][tx] = Ap[(size_t)m * lda + k0 + tx];
    sb[ty][tx] = Bp[(size_t)(k0 + ty) * ldb + n];
    __syncthreads();
#pragma unroll
    for (int kk = 0; kk < 16; kk++) acc = fmaf(sa[ty][kk], sb[kk][tx], acc);
    __syncthreads();
  }
  C[(size_t)blockIdx.z * sC_ + (size_t)m * ldc + n] = acc;
}

// ================= norms =================
__global__ void k_norms(const float* __restrict__ UL, const float* __restrict__ UK,
                        const float* __restrict__ UH,
                        const float* __restrict__ wql, const float* __restrict__ wkm,
                        const float* __restrict__ wqh, float* __restrict__ norms) {
  int id = blockIdx.x * 256 + threadIdx.x;
  if (id >= 3072) return;
  int b = id / 1536, r = id % 1536;
  const float* u; const float* wv; int K;
  if (r < 256)      { K = 64;  u = UL + (size_t)(b * 256 + r) * 64;          wv = wql + (size_t)r * 64; }
  else if (r < 768) { int e = r - 256; K = 128; u = UK + (size_t)(b * 512 + e) * 128; wv = wkm + (size_t)e * 128; }
  else              { int d = r - 768; K = 192; u = UH + (size_t)(b * 768 + d) * 192; wv = wqh + (size_t)d * 192; }
  float s = 0.f;
  for (int k = 0; k < K; k++) s = fmaf(u[k], wv[k], s);
  norms[b * 1536 + r] = fmaxf(sqrtf(fmaxf(s, 0.f)), 1e-12f);
}

// ================= attention logits + softmax =================
__global__ __launch_bounds__(256) void k_attn(
    const float* __restrict__ T1, const float* __restrict__ T1H,
    const float* __restrict__ wkm, const float* __restrict__ norms,
    const float* __restrict__ rescale,
    float* __restrict__ attL, float* __restrict__ attH)
{
  const int h = blockIdx.x, cy = blockIdx.y, b = blockIdx.z;
  const int t = threadIdx.x;
  __shared__ float sK[64 * 129];
  __shared__ float sQ[32 * 129];
  __shared__ float sNk[64];
  const int isL = (cy == 0);
  const int rbase = isL ? 0 : (cy - 1) * 32;
  const float* TQ = isL ? (T1 + (size_t)(b * 256 + h * 32) * 128)
                        : (T1H + (size_t)(b * 768 + h * 96 + rbase) * 128);
  for (int idx = t; idx < 8192; idx += 256) {
    int e = idx >> 7, k = idx & 127;
    sK[e * 129 + k] = wkm[(size_t)(h * 64 + e) * 128 + k];
  }
  for (int idx = t; idx < 4096; idx += 256) {
    int r = idx >> 7, k = idx & 127;
    sQ[r * 129 + k] = TQ[(size_t)r * 128 + k];
  }
  if (t < 64) sNk[t] = norms[b * 1536 + 256 + h * 64 + t];
  __syncthreads();

  const int w = t >> 6, lane = t & 63;
  const float rs = rescale[h];
  for (int r = w; r < 32; r += 4) {
    float s = 0.f;
    for (int k = 0; k < 128; k++) s = fmaf(sQ[r * 129 + k], sK[lane * 129 + k], s);
    float nq = norms[b * 1536 + (isL ? (h * 32 + r) : (768 + h * 96 + rbase + r))];
    float logit = s / (nq * sNk[lane]) * rs;
    float m = logit;
#pragma unroll
    for (int o = 32; o; o >>= 1) m = fmaxf(m, __shfl_xor(m, o));
    float p = __expf(logit - m);
    float den = p;
#pragma unroll
    for (int o = 32; o; o >>= 1) den += __shfl_xor(den, o);
    float av = p / den;
    if (isL) attL[((size_t)(b * 8 + h) * 32 + r) * 64 + lane] = av;
    else     attH[((size_t)(b * 8 + h) * 96 + rbase + r) * 64 + lane] = av;
  }
}

// ================= Weff = attn @ wv (per head) =================
__global__ __launch_bounds__(256) void k_weff(
    const float* __restrict__ attL, const float* __restrict__ attH,
    const float* __restrict__ wvm,
    float* __restrict__ WeL, float* __restrict__ WeH)
{
  const int h = blockIdx.x, br = blockIdx.y, b = blockIdx.z;
  const int M = br ? 96 : 32;
  __shared__ float sAt[96 * 64];
  __shared__ float sV[64 * 132];
  const int t = threadIdx.x;
  const float* asrc = br ? attH + (size_t)(b * 8 + h) * 96 * 64
                         : attL + (size_t)(b * 8 + h) * 32 * 64;
  for (int idx = t; idx < M * 64; idx += 256) sAt[idx] = asrc[idx];
  for (int idx = t; idx < 8192; idx += 256) {
    int e = idx >> 7, k = idx & 127;
    sV[e * 132 + k] = wvm[(size_t)(h * 64 + e) * 128 + k];
  }
  __syncthreads();
  const int jg = t & 31, rw = t >> 5;
  float* dst = br ? WeH + (size_t)(b * 768 + h * 96) * 128
                  : WeL + (size_t)(b * 256 + h * 32) * 128;
  for (int r = rw; r < M; r += 8) {
    float4 acc = make_float4(0.f, 0.f, 0.f, 0.f);
    for (int e = 0; e < 64; e++) {
      float a = sAt[r * 64 + e];
      float4 v4 = *(const float4*)&sV[e * 132 + jg * 4];
      acc.x = fmaf(a, v4.x, acc.x);
      acc.y = fmaf(a, v4.y, acc.y);
      acc.z = fmaf(a, v4.z, acc.z);
      acc.w = fmaf(a, v4.w, acc.w);
    }
    *(float4*)&dst[(size_t)r * 128 + jg * 4] = acc;
  }
}

// ================= QCO: reflected 3x3 tap sums (bf16 input) =================
__global__ __launch_bounds__(256) void k_tsumb(const bf16* __restrict__ Z,
                                               float* __restrict__ Tsum) {
  const int c = blockIdx.x & 63, b = blockIdx.x >> 6;
  const bf16* src = Z + (((size_t)(b * 384 + c)) << 14);
  const int t = threadIdx.x;
  float s[9] = {};
  for (int p = t; p < 16384; p += 256) {
    int y = p >> 7, x = p & 127;
#pragma unroll
    for (int dy = 0; dy < 3; dy++) {
      int ry = y + dy - 1; ry = ry < 0 ? 1 : (ry > 127 ? 126 : ry);
#pragma unroll
      for (int dx = 0; dx < 3; dx++) {
        int rx = x + dx - 1; rx = rx < 0 ? 1 : (rx > 127 ? 126 : rx);
        s[dy * 3 + dx] += __bfloat162float(src[(ry << 7) + rx]);
      }
    }
  }
  __shared__ float red[4][9];
#pragma unroll
  for (int q = 0; q < 9; q++)
#pragma unroll
    for (int o = 32; o; o >>= 1) s[q] += __shfl_xor(s[q], o);
  int w = t >> 6, lane = t & 63;
  if (lane == 0)
#pragma unroll
    for (int q = 0; q < 9; q++) red[w][q] = s[q];
  __syncthreads();
  if (t < 9) Tsum[blockIdx.x * 9 + t] = red[0][t] + red[1][t] + red[2][t] + red[3][t];
}

// ================= QCO tail (per batch, 64 threads) =================
__global__ __launch_bounds__(64) void k_qco(
    const float* __restrict__ Tsum, const float* __restrict__ w1,
    const float* __restrict__ scaw, const float* __restrict__ scab,
    const float* __restrict__ t1w, const float* __restrict__ t1b,
    const float* __restrict__ t2w, const float* __restrict__ t2b,
    float* __restrict__ attb)
{
  const int b = blockIdx.x, c = threadIdx.x;
  __shared__ float sm[64], sxq[64], scat[128], sh1[64];
  float acc = 0.f;
  for (int j = 0; j < 64; j++) {
#pragma unroll
    for (int tap = 0; tap < 9; tap++)
      acc = fmaf(w1[(c * 64 + j) * 9 + tap], Tsum[(b * 64 + j) * 9 + tap], acc);
  }
  sm[c] = acc * (1.f / 16384.f);
  __syncthreads();
  float xa = scab[c];
  for (int j = 0; j < 64; j++) xa = fmaf(scaw[c * 64 + j], sm[j], xa);
  sxq[c] = xa;
  __syncthreads();
  float mn = xa, mx = xa;
#pragma unroll
  for (int o = 32; o; o >>= 1) {
    mn = fminf(mn, __shfl_xor(mn, o));
    mx = fmaxf(mx, __shfl_xor(mx, o));
  }
  float inter = (mx - mn) * (1.f / 64.f);
  float ql = (2.f * c + 1.f) / 128.f * (mx - mn) + mn;
  float sta = 0.f;
  for (int j = 0; j < 64; j++) {
    float q = 1.f - fabsf(ql - sxq[j]);
    sta += (q > 1.f - inter) ? q : 0.f;
  }
  float tot = sta;
#pragma unroll
  for (int o = 32; o; o >>= 1) tot += __shfl_xor(tot, o);
  sta = sta / fmaxf(tot, 1e-30f);
  scat[c] = sta; scat[64 + c] = xa;
  __syncthreads();
  float h = t1b[c];
  for (int j = 0; j < 128; j++) h = fmaf(t1w[c * 128 + j], scat[j], h);
  h = fmaxf(h, 0.f);
  sh1[c] = h;
  __syncthreads();
  float o2 = t2b[c];
  for (int j = 0; j < 64; j++) o2 = fmaf(t2w[c * 64 + j], sh1[j], o2);
  attb[b * 64 + c] = fmaxf(o2, 0.f);
}

// ================= MFMA fused double-FF block =================
// Block: 128 px x 64 ch, 4 waves (wave wv owns px [wv*32, wv*32+32)).
__global__ __launch_bounds__(256) void k_ffm(const float* __restrict__ out1,
    const float* g1, const float* be1, const float* w11, const float* b11,
    const float* w12, const float* b12,
    const float* g2, const float* be2, const float* w21, const float* b21,
    const float* w22, const float* b22,
    float* __restrict__ outp)
{
  __shared__ short sW4[4][64][72];   // [stage][oc][ic]
  __shared__ short sy[128][72];      // bf16 activations [px][ch]
  __shared__ float sv[128][68];      // v (out1) f32 [px][ch]
  __shared__ float so2[128][68];     // out2 f32 [px][ch]
  __shared__ float spar[8][64];      // g1,be1,b11,b12,g2,be2,b21,b22

  const int t = threadIdx.x, lane = t & 63, wv = t >> 6;
  const int gp0 = blockIdx.x * 128;
  const int b = gp0 >> 14, p0 = gp0 & 16383;

  // stage weights + params + v
  for (int idx = t; idx < 4096; idx += 256) {
    int oc = idx >> 6, k = idx & 63;
    sW4[0][oc][k] = f2bs(w11[idx]);
    sW4[1][oc][k] = f2bs(w12[idx]);
    sW4[2][oc][k] = f2bs(w21[idx]);
    sW4[3][oc][k] = f2bs(w22[idx]);
  }
  if (t < 64) {
    spar[0][t] = g1[t]; spar[1][t] = be1[t]; spar[2][t] = b11[t]; spar[3][t] = b12[t];
    spar[4][t] = g2[t]; spar[5][t] = be2[t]; spar[6][t] = b21[t]; spar[7][t] = b22[t];
  }
  for (int i = t; i < 2048; i += 256) {
    int ch = i >> 5, p4 = (i & 31) * 4;
    float4 g = *(const float4*)&out1[(((size_t)(b * 64 + ch)) << 14) + p0 + p4];
    sv[p4 + 0][ch] = g.x; sv[p4 + 1][ch] = g.y;
    sv[p4 + 2][ch] = g.z; sv[p4 + 3][ch] = g.w;
  }
  __syncthreads();

  const int px_ln = t >> 1, half = t & 1;
  const f32x4 zero = {0.f, 0.f, 0.f, 0.f};
  f32x4 acc[4][2];

#define LN_PHASE(SRC, GI, BI)                                                   \
  {                                                                             \
    float4 vv[8]; float s1 = 0.f, s2 = 0.f;                                     \
    _Pragma("unroll")                                                           \
    for (int j = 0; j < 8; j++) {                                               \
      vv[j] = *(const float4*)&SRC[px_ln][half * 32 + j * 4];                   \
      s1 += vv[j].x + vv[j].y + vv[j].z + vv[j].w;                              \
      s2 += vv[j].x * vv[j].x + vv[j].y * vv[j].y +                             \
            vv[j].z * vv[j].z + vv[j].w * vv[j].w;                              \
    }                                                                           \
    s1 += __shfl_xor(s1, 1); s2 += __shfl_xor(s2, 1);                           \
    float mu = s1 * (1.f / 64.f);                                               \
    float var = fmaxf(s2 * (1.f / 64.f) - mu * mu, 0.f);                        \
    float rstd = 1.f / sqrtf(var + 1e-5f);                                      \
    _Pragma("unroll")                                                           \
    for (int j = 0; j < 8; j++) {                                               \
      short4v ss;                                                               \
      _Pragma("unroll")                                                         \
      for (int u = 0; u < 4; u++) {                                             \
        int c = half * 32 + j * 4 + u;                                          \
        float val = ((&vv[j].x)[u] - mu) * rstd * spar[GI][c] + spar[BI][c];    \
        ss[u] = f2bs(val);                                                      \
      }                                                                         \
      *(short4v*)&sy[px_ln][half * 32 + j * 4] = ss;                            \
    }                                                                           \
  }

#define MM_STAGE(SIDX)                                                          \
  {                                                                             \
    _Pragma("unroll")                                                           \
    for (int m = 0; m < 4; m++)                                                 \
      { acc[m][0] = zero; acc[m][1] = zero; }                                   \
    _Pragma("unroll")                                                           \
    for (int kk = 0; kk < 2; kk++) {                                            \
      const int kb = kk * 32 + (lane >> 4) * 8;                                 \
      bf8v bfr0 = *(const bf8v*)&sy[wv * 32 + (lane & 15)][kb];                 \
      bf8v bfr1 = *(const bf8v*)&sy[wv * 32 + 16 + (lane & 15)][kb];            \
      _Pragma("unroll")                                                         \
      for (int m = 0; m < 4; m++) {                                             \
        bf8v afr = *(const bf8v*)&sW4[SIDX][m * 16 + (lane & 15)][kb];          \
        acc[m][0] = MFMA16(afr, bfr0, acc[m][0]);                               \
        acc[m][1] = MFMA16(afr, bfr1, acc[m][1]);                               \
      }                                                                         \
    }                                                                           \
  }

  // ---- LN1 -> yn ----
  LN_PHASE(sv, 0, 1);
  __syncthreads();
  // ---- stage1: h = leaky(W11 @ yn + b11) -> sy ----
  MM_STAGE(0);
#pragma unroll
  for (int m = 0; m < 4; m++) {
    const int oc0 = m * 16 + ((lane >> 4) << 2);
#pragma unroll
    for (int n = 0; n < 2; n++) {
      const int px = wv * 32 + n * 16 + (lane & 15);
      short4v ss;
#pragma unroll
      for (int r = 0; r < 4; r++) {
        float h = acc[m][n][r] + spar[2][oc0 + r];
        h = h > 0.f ? h : 0.01f * h;
        ss[r] = f2bs(h);
      }
      *(short4v*)&sy[px][oc0] = ss;
    }
  }
  __syncthreads();
  // ---- stage2: o2 = W12 @ h + b12 + v -> so2 ----
  MM_STAGE(1);
#pragma unroll
  for (int m = 0; m < 4; m++) {
    const int oc0 = m * 16 + ((lane >> 4) << 2);
#pragma unroll
    for (int n = 0; n < 2; n++) {
      const int px = wv * 32 + n * 16 + (lane & 15);
      float4 vres = *(const float4*)&sv[px][oc0];
      float4 o;
      o.x = acc[m][n][0] + spar[3][oc0 + 0] + vres.x;
      o.y = acc[m][n][1] + spar[3][oc0 + 1] + vres.y;
      o.z = acc[m][n][2] + spar[3][oc0 + 2] + vres.z;
      o.w = acc[m][n][3] + spar[3][oc0 + 3] + vres.w;
      *(float4*)&so2[px][oc0] = o;
    }
  }
  __syncthreads();
  // ---- LN2 -> yn2 ----
  LN_PHASE(so2, 4, 5);
  __syncthreads();
  // ---- stage3: h2 = leaky(W21 @ yn2 + b21) -> sy ----
  MM_STAGE(2);
#pragma unroll
  for (int m = 0; m < 4; m++) {
    const int oc0 = m * 16 + ((lane >> 4) << 2);
#pragma unroll
    for (int n = 0; n < 2; n++) {
      const int px = wv * 32 + n * 16 + (lane & 15);
      short4v ss;
#pragma unroll
      for (int r = 0; r < 4; r++) {
        float h = acc[m][n][r] + spar[6][oc0 + r];
        h = h > 0.f ? h : 0.01f * h;
        ss[r] = f2bs(h);
      }
      *(short4v*)&sy[px][oc0] = ss;
    }
  }
  __syncthreads();
  // ---- stage4: out = W22 @ h2 + b22 + v -> global ----
  MM_STAGE(3);
#pragma unroll
  for (int m = 0; m < 4; m++) {
    const int oc0 = m * 16 + ((lane >> 4) << 2);
#pragma unroll
    for (int n = 0; n < 2; n++) {
      const int px = wv * 32 + n * 16 + (lane & 15);
      float4 vres = *(const float4*)&sv[px][oc0];
#pragma unroll
      for (int r = 0; r < 4; r++) {
        float outv = acc[m][n][r] + spar[7][oc0 + r] + (&vres.x)[r];
        outp[(((size_t)(b * 64 + oc0 + r)) << 14) + p0 + px] = outv;
      }
    }
  }
#undef LN_PHASE
#undef MM_STAGE
}

// ================= launcher =================
extern "C" void kernel_launch(void* const* d_in, const int* in_sizes, int n_in,
                              void* d_out, int out_size, void* d_ws, size_t ws_size,
                              hipStream_t stream)
{
  if (ws_size < WS_BYTES) return;
  char* ws = (char*)d_ws;

  const float* x       = (const float*)d_in[0];
  const float* w_down  = (const float*)d_in[1];
  const float* w_mid   = (const float*)d_in[2];
  const float* w_up    = (const float*)d_in[3];
  const float* wq_l    = (const float*)d_in[4];
  const float* wk_m    = (const float*)d_in[5];
  const float* wv_m    = (const float*)d_in[6];
  const float* wq_h    = (const float*)d_in[7];
  const float* rescale = (const float*)d_in[8];
  const float* w_proj_l= (const float*)d_in[9];
  const float* b_proj_l= (const float*)d_in[10];
  const float* w_proj_h= (const float*)d_in[11];
  const float* b_proj_h= (const float*)d_in[12];
  const float* qco_w1  = (const float*)d_in[13];
  const float* qsca_w  = (const float*)d_in[14];
  const float* qsca_b  = (const float*)d_in[15];
  const float* qt1_w   = (const float*)d_in[16];
  const float* qt1_b   = (const float*)d_in[17];
  const float* qt2_w   = (const float*)d_in[18];
  const float* qt2_b   = (const float*)d_in[19];
  const float* rsp_w1  = (const float*)d_in[20];
  const float* rsp_pr  = (const float*)d_in[21];
  const float* rsp_w2  = (const float*)d_in[22];
  const float* c31_w1  = (const float*)d_in[23];
  const float* c31_pr  = (const float*)d_in[24];
  const float* c31_w2  = (const float*)d_in[25];
  const float* c31_w3  = (const float*)d_in[26];
  const float* ln1_g   = (const float*)d_in[27];
  const float* ln1_b   = (const float*)d_in[28];
  const float* ff1_w1  = (const float*)d_in[29];
  const float* ff1_b1  = (const float*)d_in[30];
  const float* ff1_w2  = (const float*)d_in[31];
  const float* ff1_b2  = (const float*)d_in[32];
  const float* ln2_g   = (const float*)d_in[33];
  const float* ln2_b   = (const float*)d_in[34];
  const float* ff2_w1  = (const float*)d_in[35];
  const float* ff2_b1  = (const float*)d_in[36];
  const float* ff2_w2  = (const float*)d_in[37];
  const float* ff2_b2  = (const float*)d_in[38];

  bf16*  zbf   = (bf16*)(ws + OFF_ZBF);
  bf16*  wtq   = (bf16*)(ws + OFF_WTQ);
  bf16*  wtr1  = (bf16*)(ws + OFF_WTR1);
  bf16*  wtr2  = (bf16*)(ws + OFF_WTR2);
  bf16*  wtc1  = (bf16*)(ws + OFF_WTC1);
  bf16*  wtf   = (bf16*)(ws + OFF_WTF);
  float* wf32  = (float*)(ws + OFF_WF32);
  float* G     = (float*)(ws + OFF_G);
  float* gpart = (float*)(ws + OFF_GPART);
  float* T1    = (float*)(ws + OFF_T1);
  float* UL    = (float*)(ws + OFF_UL);
  float* UK    = (float*)(ws + OFF_UK);
  float* T1H   = (float*)(ws + OFF_T1H);
  float* UH    = (float*)(ws + OFF_UH);
  float* norms = (float*)(ws + OFF_NORMS);
  float* attL  = (float*)(ws + OFF_ATTL);
  float* attH  = (float*)(ws + OFF_ATTH);
  float* WeL   = (float*)(ws + OFF_WEL);
  float* WeH   = (float*)(ws + OFF_WEH);
  float* Acat  = (float*)(ws + OFF_ACAT);
  bf16*  acatb = (bf16*)(ws + OFF_ACATB);
  float* tsum  = (float*)(ws + OFF_TSUM);
  float* attb  = (float*)(ws + OFF_ATTB);
  bf16*  hcatb = (bf16*)(ws + OFF_HCATB);
  bf16*  midb  = (bf16*)(ws + OFF_MIDB);
  bf16*  houtb = (bf16*)(ws + OFF_HOUTB);
  float* out1  = (float*)(ws + OFF_OUT1);
  short* xt    = (short*)(ws + OFF_XT);

  // 0) prep: transpose x + weight transforms
  k_transp<<<dim3(256, 1, 2), 256, 0, stream>>>(x, xt);
  k_prep_wqkv<<<dim3(864), 256, 0, stream>>>(w_down, w_mid, w_up, wtq);
  k_prep_gen<<<dim3(576), 256, 0, stream>>>(rsp_w1, wtr1, 64, 256);
  k_prep_gen<<<dim3(144), 256, 0, stream>>>(rsp_w2, wtr2, 64, 64);
  k_prep_gen<<<dim3(144), 256, 0, stream>>>(c31_w1, wtc1, 64, 64);
  k_wfold<<<dim3(144), 256, 0, stream>>>(c31_w3, c31_w2, wf32);
  k_prep_gen<<<dim3(144), 256, 0, stream>>>(wf32, wtf, 64, 64);

  // 1) fused QKV conv 64->384 (zero pad, transposed-x staging) -> Z bf16
  k_convm<128, 0, 0, 1><<<dim3(128, 3, 2), 256, 0, stream>>>(
      xt, (const short*)wtq, zbf, nullptr, 64, 384,
      nullptr, nullptr, nullptr, nullptr);

  // 2) Gram G[b] = Z Z^T (MFMA, 16 k-split partials + reduce)
  k_gramm<<<dim3(9, 16, 2), 256, 0, stream>>>((const short*)zbf, gpart);
  k_gred<<<dim3(1152), 256, 0, stream>>>(gpart, G);

  // 3) attention solve on Gram blocks (f32, small)
  k_sgemm<<<dim3(8, 16, 2), 256, 0, stream>>>(wq_l, G + 64, T1, 64, 64, 384, 128, 0, 147456, 32768);
  k_sgemm<<<dim3(4, 16, 2), 256, 0, stream>>>(wq_l, G, UL, 64, 64, 384, 64, 0, 147456, 16384);
  k_sgemm<<<dim3(8, 32, 2), 256, 0, stream>>>(wk_m, G + 64 * 384 + 64, UK, 128, 128, 384, 128, 0, 147456, 65536);
  k_sgemm<<<dim3(8, 48, 2), 256, 0, stream>>>(wq_h, G + 192 * 384 + 64, T1H, 192, 192, 384, 128, 0, 147456, 98304);
  k_sgemm<<<dim3(12, 48, 2), 256, 0, stream>>>(wq_h, G + 192 * 384 + 192, UH, 192, 192, 384, 192, 0, 147456, 147456);
  k_norms<<<dim3(12), 256, 0, stream>>>(UL, UK, UH, wq_l, wk_m, wq_h, norms);
  k_attn<<<dim3(8, 4, 2), 256, 0, stream>>>(T1, T1H, wk_m, norms, rescale, attL, attH);
  k_weff<<<dim3(8, 2, 2), 256, 0, stream>>>(attL, attH, wv_m, WeL, WeH);
  k_sgemm<<<dim3(8, 4, 2), 256, 0, stream>>>(w_proj_l, WeL, Acat, 256, 256, 128, 128, 0, 32768, 32768);
  k_sgemm<<<dim3(8, 12, 2), 256, 0, stream>>>(w_proj_h, WeH, Acat + 8192, 768, 768, 128, 128, 0, 98304, 32768);
  k_cvtb<<<dim3(256), 256, 0, stream>>>(Acat, acatb, 65536);

  // 4) per-pixel linear map -> Hcat bf16 (view-quirk layout)
  k_pixm<<<dim3(256, 4, 2), 256, 0, stream>>>((const short*)zbf, (const short*)acatb,
                                              b_proj_l, b_proj_h, hcatb);

  // 5) ReshapeBlock: reflect conv 256->64 + prelu, then 64->64
  k_convm<64, 1, 1><<<dim3(128, 1, 2), 256, 0, stream>>>(
      (const short*)hcatb, (const short*)wtr1, midb, nullptr, 256, 64,
      rsp_pr, nullptr, nullptr, nullptr);
  k_convm<64, 1, 0><<<dim3(128, 1, 2), 256, 0, stream>>>(
      (const short*)midb, (const short*)wtr2, houtb, nullptr, 64, 64,
      nullptr, nullptr, nullptr, nullptr);

  // 6) QCO -> att_before
  k_tsumb<<<dim3(128), 256, 0, stream>>>(zbf, tsum);
  k_qco<<<dim3(2), 64, 0, stream>>>(tsum, qco_w1, qsca_w, qsca_b, qt1_w, qt1_b, qt2_w, qt2_b, attb);

  // 7) Conv3_1 (w3 folded) + final combine -> out1 f32
  k_convm<64, 1, 1><<<dim3(128, 1, 2), 256, 0, stream>>>(
      (const short*)houtb, (const short*)wtc1, midb, nullptr, 64, 64,
      c31_pr, nullptr, nullptr, nullptr);
  k_convm<64, 1, 2><<<dim3(128, 1, 2), 256, 0, stream>>>(
      (const short*)midb, (const short*)wtf, nullptr, out1, 64, 64,
      nullptr, houtb, attb, x);

  // 8) fused double-FF (MFMA) -> d_out (f32)
  k_ffm<<<dim3(256), 256, 0, stream>>>(out1,
      ln1_g, ln1_b, ff1_w1, ff1_b1, ff1_w2, ff1_b2,
      ln2_g, ln2_b, ff2_w1, ff2_b1, ff2_w2, ff2_b2,
      (float*)d_out);
}

// Round 7
// 345.922 us; speedup vs baseline: 3.6966x; 1.2393x over previous
//
#include <hip/hip_runtime.h>
#include <hip/hip_bf16.h>
#include <stdint.h>

typedef __hip_bfloat16 bf16;
typedef __attribute__((ext_vector_type(8))) __bf16 bf8v;
typedef __attribute__((ext_vector_type(8))) short short8;
typedef __attribute__((ext_vector_type(4))) short short4v;
typedef __attribute__((ext_vector_type(4))) float f32x4;
#define DEVINL __device__ __forceinline__
#define MFMA16(a,b,c) __builtin_amdgcn_mfma_f32_16x16x32_bf16((a),(b),(c),0,0,0)

DEVINL short f2bs(float f) { bf16 h = __float2bfloat16(f); return *reinterpret_cast<short*>(&h); }
DEVINL float bs2f(short s) { bf16 h = *reinterpret_cast<bf16*>(&s); return __bfloat162float(h); }

// ---------------- problem dims ----------------
// B=2, C=64, H=W=128, n=16384, HEADS=8, DH=32. All device I/O buffers are f32.

// ---------------- workspace layout (BYTE offsets) ----------------
static const size_t OFF_ZBF   = 0;          // [2][384][16384] bf16 (QKV conv out, NCHW)
static const size_t OFF_WTQ   = 29360128;   // [9][384][64] bf16
static const size_t OFF_WTR1  = 29802496;   // [9][64][256] bf16
static const size_t OFF_WTR2  = 30097408;   // [9][64][64] bf16
static const size_t OFF_WTC1  = 30171136;   // [9][64][64] bf16
static const size_t OFF_WTF   = 30244864;   // [9][64][64] bf16 (folded c31 w3@w2)
static const size_t OFF_G     = 30466048;   // [2][384][384] f32
static const size_t OFF_T1    = 41082880;   // [2][256][128] f32
static const size_t OFF_UL    = 41345024;   // [2][256][64] f32
static const size_t OFF_UK    = 41476096;   // [2][512][128] f32
static const size_t OFF_T1H   = 42000384;   // [2][768][128] f32
static const size_t OFF_UH    = 42786816;   // [2][768][192] f32
static const size_t OFF_NORMS = 43966464;   // [2][1536] f32
static const size_t OFF_ATTL  = 43978752;   // [2][8][32][64] f32
static const size_t OFF_ATTH  = 44109824;   // [2][8][96][64] f32
static const size_t OFF_WEL   = 44503040;   // [2][256][128] f32
static const size_t OFF_WEH   = 44765184;   // [2][768][128] f32
static const size_t OFF_ACATB = 45813760;   // [2][256][128] bf16
static const size_t OFF_TSUM  = 45944832;   // [2][64][9] f32
static const size_t OFF_ATTB  = 45949440;   // [2][64] f32
static const size_t OFF_HCATB = 45949952;   // [2][4194304] bf16 (view-quirk LINEAR layout)
static const size_t OFF_MIDB  = 62727168;   // [2][16384][64] bf16 (px-major)
static const size_t OFF_HOUTB = 66921472;   // [2][16384][64] bf16 (px-major)
static const size_t OFF_OUT1  = 71115776;   // [2][16384][64] f32 (px-major)
static const size_t OFF_GPART = 79504384;   // [16][2][384][384] f32 ; ALSO (later) hcatT
static const size_t OFF_HCATT = 79504384;   // [2][16384][256] bf16 (aliases GPART, dead by then)
static const size_t OFF_XT    = 98378752;   // [2][16384][64] bf16 (x transposed)
static const size_t WS_BYTES  = 102573056;

// ================= prep kernels =================
// x [b][64][16384] f32 -> xt [b][16384][64] bf16
__global__ __launch_bounds__(256) void k_transp(const float* __restrict__ x,
                                                short* __restrict__ xt) {
  __shared__ short sT[64][72];
  const int t = threadIdx.x, b = blockIdx.z, p0 = blockIdx.x * 64;
  for (int i = t; i < 1024; i += 256) {
    int c = i >> 4, p4 = (i & 15) * 4;
    float4 g = *(const float4*)&x[(((size_t)(b * 64 + c)) << 14) + p0 + p4];
    sT[p4 + 0][c] = f2bs(g.x);
    sT[p4 + 1][c] = f2bs(g.y);
    sT[p4 + 2][c] = f2bs(g.z);
    sT[p4 + 3][c] = f2bs(g.w);
  }
  __syncthreads();
  for (int i = t; i < 512; i += 256) {
    int p = i >> 3, co = (i & 7) * 8;
    *(short8*)&xt[((((size_t)b << 14) + p0 + p)) * 64 + co] = *(short8*)&sT[p][co];
  }
}

// hcat LINEAR (quirk view = NCHW [b][256][16384]) bf16 -> hcatT [b][16384][256] bf16
__global__ __launch_bounds__(256) void k_transph(const short* __restrict__ hc,
                                                 short* __restrict__ ht) {
  __shared__ short sT[64][72];
  const int t = threadIdx.x, b = blockIdx.z, p0 = blockIdx.x * 64, c0 = blockIdx.y * 64;
  for (int i = t; i < 512; i += 256) {
    int c = i >> 3, qo = (i & 7) * 8;
    short8 v = *(const short8*)&hc[(((size_t)(b * 256 + c0 + c)) << 14) + p0 + qo];
#pragma unroll
    for (int u = 0; u < 8; u++) sT[qo + u][c] = v[u];
  }
  __syncthreads();
  for (int i = t; i < 512; i += 256) {
    int q = i >> 3, co = (i & 7) * 8;
    *(short8*)&ht[((size_t)(b * 16384 + p0 + q)) * 256 + c0 + co] = *(short8*)&sT[q][co];
  }
}

// fused weight transforms -> [tap][oc][ic] bf16
__global__ void k_prep_all(const float* __restrict__ wd, const float* __restrict__ wm,
                           const float* __restrict__ wu, const float* __restrict__ rw1,
                           const float* __restrict__ rw2, const float* __restrict__ cw1,
                           bf16* __restrict__ wtq, bf16* __restrict__ wtr1,
                           bf16* __restrict__ wtr2, bf16* __restrict__ wtc1) {
  int i = blockIdx.x * 256 + threadIdx.x;
  if (i < 221184) {
    int tap = i / 24576, r = i % 24576, oc = r >> 6, ic = r & 63;
    float v;
    if (oc < 64)       v = wd[(oc * 64 + ic) * 9 + tap];
    else if (oc < 192) v = wm[((oc - 64) * 64 + ic) * 9 + tap];
    else               v = wu[((oc - 192) * 64 + ic) * 9 + tap];
    wtq[i] = __float2bfloat16(v);
  } else if (i < 368640) {
    int j = i - 221184;
    int tap = j / 16384, r = j % 16384, oc = r >> 8, ic = r & 255;
    wtr1[j] = __float2bfloat16(rw1[(oc * 256 + ic) * 9 + tap]);
  } else if (i < 405504) {
    int j = i - 368640;
    int tap = j / 4096, r = j % 4096, oc = r >> 6, ic = r & 63;
    wtr2[j] = __float2bfloat16(rw2[(oc * 64 + ic) * 9 + tap]);
  } else if (i < 442368) {
    int j = i - 405504;
    int tap = j / 4096, r = j % 4096, oc = r >> 6, ic = r & 63;
    wtc1[j] = __float2bfloat16(cw1[(oc * 64 + ic) * 9 + tap]);
  }
}

// wtf[tap][o][ic] = bf16( sum_m c31_w3[o][m] * c31_w2[m][ic][tap] )
__global__ void k_wfoldb(const float* __restrict__ w3, const float* __restrict__ w2,
                         bf16* __restrict__ wtf) {
  int i = blockIdx.x * 256 + threadIdx.x;
  if (i >= 36864) return;
  int tap = i / 4096, r = i % 4096, o = r >> 6, ic = r & 63;
  float s = 0.f;
  for (int m = 0; m < 64; m++)
    s = fmaf(w3[o * 64 + m], w2[(m * 64 + ic) * 9 + tap], s);
  wtf[i] = __float2bfloat16(s);
}

// ================= QKV conv 64->384 (zero pad), direct-A MFMA =================
__global__ __launch_bounds__(256) void k_convq(
    const short* __restrict__ xt, const short* __restrict__ wtq,
    bf16* __restrict__ zbf)
{
  __shared__ short sX[3][130][72];
  const int t = threadIdx.x, lane = t & 63, wv = t >> 6;
  const int y = blockIdx.x, ocg = blockIdx.y, b = blockIdx.z;

  for (int i = t; i < 3120; i += 256) {
    int col = i % 130, rr = i / 130, row = rr % 3, ko = rr / 3;
    int gy = y + row - 1, gx = col - 1;
    short8 vv;
    if ((gy >= 0) & (gy < 128) & (gx >= 0) & (gx < 128)) {
      vv = *(const short8*)&xt[((size_t)b * 1048576 + (size_t)((gy << 7) + gx) * 64) + ko * 8];
    } else {
#pragma unroll
      for (int u = 0; u < 8; u++) vv[u] = 0;
    }
    *(short8*)&sX[row][col][ko * 8] = vv;
  }
  __syncthreads();

  const f32x4 zero = {0.f, 0.f, 0.f, 0.f};
  f32x4 acc[2][8];
#pragma unroll
  for (int m = 0; m < 2; m++)
#pragma unroll
    for (int n = 0; n < 8; n++) acc[m][n] = zero;

#pragma unroll
  for (int tap = 0; tap < 9; tap++) {
    const int ky = tap / 3, kx = tap % 3;
#pragma unroll
    for (int kk = 0; kk < 2; kk++) {
      const int kb = kk * 32 + (lane >> 4) * 8;
      bf8v a0 = *(const bf8v*)&wtq[(size_t)((tap * 384 + ocg * 128 + wv * 32 + (lane & 15)) * 64) + kb];
      bf8v a1 = *(const bf8v*)&wtq[(size_t)((tap * 384 + ocg * 128 + wv * 32 + 16 + (lane & 15)) * 64) + kb];
#pragma unroll
      for (int n = 0; n < 8; n++) {
        bf8v bfr = *(const bf8v*)&sX[ky][n * 16 + (lane & 15) + kx][kb];
        acc[0][n] = MFMA16(a0, bfr, acc[0][n]);
        acc[1][n] = MFMA16(a1, bfr, acc[1][n]);
      }
    }
  }
#pragma unroll
  for (int m = 0; m < 2; m++) {
    const int oc0 = ocg * 128 + wv * 32 + m * 16 + ((lane >> 4) << 2);
#pragma unroll
    for (int n = 0; n < 8; n++) {
      const int px = n * 16 + (lane & 15);
#pragma unroll
      for (int r = 0; r < 4; r++)
        zbf[(((size_t)(b * 384 + oc0 + r)) << 14) + (y << 7) + px] = __float2bfloat16(acc[m][n][r]);
    }
  }
}

// ================= 3x3 reflect conv -> 64 out (direct-A MFMA, px-major IO) =================
// Block: 64 px (half row) x 64 oc; 4 waves, wave wv -> oc [wv*16, wv*16+16).
// in: px-major bf16 [b][16384][str].
// EPI: 0 plain->bf16 pm, 1 prelu->bf16 pm, 2 final(acc + hout*attb + x)->f32 pm
template<int EPI>
__global__ __launch_bounds__(256) void k_conv64(
    const short* __restrict__ in, int str, long bstride, int Cin,
    const short* __restrict__ Wt,
    short* __restrict__ outb, float* __restrict__ outf,
    const float* __restrict__ prelu_a,
    const short* __restrict__ houtpm, const float* __restrict__ attb,
    const float* __restrict__ x_nchw)
{
  __shared__ short sX[3][66][72];
  const int t = threadIdx.x, lane = t & 63, wv = t >> 6;
  const int y = blockIdx.x, x0 = blockIdx.y * 64, b = blockIdx.z;

  const f32x4 zero = {0.f, 0.f, 0.f, 0.f};
  f32x4 acc[4] = {zero, zero, zero, zero};

  for (int icb = 0; icb < Cin; icb += 64) {
    __syncthreads();
    for (int i = t; i < 1584; i += 256) {
      int col = i % 66, rr = i / 66, row = rr % 3, ko = rr / 3;
      int gy = y + row - 1, gx = x0 + col - 1;
      gy = gy < 0 ? 1 : (gy > 127 ? 126 : gy);
      gx = gx < 0 ? 1 : (gx > 127 ? 126 : gx);
      *(short8*)&sX[row][col][ko * 8] =
          *(const short8*)&in[(size_t)b * bstride + (size_t)((gy << 7) + gx) * str + icb + ko * 8];
    }
    __syncthreads();
#pragma unroll
    for (int tap = 0; tap < 9; tap++) {
      const int ky = tap / 3, kx = tap % 3;
#pragma unroll
      for (int kk = 0; kk < 2; kk++) {
        const int kb = kk * 32 + (lane >> 4) * 8;
        bf8v afr = *(const bf8v*)&Wt[(size_t)(tap * 64 + wv * 16 + (lane & 15)) * Cin + icb + kb];
#pragma unroll
        for (int n = 0; n < 4; n++) {
          bf8v bfr = *(const bf8v*)&sX[ky][n * 16 + (lane & 15) + kx][kb];
          acc[n] = MFMA16(afr, bfr, acc[n]);
        }
      }
    }
  }
  // epilogue: oc = wv*16 + (lane>>4)*4 + r ; px = x0 + n*16 + (lane&15)
  const int oc0 = wv * 16 + ((lane >> 4) << 2);
  const float aP = (EPI == 1) ? prelu_a[0] : 0.f;
#pragma unroll
  for (int n = 0; n < 4; n++) {
    const int gpx = (y << 7) + x0 + n * 16 + (lane & 15);
    if (EPI == 2) {
      short4v hv = *(const short4v*)&houtpm[((size_t)(b * 16384 + gpx)) * 64 + oc0];
      float4 av = *(const float4*)&attb[b * 64 + oc0];
      float4 o;
#pragma unroll
      for (int r = 0; r < 4; r++)
        (&o.x)[r] = acc[n][r] + bs2f(hv[r]) * (&av.x)[r] +
                    x_nchw[(((size_t)(b * 64 + oc0 + r)) << 14) + gpx];
      *(float4*)&outf[((size_t)(b * 16384 + gpx)) * 64 + oc0] = o;
    } else {
      short4v ss;
#pragma unroll
      for (int r = 0; r < 4; r++) {
        float v = acc[n][r];
        if (EPI == 1) v = v > 0.f ? v : aP * v;
        ss[r] = f2bs(v);
      }
      *(short4v*)&outb[((size_t)(b * 16384 + gpx)) * 64 + oc0] = ss;
    }
  }
}

// ================= Gram via MFMA: G[b] = Z Z^T =================
__global__ __launch_bounds__(256) void k_gramm(const short* __restrict__ Z,
                                               float* __restrict__ Gp) {
  const int ti = blockIdx.x / 3, tj = blockIdx.x % 3;
  const int kc = blockIdx.y, b = blockIdx.z;
  __shared__ short sA[128][72];
  __shared__ short sB[128][72];
  const int t = threadIdx.x, lane = t & 63, wv = t >> 6;
  const int wo = wv & 1, wp = wv >> 1;
  const f32x4 zero = {0.f, 0.f, 0.f, 0.f};
  f32x4 acc[4][4];
#pragma unroll
  for (int m = 0; m < 4; m++)
#pragma unroll
    for (int n = 0; n < 4; n++) acc[m][n] = zero;
  const size_t zb = (size_t)b * 6291456;
  const int k0 = kc * 1024;
  for (int ks = 0; ks < 1024; ks += 64) {
    __syncthreads();
    for (int i = t; i < 1024; i += 256) {
      int r = i >> 3, ko = i & 7;
      *(short8*)&sA[r][ko * 8] =
          *(const short8*)&Z[zb + ((size_t)(ti * 128 + r) << 14) + k0 + ks + ko * 8];
      *(short8*)&sB[r][ko * 8] =
          *(const short8*)&Z[zb + ((size_t)(tj * 128 + r) << 14) + k0 + ks + ko * 8];
    }
    __syncthreads();
#pragma unroll
    for (int kk = 0; kk < 2; kk++) {
      const int kb = kk * 32 + (lane >> 4) * 8;
      bf8v bfr[4];
#pragma unroll
      for (int n = 0; n < 4; n++)
        bfr[n] = *(const bf8v*)&sB[wp * 64 + n * 16 + (lane & 15)][kb];
#pragma unroll
      for (int m = 0; m < 4; m++) {
        bf8v afr = *(const bf8v*)&sA[wo * 64 + m * 16 + (lane & 15)][kb];
#pragma unroll
        for (int n = 0; n < 4; n++)
          acc[m][n] = MFMA16(afr, bfr[n], acc[m][n]);
      }
    }
  }
  float* gp = Gp + ((size_t)(kc * 2 + b)) * 147456;
#pragma unroll
  for (int m = 0; m < 4; m++)
#pragma unroll
    for (int n = 0; n < 4; n++)
#pragma unroll
      for (int r = 0; r < 4; r++)
        gp[(size_t)(ti * 128 + wo * 64 + m * 16 + ((lane >> 4) << 2) + r) * 384 +
           tj * 128 + wp * 64 + n * 16 + (lane & 15)] = acc[m][n][r];
}

__global__ void k_gred(const float* __restrict__ Gp, float* __restrict__ G) {
  int i = blockIdx.x * 256 + threadIdx.x;
  if (i >= 294912) return;
  int b = i / 147456, e = i % 147456;
  float s = 0.f;
#pragma unroll
  for (int c = 0; c < 16; c++) s += Gp[(size_t)(c * 2 + b) * 147456 + e];
  G[i] = s;
}

// ================= per-pixel map via MFMA (view-quirk LINEAR output) =================
__global__ __launch_bounds__(256) void k_pixm(
    const short* __restrict__ Z, const short* __restrict__ Acatb,
    const float* __restrict__ bl, const float* __restrict__ bh,
    bf16* __restrict__ hcat)
{
  const int p0 = blockIdx.x * 64, ocg = blockIdx.y, b = blockIdx.z;
  __shared__ short sA[64][136];
  __shared__ short sB[64][136];
  const int t = threadIdx.x, lane = t & 63, wv = t >> 6;
  for (int i = t; i < 1024; i += 256) {
    int oc = i >> 4, ko = i & 15;
    *(short8*)&sA[oc][ko * 8] =
        *(const short8*)&Acatb[((size_t)(b * 256 + ocg * 64 + oc)) * 128 + ko * 8];
  }
  for (int i = t; i < 1024; i += 256) {
    int px = i & 63, ko = i >> 6;
    short8 vv;
#pragma unroll
    for (int u = 0; u < 8; u++)
      vv[u] = Z[((size_t)(b * 384 + 64 + ko * 8 + u) << 14) + p0 + px];
    *(short8*)&sB[px][ko * 8] = vv;
  }
  __syncthreads();
  const f32x4 zero = {0.f, 0.f, 0.f, 0.f};
  f32x4 acc[4] = {zero, zero, zero, zero};
#pragma unroll
  for (int kk = 0; kk < 4; kk++) {
    const int kb = kk * 32 + (lane >> 4) * 8;
    bf8v afr = *(const bf8v*)&sA[wv * 16 + (lane & 15)][kb];
#pragma unroll
    for (int n = 0; n < 4; n++) {
      bf8v bfr = *(const bf8v*)&sB[n * 16 + (lane & 15)][kb];
      acc[n] = MFMA16(afr, bfr, acc[n]);
    }
  }
  const size_t hbase = (size_t)b * 4194304;
#pragma unroll
  for (int n = 0; n < 4; n++) {
    const int px = p0 + n * 16 + (lane & 15);
#pragma unroll
    for (int r = 0; r < 4; r++) {
      const int oc = ocg * 64 + wv * 16 + ((lane >> 4) << 2) + r;
      float v = acc[n][r] + (oc < 64 ? bl[oc] : bh[oc - 64]);
      size_t addr = (oc < 64) ? hbase + (size_t)px * 64 + oc
                              : hbase + 1048576 + (size_t)px * 192 + (oc - 64);
      hcat[addr] = __float2bfloat16(v);
    }
  }
}

// ================= fused small-GEMM chain (5 jobs): C = A[M,K]*B[K,N] =================
struct Jobs5 {
  const float* A[5]; const float* B[5]; float* C[5];
  int K[5]; int lda[5]; int ldb[5]; int ldc[5];
  long sB[5]; long sC[5];
  int nx[5]; int b0[6];
};

__global__ __launch_bounds__(256) void k_sgemm5(Jobs5 J) {
  __shared__ float sa[16][17];
  __shared__ float sb[16][17];
  const int bx = blockIdx.x, z = blockIdx.y;
  int j = 0;
  while (bx >= J.b0[j + 1]) j++;
  const int local = bx - J.b0[j];
  const int x = local % J.nx[j], y = local / J.nx[j];
  const int tx = threadIdx.x & 15, ty = threadIdx.x >> 4;
  const float* Ap = J.A[j];
  const float* Bp = J.B[j] + (size_t)z * J.sB[j];
  const int K = J.K[j], lda = J.lda[j], ldb = J.ldb[j];
  const int m = y * 16 + ty, n = x * 16 + tx;
  float acc = 0.f;
  for (int k0 = 0; k0 < K; k0 += 16) {
    sa[ty][tx] = Ap[(size_t)m * lda + k0 + tx];
    sb[ty][tx] = Bp[(size_t)(k0 + ty) * ldb + n];
    __syncthreads();
#pragma unroll
    for (int kk = 0; kk < 16; kk++) acc = fmaf(sa[ty][kk], sb[kk][tx], acc);
    __syncthreads();
  }
  J.C[j][(size_t)z * J.sC[j] + (size_t)m * J.ldc[j] + n] = acc;
}

// ================= proj GEMMs (2 jobs) -> bf16 Acat =================
struct Jobs2 {
  const float* A[2]; const float* B[2];
  int K[2]; int lda[2];
  long sB[2];
  int nx[2]; int b0[3]; int co[2];
};

__global__ __launch_bounds__(256) void k_sgemm2b(Jobs2 J, bf16* __restrict__ Cb) {
  __shared__ float sa[16][17];
  __shared__ float sb[16][17];
  const int bx = blockIdx.x, z = blockIdx.y;
  int j = (bx >= J.b0[1]) ? 1 : 0;
  const int local = bx - J.b0[j];
  const int x = local % J.nx[j], y = local / J.nx[j];
  const int tx = threadIdx.x & 15, ty = threadIdx.x >> 4;
  const float* Ap = J.A[j];
  const float* Bp = J.B[j] + (size_t)z * J.sB[j];
  const int K = J.K[j], lda = J.lda[j];
  const int m = y * 16 + ty, n = x * 16 + tx;
  float acc = 0.f;
  for (int k0 = 0; k0 < K; k0 += 16) {
    sa[ty][tx] = Ap[(size_t)m * lda + k0 + tx];
    sb[ty][tx] = Bp[(size_t)(k0 + ty) * 128 + n];
    __syncthreads();
#pragma unroll
    for (int kk = 0; kk < 16; kk++) acc = fmaf(sa[ty][kk], sb[kk][tx], acc);
    __syncthreads();
  }
  Cb[(size_t)z * 32768 + J.co[j] + (size_t)m * 128 + n] = __float2bfloat16(acc);
}

// ================= norms =================
__global__ void k_norms(const float* __restrict__ UL, const float* __restrict__ UK,
                        const float* __restrict__ UH,
                        const float* __restrict__ wql, const float* __restrict__ wkm,
                        const float* __restrict__ wqh, float* __restrict__ norms) {
  int id = blockIdx.x * 256 + threadIdx.x;
  if (id >= 3072) return;
  int b = id / 1536, r = id % 1536;
  const float* u; const float* wv; int K;
  if (r < 256)      { K = 64;  u = UL + (size_t)(b * 256 + r) * 64;          wv = wql + (size_t)r * 64; }
  else if (r < 768) { int e = r - 256; K = 128; u = UK + (size_t)(b * 512 + e) * 128; wv = wkm + (size_t)e * 128; }
  else              { int d = r - 768; K = 192; u = UH + (size_t)(b * 768 + d) * 192; wv = wqh + (size_t)d * 192; }
  float s = 0.f;
  for (int k = 0; k < K; k++) s = fmaf(u[k], wv[k], s);
  norms[b * 1536 + r] = fmaxf(sqrtf(fmaxf(s, 0.f)), 1e-12f);
}

// ================= attention logits + softmax =================
__global__ __launch_bounds__(256) void k_attn(
    const float* __restrict__ T1, const float* __restrict__ T1H,
    const float* __restrict__ wkm, const float* __restrict__ norms,
    const float* __restrict__ rescale,
    float* __restrict__ attL, float* __restrict__ attH)
{
  const int h = blockIdx.x, cy = blockIdx.y, b = blockIdx.z;
  const int t = threadIdx.x;
  __shared__ float sK[64 * 129];
  __shared__ float sQ[32 * 129];
  __shared__ float sNk[64];
  const int isL = (cy == 0);
  const int rbase = isL ? 0 : (cy - 1) * 32;
  const float* TQ = isL ? (T1 + (size_t)(b * 256 + h * 32) * 128)
                        : (T1H + (size_t)(b * 768 + h * 96 + rbase) * 128);
  for (int idx = t; idx < 8192; idx += 256) {
    int e = idx >> 7, k = idx & 127;
    sK[e * 129 + k] = wkm[(size_t)(h * 64 + e) * 128 + k];
  }
  for (int idx = t; idx < 4096; idx += 256) {
    int r = idx >> 7, k = idx & 127;
    sQ[r * 129 + k] = TQ[(size_t)r * 128 + k];
  }
  if (t < 64) sNk[t] = norms[b * 1536 + 256 + h * 64 + t];
  __syncthreads();

  const int w = t >> 6, lane = t & 63;
  const float rs = rescale[h];
  for (int r = w; r < 32; r += 4) {
    float s = 0.f;
    for (int k = 0; k < 128; k++) s = fmaf(sQ[r * 129 + k], sK[lane * 129 + k], s);
    float nq = norms[b * 1536 + (isL ? (h * 32 + r) : (768 + h * 96 + rbase + r))];
    float logit = s / (nq * sNk[lane]) * rs;
    float m = logit;
#pragma unroll
    for (int o = 32; o; o >>= 1) m = fmaxf(m, __shfl_xor(m, o));
    float p = __expf(logit - m);
    float den = p;
#pragma unroll
    for (int o = 32; o; o >>= 1) den += __shfl_xor(den, o);
    float av = p / den;
    if (isL) attL[((size_t)(b * 8 + h) * 32 + r) * 64 + lane] = av;
    else     attH[((size_t)(b * 8 + h) * 96 + rbase + r) * 64 + lane] = av;
  }
}

// ================= Weff = attn @ wv (per head) =================
__global__ __launch_bounds__(256) void k_weff(
    const float* __restrict__ attL, const float* __restrict__ attH,
    const float* __restrict__ wvm,
    float* __restrict__ WeL, float* __restrict__ WeH)
{
  const int h = blockIdx.x, br = blockIdx.y, b = blockIdx.z;
  const int M = br ? 96 : 32;
  __shared__ float sAt[96 * 64];
  __shared__ float sV[64 * 132];
  const int t = threadIdx.x;
  const float* asrc = br ? attH + (size_t)(b * 8 + h) * 96 * 64
                         : attL + (size_t)(b * 8 + h) * 32 * 64;
  for (int idx = t; idx < M * 64; idx += 256) sAt[idx] = asrc[idx];
  for (int idx = t; idx < 8192; idx += 256) {
    int e = idx >> 7, k = idx & 127;
    sV[e * 132 + k] = wvm[(size_t)(h * 64 + e) * 128 + k];
  }
  __syncthreads();
  const int jg = t & 31, rw = t >> 5;
  float* dst = br ? WeH + (size_t)(b * 768 + h * 96) * 128
                  : WeL + (size_t)(b * 256 + h * 32) * 128;
  for (int r = rw; r < M; r += 8) {
    float4 acc = make_float4(0.f, 0.f, 0.f, 0.f);
    for (int e = 0; e < 64; e++) {
      float a = sAt[r * 64 + e];
      float4 v4 = *(const float4*)&sV[e * 132 + jg * 4];
      acc.x = fmaf(a, v4.x, acc.x);
      acc.y = fmaf(a, v4.y, acc.y);
      acc.z = fmaf(a, v4.z, acc.z);
      acc.w = fmaf(a, v4.w, acc.w);
    }
    *(float4*)&dst[(size_t)r * 128 + jg * 4] = acc;
  }
}

// ================= QCO tap sums, separable (one vectorized pass) =================
__global__ __launch_bounds__(256) void k_tsum2(const bf16* __restrict__ Z,
                                               float* __restrict__ Tsum) {
  const int c = blockIdx.x & 63, b = blockIdx.x >> 6;
  const bf16* src = Z + (((size_t)(b * 384 + c)) << 14);
  const int t = threadIdx.x;
  __shared__ float sc[16];      // corners e[ri][xi], ri,xi map {0,1,126,127}->0..3
  __shared__ float red[4][9];
  float a9[9] = {};             // tot, r0, r1, r126, r127, c0, c1, c126, c127
  for (int i = t; i < 2048; i += 256) {
    int y = i >> 4, x0 = (i & 15) * 8;
    short8 v8 = *(const short8*)&src[(y << 7) + x0];
    float vs[8], s8 = 0.f;
#pragma unroll
    for (int u = 0; u < 8; u++) { vs[u] = bs2f(v8[u]); s8 += vs[u]; }
    a9[0] += s8;
    int ri = (y == 0) ? 0 : (y == 1) ? 1 : (y == 126) ? 2 : (y == 127) ? 3 : -1;
    if (ri >= 0) a9[1 + ri] += s8;
    if (x0 == 0)   { a9[5] += vs[0]; a9[6] += vs[1]; }
    if (x0 == 120) { a9[7] += vs[6]; a9[8] += vs[7]; }
    if (ri >= 0) {
      if (x0 == 0)   { sc[ri * 4 + 0] = vs[0]; sc[ri * 4 + 1] = vs[1]; }
      if (x0 == 120) { sc[ri * 4 + 2] = vs[6]; sc[ri * 4 + 3] = vs[7]; }
    }
  }
#pragma unroll
  for (int q = 0; q < 9; q++)
#pragma unroll
    for (int o = 32; o; o >>= 1) a9[q] += __shfl_xor(a9[q], o);
  const int w = t >> 6;
  if ((t & 63) == 0)
#pragma unroll
    for (int q = 0; q < 9; q++) red[w][q] = a9[q];
  __syncthreads();
  if (t == 0) {
    float s9[9];
#pragma unroll
    for (int q = 0; q < 9; q++) s9[q] = red[0][q] + red[1][q] + red[2][q] + red[3][q];
    const float T = s9[0];
    float R[4] = {s9[1], s9[2], s9[3], s9[4]};
    const float C0 = s9[5], C1 = s9[6], C126 = s9[7], C127 = s9[8];
    float rs[4][3];   // rowshift[ri][dxi]
#pragma unroll
    for (int ri = 0; ri < 4; ri++) {
      rs[ri][0] = R[ri] - sc[ri * 4 + 3] + sc[ri * 4 + 1];
      rs[ri][1] = R[ri];
      rs[ri][2] = R[ri] - sc[ri * 4 + 0] + sc[ri * 4 + 2];
    }
    float A3[3] = {T - C127 + C1, T, T - C0 + C126};
#pragma unroll
    for (int dx = 0; dx < 3; dx++) {
      Tsum[blockIdx.x * 9 + 0 * 3 + dx] = A3[dx] - rs[3][dx] + rs[1][dx];
      Tsum[blockIdx.x * 9 + 1 * 3 + dx] = A3[dx];
      Tsum[blockIdx.x * 9 + 2 * 3 + dx] = A3[dx] - rs[0][dx] + rs[2][dx];
    }
  }
}

// ================= QCO tail (per batch, 64 threads) =================
__global__ __launch_bounds__(64) void k_qco(
    const float* __restrict__ Tsum, const float* __restrict__ w1,
    const float* __restrict__ scaw, const float* __restrict__ scab,
    const float* __restrict__ t1w, const float* __restrict__ t1b,
    const float* __restrict__ t2w, const float* __restrict__ t2b,
    float* __restrict__ attb)
{
  const int b = blockIdx.x, c = threadIdx.x;
  __shared__ float sm[64], sxq[64], scat[128], sh1[64];
  float acc = 0.f;
  for (int j = 0; j < 64; j++) {
#pragma unroll
    for (int tap = 0; tap < 9; tap++)
      acc = fmaf(w1[(c * 64 + j) * 9 + tap], Tsum[(b * 64 + j) * 9 + tap], acc);
  }
  sm[c] = acc * (1.f / 16384.f);
  __syncthreads();
  float xa = scab[c];
  for (int j = 0; j < 64; j++) xa = fmaf(scaw[c * 64 + j], sm[j], xa);
  sxq[c] = xa;
  __syncthreads();
  float mn = xa, mx = xa;
#pragma unroll
  for (int o = 32; o; o >>= 1) {
    mn = fminf(mn, __shfl_xor(mn, o));
    mx = fmaxf(mx, __shfl_xor(mx, o));
  }
  float inter = (mx - mn) * (1.f / 64.f);
  float ql = (2.f * c + 1.f) / 128.f * (mx - mn) + mn;
  float sta = 0.f;
  for (int j = 0; j < 64; j++) {
    float q = 1.f - fabsf(ql - sxq[j]);
    sta += (q > 1.f - inter) ? q : 0.f;
  }
  float tot = sta;
#pragma unroll
  for (int o = 32; o; o >>= 1) tot += __shfl_xor(tot, o);
  sta = sta / fmaxf(tot, 1e-30f);
  scat[c] = sta; scat[64 + c] = xa;
  __syncthreads();
  float h = t1b[c];
  for (int j = 0; j < 128; j++) h = fmaf(t1w[c * 128 + j], scat[j], h);
  h = fmaxf(h, 0.f);
  sh1[c] = h;
  __syncthreads();
  float o2 = t2b[c];
  for (int j = 0; j < 64; j++) o2 = fmaf(t2w[c * 64 + j], sh1[j], o2);
  attb[b * 64 + c] = fmaxf(o2, 0.f);
}

// ================= MFMA fused double-FF (register residual + in-reg LN) =================
// Block: 128 px x 64 ch; wave wv owns px [wv*32, wv*32+32).
__global__ __launch_bounds__(256) void k_ffm2(const float* __restrict__ out1pm,
    const float* g1, const float* be1, const float* w11, const float* b11,
    const float* w12, const float* b12,
    const float* g2, const float* be2, const float* w21, const float* b21,
    const float* w22, const float* b22,
    float* __restrict__ outp)
{
  __shared__ short sW4[4][64][72];
  __shared__ short sy[128][72];
  __shared__ float spar[8][64];

  const int t = threadIdx.x, lane = t & 63, wv = t >> 6;
  const int gp0 = blockIdx.x * 128;
  const int b = gp0 >> 14, p0 = gp0 & 16383;
  const int chq = ((lane >> 4) << 2);

  for (int idx = t; idx < 4096; idx += 256) {
    int oc = idx >> 6, k = idx & 63;
    sW4[0][oc][k] = f2bs(w11[idx]);
    sW4[1][oc][k] = f2bs(w12[idx]);
    sW4[2][oc][k] = f2bs(w21[idx]);
    sW4[3][oc][k] = f2bs(w22[idx]);
  }
  if (t < 64) {
    spar[0][t] = g1[t]; spar[1][t] = be1[t]; spar[2][t] = b11[t]; spar[3][t] = b12[t];
    spar[4][t] = g2[t]; spar[5][t] = be2[t]; spar[6][t] = b21[t]; spar[7][t] = b22[t];
  }
  // residual v in registers: vv[m][n] -> ch m*16+chq+0..3, px wv*32+n*16+(lane&15)
  float4 vv[4][2];
#pragma unroll
  for (int m = 0; m < 4; m++)
#pragma unroll
    for (int n = 0; n < 2; n++) {
      const int px = p0 + wv * 32 + n * 16 + (lane & 15);
      vv[m][n] = *(const float4*)&out1pm[((size_t)(b * 16384 + px)) * 64 + m * 16 + chq];
    }
  __syncthreads();

  const f32x4 zero = {0.f, 0.f, 0.f, 0.f};
  f32x4 acc[4][2];

#define LN_REG(SRCV, GI, BI)                                                     \
  {                                                                              \
    _Pragma("unroll")                                                            \
    for (int n = 0; n < 2; n++) {                                                \
      float s1 = 0.f, s2 = 0.f;                                                  \
      _Pragma("unroll")                                                          \
      for (int m = 0; m < 4; m++)                                                \
        _Pragma("unroll")                                                        \
        for (int r = 0; r < 4; r++) {                                            \
          float vx = (&SRCV[m][n].x)[r];                                         \
          s1 += vx; s2 += vx * vx;                                               \
        }                                                                        \
      s1 += __shfl_xor(s1, 16); s1 += __shfl_xor(s1, 32);                        \
      s2 += __shfl_xor(s2, 16); s2 += __shfl_xor(s2, 32);                        \
      float mu = s1 * (1.f / 64.f);                                              \
      float var = fmaxf(s2 * (1.f / 64.f) - mu * mu, 0.f);                       \
      float rstd = 1.f / sqrtf(var + 1e-5f);                                     \
      const int pxl = wv * 32 + n * 16 + (lane & 15);                            \
      _Pragma("unroll")                                                          \
      for (int m = 0; m < 4; m++) {                                              \
        short4v ss;                                                              \
        _Pragma("unroll")                                                        \
        for (int r = 0; r < 4; r++) {                                            \
          int ch = m * 16 + chq + r;                                             \
          ss[r] = f2bs(((&SRCV[m][n].x)[r] - mu) * rstd * spar[GI][ch] + spar[BI][ch]); \
        }                                                                        \
        *(short4v*)&sy[pxl][m * 16 + chq] = ss;                                  \
      }                                                                          \
    }                                                                            \
  }

#define MM_STAGE(SIDX)                                                           \
  {                                                                              \
    _Pragma("unroll")                                                            \
    for (int m = 0; m < 4; m++) { acc[m][0] = zero; acc[m][1] = zero; }          \
    _Pragma("unroll")                                                            \
    for (int kk = 0; kk < 2; kk++) {                                             \
      const int kb = kk * 32 + (lane >> 4) * 8;                                  \
      bf8v bfr0 = *(const bf8v*)&sy[wv * 32 + (lane & 15)][kb];                  \
      bf8v bfr1 = *(const bf8v*)&sy[wv * 32 + 16 + (lane & 15)][kb];             \
      _Pragma("unroll")                                                          \
      for (int m = 0; m < 4; m++) {                                              \
        bf8v afr = *(const bf8v*)&sW4[SIDX][m * 16 + (lane & 15)][kb];           \
        acc[m][0] = MFMA16(afr, bfr0, acc[m][0]);                                \
        acc[m][1] = MFMA16(afr, bfr1, acc[m][1]);                                \
      }                                                                          \
    }                                                                            \
  }

  // LN1 -> sy
  LN_REG(vv, 0, 1);
  __syncthreads();
  // stage1: h = leaky(W11 @ yn + b11) -> sy
  MM_STAGE(0);
#pragma unroll
  for (int m = 0; m < 4; m++) {
#pragma unroll
    for (int n = 0; n < 2; n++) {
      const int pxl = wv * 32 + n * 16 + (lane & 15);
      short4v ss;
#pragma unroll
      for (int r = 0; r < 4; r++) {
        float h = acc[m][n][r] + spar[2][m * 16 + chq + r];
        h = h > 0.f ? h : 0.01f * h;
        ss[r] = f2bs(h);
      }
      *(short4v*)&sy[pxl][m * 16 + chq] = ss;
    }
  }
  __syncthreads();
  // stage2: o2 = W12 @ h + b12 + v  (registers)
  MM_STAGE(1);
  float4 o2v[4][2];
#pragma unroll
  for (int m = 0; m < 4; m++)
#pragma unroll
    for (int n = 0; n < 2; n++)
#pragma unroll
      for (int r = 0; r < 4; r++)
        (&o2v[m][n].x)[r] = acc[m][n][r] + spar[3][m * 16 + chq + r] + (&vv[m][n].x)[r];
  // LN2 -> sy
  LN_REG(o2v, 4, 5);
  __syncthreads();
  // stage3: h2 = leaky(W21 @ yn2 + b21) -> sy
  MM_STAGE(2);
#pragma unroll
  for (int m = 0; m < 4; m++) {
#pragma unroll
    for (int n = 0; n < 2; n++) {
      const int pxl = wv * 32 + n * 16 + (lane & 15);
      short4v ss;
#pragma unroll
      for (int r = 0; r < 4; r++) {
        float h = acc[m][n][r] + spar[6][m * 16 + chq + r];
        h = h > 0.f ? h : 0.01f * h;
        ss[r] = f2bs(h);
      }
      *(short4v*)&sy[pxl][m * 16 + chq] = ss;
    }
  }
  __syncthreads();
  // stage4: out = W22 @ h2 + b22 + v -> d_out (NCHW f32)
  MM_STAGE(3);
#pragma unroll
  for (int m = 0; m < 4; m++)
#pragma unroll
    for (int n = 0; n < 2; n++) {
      const int pxl = wv * 32 + n * 16 + (lane & 15);
#pragma unroll
      for (int r = 0; r < 4; r++) {
        const int ch = m * 16 + chq + r;
        outp[(((size_t)(b * 64 + ch)) << 14) + p0 + pxl] =
            acc[m][n][r] + spar[7][ch] + (&vv[m][n].x)[r];
      }
    }
#undef LN_REG
#undef MM_STAGE
}

// ================= launcher =================
extern "C" void kernel_launch(void* const* d_in, const int* in_sizes, int n_in,
                              void* d_out, int out_size, void* d_ws, size_t ws_size,
                              hipStream_t stream)
{
  if (ws_size < WS_BYTES) return;
  char* ws = (char*)d_ws;

  const float* x       = (const float*)d_in[0];
  const float* w_down  = (const float*)d_in[1];
  const float* w_mid   = (const float*)d_in[2];
  const float* w_up    = (const float*)d_in[3];
  const float* wq_l    = (const float*)d_in[4];
  const float* wk_m    = (const float*)d_in[5];
  const float* wv_m    = (const float*)d_in[6];
  const float* wq_h    = (const float*)d_in[7];
  const float* rescale = (const float*)d_in[8];
  const float* w_proj_l= (const float*)d_in[9];
  const float* b_proj_l= (const float*)d_in[10];
  const float* w_proj_h= (const float*)d_in[11];
  const float* b_proj_h= (const float*)d_in[12];
  const float* qco_w1  = (const float*)d_in[13];
  const float* qsca_w  = (const float*)d_in[14];
  const float* qsca_b  = (const float*)d_in[15];
  const float* qt1_w   = (const float*)d_in[16];
  const float* qt1_b   = (const float*)d_in[17];
  const float* qt2_w   = (const float*)d_in[18];
  const float* qt2_b   = (const float*)d_in[19];
  const float* rsp_w1  = (const float*)d_in[20];
  const float* rsp_pr  = (const float*)d_in[21];
  const float* rsp_w2  = (const float*)d_in[22];
  const float* c31_w1  = (const float*)d_in[23];
  const float* c31_pr  = (const float*)d_in[24];
  const float* c31_w2  = (const float*)d_in[25];
  const float* c31_w3  = (const float*)d_in[26];
  const float* ln1_g   = (const float*)d_in[27];
  const float* ln1_b   = (const float*)d_in[28];
  const float* ff1_w1  = (const float*)d_in[29];
  const float* ff1_b1  = (const float*)d_in[30];
  const float* ff1_w2  = (const float*)d_in[31];
  const float* ff1_b2  = (const float*)d_in[32];
  const float* ln2_g   = (const float*)d_in[33];
  const float* ln2_b   = (const float*)d_in[34];
  const float* ff2_w1  = (const float*)d_in[35];
  const float* ff2_b1  = (const float*)d_in[36];
  const float* ff2_w2  = (const float*)d_in[37];
  const float* ff2_b2  = (const float*)d_in[38];

  bf16*  zbf   = (bf16*)(ws + OFF_ZBF);
  bf16*  wtq   = (bf16*)(ws + OFF_WTQ);
  bf16*  wtr1  = (bf16*)(ws + OFF_WTR1);
  bf16*  wtr2  = (bf16*)(ws + OFF_WTR2);
  bf16*  wtc1  = (bf16*)(ws + OFF_WTC1);
  bf16*  wtf   = (bf16*)(ws + OFF_WTF);
  float* G     = (float*)(ws + OFF_G);
  float* gpart = (float*)(ws + OFF_GPART);
  float* T1    = (float*)(ws + OFF_T1);
  float* UL    = (float*)(ws + OFF_UL);
  float* UK    = (float*)(ws + OFF_UK);
  float* T1H   = (float*)(ws + OFF_T1H);
  float* UH    = (float*)(ws + OFF_UH);
  float* norms = (float*)(ws + OFF_NORMS);
  float* attL  = (float*)(ws + OFF_ATTL);
  float* attH  = (float*)(ws + OFF_ATTH);
  float* WeL   = (float*)(ws + OFF_WEL);
  float* WeH   = (float*)(ws + OFF_WEH);
  bf16*  acatb = (bf16*)(ws + OFF_ACATB);
  float* tsum  = (float*)(ws + OFF_TSUM);
  float* attb  = (float*)(ws + OFF_ATTB);
  bf16*  hcatb = (bf16*)(ws + OFF_HCATB);
  short* hcatT = (short*)(ws + OFF_HCATT);   // aliases gpart (dead after k_gred)
  short* midb  = (short*)(ws + OFF_MIDB);
  short* houtb = (short*)(ws + OFF_HOUTB);
  float* out1  = (float*)(ws + OFF_OUT1);
  short* xt    = (short*)(ws + OFF_XT);

  // 0) prep
  k_transp<<<dim3(256, 1, 2), 256, 0, stream>>>(x, xt);
  k_prep_all<<<dim3(1728), 256, 0, stream>>>(w_down, w_mid, w_up, rsp_w1, rsp_w2, c31_w1,
                                             wtq, wtr1, wtr2, wtc1);
  k_wfoldb<<<dim3(144), 256, 0, stream>>>(c31_w3, c31_w2, wtf);

  // 1) fused QKV conv 64->384 -> Z (NCHW bf16)
  k_convq<<<dim3(128, 3, 2), 256, 0, stream>>>(xt, (const short*)wtq, zbf);

  // 2) Gram + reduce
  k_gramm<<<dim3(9, 16, 2), 256, 0, stream>>>((const short*)zbf, gpart);
  k_gred<<<dim3(1152), 256, 0, stream>>>(gpart, G);

  // QCO tap sums (needs only Z)
  k_tsum2<<<dim3(128), 256, 0, stream>>>(zbf, tsum);

  // 3) attention solve on Gram blocks (fused 5-job GEMM)
  Jobs5 J5;
  J5.A[0] = wq_l;  J5.B[0] = G + 64;              J5.C[0] = T1;  J5.K[0] = 64;  J5.lda[0] = 64;  J5.ldb[0] = 384; J5.ldc[0] = 128; J5.sB[0] = 147456; J5.sC[0] = 32768;  J5.nx[0] = 8;
  J5.A[1] = wq_l;  J5.B[1] = G;                   J5.C[1] = UL;  J5.K[1] = 64;  J5.lda[1] = 64;  J5.ldb[1] = 384; J5.ldc[1] = 64;  J5.sB[1] = 147456; J5.sC[1] = 16384;  J5.nx[1] = 4;
  J5.A[2] = wk_m;  J5.B[2] = G + 64 * 384 + 64;   J5.C[2] = UK;  J5.K[2] = 128; J5.lda[2] = 128; J5.ldb[2] = 384; J5.ldc[2] = 128; J5.sB[2] = 147456; J5.sC[2] = 65536;  J5.nx[2] = 8;
  J5.A[3] = wq_h;  J5.B[3] = G + 192 * 384 + 64;  J5.C[3] = T1H; J5.K[3] = 192; J5.lda[3] = 192; J5.ldb[3] = 384; J5.ldc[3] = 128; J5.sB[3] = 147456; J5.sC[3] = 98304;  J5.nx[3] = 8;
  J5.A[4] = wq_h;  J5.B[4] = G + 192 * 384 + 192; J5.C[4] = UH;  J5.K[4] = 192; J5.lda[4] = 192; J5.ldb[4] = 384; J5.ldc[4] = 192; J5.sB[4] = 147456; J5.sC[4] = 147456; J5.nx[4] = 12;
  J5.b0[0] = 0; J5.b0[1] = 128; J5.b0[2] = 192; J5.b0[3] = 448; J5.b0[4] = 832; J5.b0[5] = 1408;
  k_sgemm5<<<dim3(1408, 2), 256, 0, stream>>>(J5);

  k_norms<<<dim3(12), 256, 0, stream>>>(UL, UK, UH, wq_l, wk_m, wq_h, norms);
  k_qco<<<dim3(2), 64, 0, stream>>>(tsum, qco_w1, qsca_w, qsca_b, qt1_w, qt1_b, qt2_w, qt2_b, attb);
  k_attn<<<dim3(8, 4, 2), 256, 0, stream>>>(T1, T1H, wk_m, norms, rescale, attL, attH);
  k_weff<<<dim3(8, 2, 2), 256, 0, stream>>>(attL, attH, wv_m, WeL, WeH);

  Jobs2 J2;
  J2.A[0] = w_proj_l; J2.B[0] = WeL; J2.K[0] = 256; J2.lda[0] = 256; J2.sB[0] = 32768; J2.nx[0] = 8; J2.co[0] = 0;
  J2.A[1] = w_proj_h; J2.B[1] = WeH; J2.K[1] = 768; J2.lda[1] = 768; J2.sB[1] = 98304; J2.nx[1] = 8; J2.co[1] = 8192;
  J2.b0[0] = 0; J2.b0[1] = 32; J2.b0[2] = 128;
  k_sgemm2b<<<dim3(128, 2), 256, 0, stream>>>(J2, acatb);

  // 4) per-pixel linear map -> Hcat (view-quirk LINEAR layout)
  k_pixm<<<dim3(256, 4, 2), 256, 0, stream>>>((const short*)zbf, (const short*)acatb,
                                              b_proj_l, b_proj_h, hcatb);

  // 4b) view-quirk: Hcat linear == NCHW [256][16384]; transpose to px-major for conv
  k_transph<<<dim3(256, 4, 2), 256, 0, stream>>>((const short*)hcatb, hcatT);

  // 5) ReshapeBlock: 256->64 (+prelu) then 64->64
  k_conv64<1><<<dim3(128, 2, 2), 256, 0, stream>>>(
      hcatT, 256, 4194304L, 256,
      (const short*)wtr1, midb, nullptr, rsp_pr, nullptr, nullptr, nullptr);
  k_conv64<0><<<dim3(128, 2, 2), 256, 0, stream>>>(
      midb, 64, 1048576L, 64,
      (const short*)wtr2, houtb, nullptr, nullptr, nullptr, nullptr, nullptr);

  // 7) Conv3_1 (+prelu) then folded conv + final combine -> out1 (px-major f32)
  k_conv64<1><<<dim3(128, 2, 2), 256, 0, stream>>>(
      houtb, 64, 1048576L, 64,
      (const short*)wtc1, midb, nullptr, c31_pr, nullptr, nullptr, nullptr);
  k_conv64<2><<<dim3(128, 2, 2), 256, 0, stream>>>(
      midb, 64, 1048576L, 64,
      (const short*)wtf, nullptr, out1, nullptr, houtb, attb, x);

  // 8) fused double-FF -> d_out (NCHW f32)
  k_ffm2<<<dim3(256), 256, 0, stream>>>(out1,
      ln1_g, ln1_b, ff1_w1, ff1_b1, ff1_w2, ff1_b2,
      ln2_g, ln2_b, ff2_w1, ff2_b1, ff2_w2, ff2_b2,
      (float*)d_out);
}

// Round 9
// 305.699 us; speedup vs baseline: 4.1830x; 1.1316x over previous
//
#include <hip/hip_runtime.h>
#include <hip/hip_bf16.h>
#include <stdint.h>

typedef __hip_bfloat16 bf16;
typedef __attribute__((ext_vector_type(8))) __bf16 bf8v;
typedef __attribute__((ext_vector_type(8))) short short8;
typedef __attribute__((ext_vector_type(4))) short short4v;
typedef __attribute__((ext_vector_type(4))) float f32x4;
#define DEVINL __device__ __forceinline__
#define MFMA16(a,b,c) __builtin_amdgcn_mfma_f32_16x16x32_bf16((a),(b),(c),0,0,0)

DEVINL short f2bs(float f) { bf16 h = __float2bfloat16(f); return *reinterpret_cast<short*>(&h); }
DEVINL float bs2f(short s) { bf16 h = *reinterpret_cast<bf16*>(&s); return __bfloat162float(h); }

// ---------------- problem dims ----------------
// B=2, C=64, H=W=128, n=16384, HEADS=8, DH=32. All device I/O buffers are f32.

// ---------------- workspace layout (BYTE offsets) ----------------
static const size_t OFF_ZBF   = 0;          // [2][384][16384] bf16 (QKV conv out, NCHW)
static const size_t OFF_WTQ   = 29360128;   // [9][384][64] bf16
static const size_t OFF_WTR1  = 29802496;   // [9][64][256] bf16
static const size_t OFF_WTR2  = 30097408;   // [9][64][64] bf16
static const size_t OFF_WTC1  = 30171136;   // [9][64][64] bf16
static const size_t OFF_WTF   = 30244864;   // [9][64][64] bf16 (folded c31 w3@w2)
static const size_t OFF_G     = 30466048;   // [2][384][384] f32
static const size_t OFF_T1    = 41082880;   // [2][256][128] f32
static const size_t OFF_UL    = 41345024;   // [2][256][64] f32
static const size_t OFF_UK    = 41476096;   // [2][512][128] f32
static const size_t OFF_T1H   = 42000384;   // [2][768][128] f32
static const size_t OFF_UH    = 42786816;   // [2][768][192] f32
static const size_t OFF_NORMS = 43966464;   // [2][1536] f32
static const size_t OFF_ATTL  = 43978752;   // [2][8][32][64] f32
static const size_t OFF_ATTH  = 44109824;   // [2][8][96][64] f32
static const size_t OFF_WEL   = 44503040;   // [2][256][128] f32
static const size_t OFF_WEH   = 44765184;   // [2][768][128] f32
static const size_t OFF_ACATB = 45813760;   // [2][256][128] bf16
static const size_t OFF_TSUM  = 45944832;   // [2][64][9] f32
static const size_t OFF_ATTB  = 45949440;   // [2][64] f32
static const size_t OFF_HCATB = 45949952;   // [2][4194304] bf16 (view-quirk LINEAR layout)
static const size_t OFF_MIDB  = 62727168;   // [2][16384][64] bf16 (px-major)
static const size_t OFF_HOUTB = 66921472;   // [2][16384][64] bf16 (px-major)
static const size_t OFF_OUT1  = 71115776;   // [2][16384][64] f32 (px-major)
static const size_t OFF_GPART = 79504384;   // [16][2][384][384] f32 ; ALSO (later) hcatT
static const size_t OFF_HCATT = 79504384;   // [2][16384][256] bf16 (aliases GPART, dead by then)
static const size_t OFF_XT    = 98378752;   // [2][16384][64] bf16 (x transposed)
static const size_t WS_BYTES  = 102573056;

// ================= prep kernels =================
// x [b][64][16384] f32 -> xt [b][16384][64] bf16
__global__ __launch_bounds__(256) void k_transp(const float* __restrict__ x,
                                                short* __restrict__ xt) {
  __shared__ short sT[64][72];
  const int t = threadIdx.x, b = blockIdx.z, p0 = blockIdx.x * 64;
  for (int i = t; i < 1024; i += 256) {
    int c = i >> 4, p4 = (i & 15) * 4;
    float4 g = *(const float4*)&x[(((size_t)(b * 64 + c)) << 14) + p0 + p4];
    sT[p4 + 0][c] = f2bs(g.x);
    sT[p4 + 1][c] = f2bs(g.y);
    sT[p4 + 2][c] = f2bs(g.z);
    sT[p4 + 3][c] = f2bs(g.w);
  }
  __syncthreads();
  for (int i = t; i < 512; i += 256) {
    int p = i >> 3, co = (i & 7) * 8;
    *(short8*)&xt[((((size_t)b << 14) + p0 + p)) * 64 + co] = *(short8*)&sT[p][co];
  }
}

// hcat LINEAR (quirk view = NCHW [b][256][16384]) bf16 -> hcatT [b][16384][256] bf16
__global__ __launch_bounds__(256) void k_transph(const short* __restrict__ hc,
                                                 short* __restrict__ ht) {
  __shared__ short sT[64][72];
  const int t = threadIdx.x, b = blockIdx.z, p0 = blockIdx.x * 64, c0 = blockIdx.y * 64;
  for (int i = t; i < 512; i += 256) {
    int c = i >> 3, qo = (i & 7) * 8;
    short8 v = *(const short8*)&hc[(((size_t)(b * 256 + c0 + c)) << 14) + p0 + qo];
#pragma unroll
    for (int u = 0; u < 8; u++) sT[qo + u][c] = v[u];
  }
  __syncthreads();
  for (int i = t; i < 512; i += 256) {
    int q = i >> 3, co = (i & 7) * 8;
    *(short8*)&ht[((size_t)(b * 16384 + p0 + q)) * 256 + c0 + co] = *(short8*)&sT[q][co];
  }
}

// fused weight transforms -> [tap][oc][ic] bf16
__global__ void k_prep_all(const float* __restrict__ wd, const float* __restrict__ wm,
                           const float* __restrict__ wu, const float* __restrict__ rw1,
                           const float* __restrict__ rw2, const float* __restrict__ cw1,
                           bf16* __restrict__ wtq, bf16* __restrict__ wtr1,
                           bf16* __restrict__ wtr2, bf16* __restrict__ wtc1) {
  int i = blockIdx.x * 256 + threadIdx.x;
  if (i < 221184) {
    int tap = i / 24576, r = i % 24576, oc = r >> 6, ic = r & 63;
    float v;
    if (oc < 64)       v = wd[(oc * 64 + ic) * 9 + tap];
    else if (oc < 192) v = wm[((oc - 64) * 64 + ic) * 9 + tap];
    else               v = wu[((oc - 192) * 64 + ic) * 9 + tap];
    wtq[i] = __float2bfloat16(v);
  } else if (i < 368640) {
    int j = i - 221184;
    int tap = j / 16384, r = j % 16384, oc = r >> 8, ic = r & 255;
    wtr1[j] = __float2bfloat16(rw1[(oc * 256 + ic) * 9 + tap]);
  } else if (i < 405504) {
    int j = i - 368640;
    int tap = j / 4096, r = j % 4096, oc = r >> 6, ic = r & 63;
    wtr2[j] = __float2bfloat16(rw2[(oc * 64 + ic) * 9 + tap]);
  } else if (i < 442368) {
    int j = i - 405504;
    int tap = j / 4096, r = j % 4096, oc = r >> 6, ic = r & 63;
    wtc1[j] = __float2bfloat16(cw1[(oc * 64 + ic) * 9 + tap]);
  }
}

// wtf[tap][o][ic] = bf16( sum_m c31_w3[o][m] * c31_w2[m][ic][tap] )
__global__ void k_wfoldb(const float* __restrict__ w3, const float* __restrict__ w2,
                         bf16* __restrict__ wtf) {
  int i = blockIdx.x * 256 + threadIdx.x;
  if (i >= 36864) return;
  int tap = i / 4096, r = i % 4096, o = r >> 6, ic = r & 63;
  float s = 0.f;
  for (int m = 0; m < 64; m++)
    s = fmaf(w3[o * 64 + m], w2[(m * 64 + ic) * 9 + tap], s);
  wtf[i] = __float2bfloat16(s);
}

// ================= QKV conv 64->384 (zero pad), direct-A MFMA =================
__global__ __launch_bounds__(256) void k_convq(
    const short* __restrict__ xt, const short* __restrict__ wtq,
    bf16* __restrict__ zbf)
{
  __shared__ short sX[3][130][72];
  const int t = threadIdx.x, lane = t & 63, wv = t >> 6;
  const int y = blockIdx.x, ocg = blockIdx.y, b = blockIdx.z;

  for (int i = t; i < 3120; i += 256) {
    int col = i % 130, rr = i / 130, row = rr % 3, ko = rr / 3;
    int gy = y + row - 1, gx = col - 1;
    short8 vv;
    if ((gy >= 0) & (gy < 128) & (gx >= 0) & (gx < 128)) {
      vv = *(const short8*)&xt[((size_t)b * 1048576 + (size_t)((gy << 7) + gx) * 64) + ko * 8];
    } else {
#pragma unroll
      for (int u = 0; u < 8; u++) vv[u] = 0;
    }
    *(short8*)&sX[row][col][ko * 8] = vv;
  }
  __syncthreads();

  const f32x4 zero = {0.f, 0.f, 0.f, 0.f};
  f32x4 acc[2][8];
#pragma unroll
  for (int m = 0; m < 2; m++)
#pragma unroll
    for (int n = 0; n < 8; n++) acc[m][n] = zero;

#pragma unroll
  for (int tap = 0; tap < 9; tap++) {
    const int ky = tap / 3, kx = tap % 3;
#pragma unroll
    for (int kk = 0; kk < 2; kk++) {
      const int kb = kk * 32 + (lane >> 4) * 8;
      bf8v a0 = *(const bf8v*)&wtq[(size_t)((tap * 384 + ocg * 128 + wv * 32 + (lane & 15)) * 64) + kb];
      bf8v a1 = *(const bf8v*)&wtq[(size_t)((tap * 384 + ocg * 128 + wv * 32 + 16 + (lane & 15)) * 64) + kb];
#pragma unroll
      for (int n = 0; n < 8; n++) {
        bf8v bfr = *(const bf8v*)&sX[ky][n * 16 + (lane & 15) + kx][kb];
        acc[0][n] = MFMA16(a0, bfr, acc[0][n]);
        acc[1][n] = MFMA16(a1, bfr, acc[1][n]);
      }
    }
  }
#pragma unroll
  for (int m = 0; m < 2; m++) {
    const int oc0 = ocg * 128 + wv * 32 + m * 16 + ((lane >> 4) << 2);
#pragma unroll
    for (int n = 0; n < 8; n++) {
      const int px = n * 16 + (lane & 15);
#pragma unroll
      for (int r = 0; r < 4; r++)
        zbf[(((size_t)(b * 384 + oc0 + r)) << 14) + (y << 7) + px] = __float2bfloat16(acc[m][n][r]);
    }
  }
}

// ================= 3x3 reflect conv -> 64 out (direct-A MFMA, px-major IO) =================
// Block: 64 px (half row) x 64 oc; 4 waves, wave wv -> oc [wv*16, wv*16+16).
// in: px-major bf16 [b][16384][str].
// EPI: 0 plain->bf16 pm, 1 prelu->bf16 pm, 2 final(acc + hout*attb + x)->f32 pm
template<int EPI>
__global__ __launch_bounds__(256) void k_conv64(
    const short* __restrict__ in, int str, long bstride, int Cin,
    const short* __restrict__ Wt,
    short* __restrict__ outb, float* __restrict__ outf,
    const float* __restrict__ prelu_a,
    const short* __restrict__ houtpm, const float* __restrict__ attb,
    const float* __restrict__ x_nchw)
{
  __shared__ short sX[3][66][72];
  const int t = threadIdx.x, lane = t & 63, wv = t >> 6;
  const int y = blockIdx.x, x0 = blockIdx.y * 64, b = blockIdx.z;

  const f32x4 zero = {0.f, 0.f, 0.f, 0.f};
  f32x4 acc[4] = {zero, zero, zero, zero};

  for (int icb = 0; icb < Cin; icb += 64) {
    __syncthreads();
    for (int i = t; i < 1584; i += 256) {
      int col = i % 66, rr = i / 66, row = rr % 3, ko = rr / 3;
      int gy = y + row - 1, gx = x0 + col - 1;
      gy = gy < 0 ? 1 : (gy > 127 ? 126 : gy);
      gx = gx < 0 ? 1 : (gx > 127 ? 126 : gx);
      *(short8*)&sX[row][col][ko * 8] =
          *(const short8*)&in[(size_t)b * bstride + (size_t)((gy << 7) + gx) * str + icb + ko * 8];
    }
    __syncthreads();
#pragma unroll
    for (int tap = 0; tap < 9; tap++) {
      const int ky = tap / 3, kx = tap % 3;
#pragma unroll
      for (int kk = 0; kk < 2; kk++) {
        const int kb = kk * 32 + (lane >> 4) * 8;
        bf8v afr = *(const bf8v*)&Wt[(size_t)(tap * 64 + wv * 16 + (lane & 15)) * Cin + icb + kb];
#pragma unroll
        for (int n = 0; n < 4; n++) {
          bf8v bfr = *(const bf8v*)&sX[ky][n * 16 + (lane & 15) + kx][kb];
          acc[n] = MFMA16(afr, bfr, acc[n]);
        }
      }
    }
  }
  // epilogue: oc = wv*16 + (lane>>4)*4 + r ; px = x0 + n*16 + (lane&15)
  const int oc0 = wv * 16 + ((lane >> 4) << 2);
  const float aP = (EPI == 1) ? prelu_a[0] : 0.f;
#pragma unroll
  for (int n = 0; n < 4; n++) {
    const int gpx = (y << 7) + x0 + n * 16 + (lane & 15);
    if (EPI == 2) {
      short4v hv = *(const short4v*)&houtpm[((size_t)(b * 16384 + gpx)) * 64 + oc0];
      float4 av = *(const float4*)&attb[b * 64 + oc0];
      float4 o;
#pragma unroll
      for (int r = 0; r < 4; r++)
        (&o.x)[r] = acc[n][r] + bs2f(hv[r]) * (&av.x)[r] +
                    x_nchw[(((size_t)(b * 64 + oc0 + r)) << 14) + gpx];
      *(float4*)&outf[((size_t)(b * 16384 + gpx)) * 64 + oc0] = o;
    } else {
      short4v ss;
#pragma unroll
      for (int r = 0; r < 4; r++) {
        float v = acc[n][r];
        if (EPI == 1) v = v > 0.f ? v : aP * v;
        ss[r] = f2bs(v);
      }
      *(short4v*)&outb[((size_t)(b * 16384 + gpx)) * 64 + oc0] = ss;
    }
  }
}

// ================= Gram via MFMA: G[b] = Z Z^T (6 unique tile pairs + mirror) ========
__global__ __launch_bounds__(256) void k_gramm(const short* __restrict__ Z,
                                               float* __restrict__ Gp) {
  static const int map_i[6] = {0, 0, 0, 1, 1, 2};
  static const int map_j[6] = {0, 1, 2, 1, 2, 2};
  const int ti = map_i[blockIdx.x], tj = map_j[blockIdx.x];
  const int kc = blockIdx.y, b = blockIdx.z;
  __shared__ short sA[128][72];
  __shared__ short sB[128][72];
  const int t = threadIdx.x, lane = t & 63, wv = t >> 6;
  const int wo = wv & 1, wp = wv >> 1;
  const f32x4 zero = {0.f, 0.f, 0.f, 0.f};
  f32x4 acc[4][4];
#pragma unroll
  for (int m = 0; m < 4; m++)
#pragma unroll
    for (int n = 0; n < 4; n++) acc[m][n] = zero;
  const size_t zb = (size_t)b * 6291456;
  const int k0 = kc * 1024;
  for (int ks = 0; ks < 1024; ks += 64) {
    __syncthreads();
    for (int i = t; i < 1024; i += 256) {
      int r = i >> 3, ko = i & 7;
      *(short8*)&sA[r][ko * 8] =
          *(const short8*)&Z[zb + ((size_t)(ti * 128 + r) << 14) + k0 + ks + ko * 8];
      *(short8*)&sB[r][ko * 8] =
          *(const short8*)&Z[zb + ((size_t)(tj * 128 + r) << 14) + k0 + ks + ko * 8];
    }
    __syncthreads();
#pragma unroll
    for (int kk = 0; kk < 2; kk++) {
      const int kb = kk * 32 + (lane >> 4) * 8;
      bf8v bfr[4];
#pragma unroll
      for (int n = 0; n < 4; n++)
        bfr[n] = *(const bf8v*)&sB[wp * 64 + n * 16 + (lane & 15)][kb];
#pragma unroll
      for (int m = 0; m < 4; m++) {
        bf8v afr = *(const bf8v*)&sA[wo * 64 + m * 16 + (lane & 15)][kb];
#pragma unroll
        for (int n = 0; n < 4; n++)
          acc[m][n] = MFMA16(afr, bfr[n], acc[m][n]);
      }
    }
  }
  float* gp = Gp + ((size_t)(kc * 2 + b)) * 147456;
#pragma unroll
  for (int m = 0; m < 4; m++)
#pragma unroll
    for (int n = 0; n < 4; n++)
#pragma unroll
      for (int r = 0; r < 4; r++) {
        const int row = ti * 128 + wo * 64 + m * 16 + ((lane >> 4) << 2) + r;
        const int col = tj * 128 + wp * 64 + n * 16 + (lane & 15);
        float v = acc[m][n][r];
        gp[(size_t)row * 384 + col] = v;
        if (ti != tj) gp[(size_t)col * 384 + row] = v;
      }
}

__global__ void k_gred(const float* __restrict__ Gp, float* __restrict__ G) {
  int i = blockIdx.x * 256 + threadIdx.x;
  if (i >= 294912) return;
  int b = i / 147456, e = i % 147456;
  float s = 0.f;
#pragma unroll
  for (int c = 0; c < 16; c++) s += Gp[(size_t)(c * 2 + b) * 147456 + e];
  G[i] = s;
}

// ================= per-pixel map via MFMA (view-quirk LINEAR output) =================
__global__ __launch_bounds__(256) void k_pixm(
    const short* __restrict__ Z, const short* __restrict__ Acatb,
    const float* __restrict__ bl, const float* __restrict__ bh,
    bf16* __restrict__ hcat)
{
  const int p0 = blockIdx.x * 64, ocg = blockIdx.y, b = blockIdx.z;
  __shared__ short sA[64][136];
  __shared__ short sB[64][136];
  const int t = threadIdx.x, lane = t & 63, wv = t >> 6;
  for (int i = t; i < 1024; i += 256) {
    int oc = i >> 4, ko = i & 15;
    *(short8*)&sA[oc][ko * 8] =
        *(const short8*)&Acatb[((size_t)(b * 256 + ocg * 64 + oc)) * 128 + ko * 8];
  }
  for (int i = t; i < 1024; i += 256) {
    int px = i & 63, ko = i >> 6;
    short8 vv;
#pragma unroll
    for (int u = 0; u < 8; u++)
      vv[u] = Z[((size_t)(b * 384 + 64 + ko * 8 + u) << 14) + p0 + px];
    *(short8*)&sB[px][ko * 8] = vv;
  }
  __syncthreads();
  const f32x4 zero = {0.f, 0.f, 0.f, 0.f};
  f32x4 acc[4] = {zero, zero, zero, zero};
#pragma unroll
  for (int kk = 0; kk < 4; kk++) {
    const int kb = kk * 32 + (lane >> 4) * 8;
    bf8v afr = *(const bf8v*)&sA[wv * 16 + (lane & 15)][kb];
#pragma unroll
    for (int n = 0; n < 4; n++) {
      bf8v bfr = *(const bf8v*)&sB[n * 16 + (lane & 15)][kb];
      acc[n] = MFMA16(afr, bfr, acc[n]);
    }
  }
  const size_t hbase = (size_t)b * 4194304;
#pragma unroll
  for (int n = 0; n < 4; n++) {
    const int px = p0 + n * 16 + (lane & 15);
#pragma unroll
    for (int r = 0; r < 4; r++) {
      const int oc = ocg * 64 + wv * 16 + ((lane >> 4) << 2) + r;
      float v = acc[n][r] + (oc < 64 ? bl[oc] : bh[oc - 64]);
      size_t addr = (oc < 64) ? hbase + (size_t)px * 64 + oc
                              : hbase + 1048576 + (size_t)px * 192 + (oc - 64);
      hcat[addr] = __float2bfloat16(v);
    }
  }
}

// ================= fused small-GEMM chain (5 jobs): C = A[M,K]*B[K,N] =================
struct Jobs5 {
  const float* A[5]; const float* B[5]; float* C[5];
  int K[5]; int lda[5]; int ldb[5]; int ldc[5];
  long sB[5]; long sC[5];
  int nx[5]; int b0[6];
};

__global__ __launch_bounds__(256) void k_sgemm5(Jobs5 J) {
  __shared__ float sa[16][17];
  __shared__ float sb[16][17];
  const int bx = blockIdx.x, z = blockIdx.y;
  int j = 0;
  while (bx >= J.b0[j + 1]) j++;
  const int local = bx - J.b0[j];
  const int x = local % J.nx[j], y = local / J.nx[j];
  const int tx = threadIdx.x & 15, ty = threadIdx.x >> 4;
  const float* Ap = J.A[j];
  const float* Bp = J.B[j] + (size_t)z * J.sB[j];
  const int K = J.K[j], lda = J.lda[j], ldb = J.ldb[j];
  const int m = y * 16 + ty, n = x * 16 + tx;
  float acc = 0.f;
  for (int k0 = 0; k0 < K; k0 += 16) {
    sa[ty][tx] = Ap[(size_t)m * lda + k0 + tx];
    sb[ty][tx] = Bp[(size_t)(k0 + ty) * ldb + n];
    __syncthreads();
#pragma unroll
    for (int kk = 0; kk < 16; kk++) acc = fmaf(sa[ty][kk], sb[kk][tx], acc);
    __syncthreads();
  }
  J.C[j][(size_t)z * J.sC[j] + (size_t)m * J.ldc[j] + n] = acc;
}

// ================= proj GEMMs (2 jobs) -> bf16 Acat =================
struct Jobs2 {
  const float* A[2]; const float* B[2];
  int K[2]; int lda[2];
  long sB[2];
  int nx[2]; int b0[3]; int co[2];
};

__global__ __launch_bounds__(256) void k_sgemm2b(Jobs2 J, bf16* __restrict__ Cb) {
  __shared__ float sa[16][17];
  __shared__ float sb[16][17];
  const int bx = blockIdx.x, z = blockIdx.y;
  int j = (bx >= J.b0[1]) ? 1 : 0;
  const int local = bx - J.b0[j];
  const int x = local % J.nx[j], y = local / J.nx[j];
  const int tx = threadIdx.x & 15, ty = threadIdx.x >> 4;
  const float* Ap = J.A[j];
  const float* Bp = J.B[j] + (size_t)z * J.sB[j];
  const int K = J.K[j], lda = J.lda[j];
  const int m = y * 16 + ty, n = x * 16 + tx;
  float acc = 0.f;
  for (int k0 = 0; k0 < K; k0 += 16) {
    sa[ty][tx] = Ap[(size_t)m * lda + k0 + tx];
    sb[ty][tx] = Bp[(size_t)(k0 + ty) * 128 + n];
    __syncthreads();
#pragma unroll
    for (int kk = 0; kk < 16; kk++) acc = fmaf(sa[ty][kk], sb[kk][tx], acc);
    __syncthreads();
  }
  Cb[(size_t)z * 32768 + J.co[j] + (size_t)m * 128 + n] = __float2bfloat16(acc);
}

// ================= norms: one wave per row, coalesced + shuffle reduce =================
__global__ __launch_bounds__(256) void k_norms2(
    const float* __restrict__ UL, const float* __restrict__ UK,
    const float* __restrict__ UH,
    const float* __restrict__ wql, const float* __restrict__ wkm,
    const float* __restrict__ wqh, float* __restrict__ norms) {
  const int t = threadIdx.x, lane = t & 63;
  const int row = blockIdx.x * 4 + (t >> 6);   // 0..3071
  const int b = row >> 11 ? 1 : (row >= 1536 ? 1 : 0);
  const int r = row - b * 1536;
  const float* u; const float* wv; int K;
  if (r < 256)      { K = 64;  u = UL + (size_t)(b * 256 + r) * 64;          wv = wql + (size_t)r * 64; }
  else if (r < 768) { int e = r - 256; K = 128; u = UK + (size_t)(b * 512 + e) * 128; wv = wkm + (size_t)e * 128; }
  else              { int d = r - 768; K = 192; u = UH + (size_t)(b * 768 + d) * 192; wv = wqh + (size_t)d * 192; }
  float s = 0.f;
  for (int k = lane; k < K; k += 64) s = fmaf(u[k], wv[k], s);
#pragma unroll
  for (int o = 32; o; o >>= 1) s += __shfl_xor(s, o);
  if (lane == 0) norms[b * 1536 + r] = fmaxf(sqrtf(fmaxf(s, 0.f)), 1e-12f);
}

// ================= attention logits + softmax =================
__global__ __launch_bounds__(256) void k_attn(
    const float* __restrict__ T1, const float* __restrict__ T1H,
    const float* __restrict__ wkm, const float* __restrict__ norms,
    const float* __restrict__ rescale,
    float* __restrict__ attL, float* __restrict__ attH)
{
  const int h = blockIdx.x, cy = blockIdx.y, b = blockIdx.z;
  const int t = threadIdx.x;
  __shared__ float sK[64 * 129];
  __shared__ float sQ[32 * 129];
  __shared__ float sNk[64];
  const int isL = (cy == 0);
  const int rbase = isL ? 0 : (cy - 1) * 32;
  const float* TQ = isL ? (T1 + (size_t)(b * 256 + h * 32) * 128)
                        : (T1H + (size_t)(b * 768 + h * 96 + rbase) * 128);
  for (int idx = t; idx < 8192; idx += 256) {
    int e = idx >> 7, k = idx & 127;
    sK[e * 129 + k] = wkm[(size_t)(h * 64 + e) * 128 + k];
  }
  for (int idx = t; idx < 4096; idx += 256) {
    int r = idx >> 7, k = idx & 127;
    sQ[r * 129 + k] = TQ[(size_t)r * 128 + k];
  }
  if (t < 64) sNk[t] = norms[b * 1536 + 256 + h * 64 + t];
  __syncthreads();

  const int w = t >> 6, lane = t & 63;
  const float rs = rescale[h];
  for (int r = w; r < 32; r += 4) {
    float s = 0.f;
    for (int k = 0; k < 128; k++) s = fmaf(sQ[r * 129 + k], sK[lane * 129 + k], s);
    float nq = norms[b * 1536 + (isL ? (h * 32 + r) : (768 + h * 96 + rbase + r))];
    float logit = s / (nq * sNk[lane]) * rs;
    float m = logit;
#pragma unroll
    for (int o = 32; o; o >>= 1) m = fmaxf(m, __shfl_xor(m, o));
    float p = __expf(logit - m);
    float den = p;
#pragma unroll
    for (int o = 32; o; o >>= 1) den += __shfl_xor(den, o);
    float av = p / den;
    if (isL) attL[((size_t)(b * 8 + h) * 32 + r) * 64 + lane] = av;
    else     attH[((size_t)(b * 8 + h) * 96 + rbase + r) * 64 + lane] = av;
  }
}

// ================= Weff = attn @ wv (per head) =================
__global__ __launch_bounds__(256) void k_weff(
    const float* __restrict__ attL, const float* __restrict__ attH,
    const float* __restrict__ wvm,
    float* __restrict__ WeL, float* __restrict__ WeH)
{
  const int h = blockIdx.x, br = blockIdx.y, b = blockIdx.z;
  const int M = br ? 96 : 32;
  __shared__ float sAt[96 * 64];
  __shared__ float sV[64 * 132];
  const int t = threadIdx.x;
  const float* asrc = br ? attH + (size_t)(b * 8 + h) * 96 * 64
                         : attL + (size_t)(b * 8 + h) * 32 * 64;
  for (int idx = t; idx < M * 64; idx += 256) sAt[idx] = asrc[idx];
  for (int idx = t; idx < 8192; idx += 256) {
    int e = idx >> 7, k = idx & 127;
    sV[e * 132 + k] = wvm[(size_t)(h * 64 + e) * 128 + k];
  }
  __syncthreads();
  const int jg = t & 31, rw = t >> 5;
  float* dst = br ? WeH + (size_t)(b * 768 + h * 96) * 128
                  : WeL + (size_t)(b * 256 + h * 32) * 128;
  for (int r = rw; r < M; r += 8) {
    float4 acc = make_float4(0.f, 0.f, 0.f, 0.f);
    for (int e = 0; e < 64; e++) {
      float a = sAt[r * 64 + e];
      float4 v4 = *(const float4*)&sV[e * 132 + jg * 4];
      acc.x = fmaf(a, v4.x, acc.x);
      acc.y = fmaf(a, v4.y, acc.y);
      acc.z = fmaf(a, v4.z, acc.z);
      acc.w = fmaf(a, v4.w, acc.w);
    }
    *(float4*)&dst[(size_t)r * 128 + jg * 4] = acc;
  }
}

// ================= QCO tap sums, separable (one vectorized pass) =================
__global__ __launch_bounds__(256) void k_tsum2(const bf16* __restrict__ Z,
                                               float* __restrict__ Tsum) {
  const int c = blockIdx.x & 63, b = blockIdx.x >> 6;
  const bf16* src = Z + (((size_t)(b * 384 + c)) << 14);
  const int t = threadIdx.x;
  __shared__ float sc[16];      // corners e[ri][xi], ri,xi map {0,1,126,127}->0..3
  __shared__ float red[4][9];
  float a9[9] = {};             // tot, r0, r1, r126, r127, c0, c1, c126, c127
  for (int i = t; i < 2048; i += 256) {
    int y = i >> 4, x0 = (i & 15) * 8;
    short8 v8 = *(const short8*)&src[(y << 7) + x0];
    float vs[8], s8 = 0.f;
#pragma unroll
    for (int u = 0; u < 8; u++) { vs[u] = bs2f(v8[u]); s8 += vs[u]; }
    a9[0] += s8;
    int ri = (y == 0) ? 0 : (y == 1) ? 1 : (y == 126) ? 2 : (y == 127) ? 3 : -1;
    if (ri >= 0) a9[1 + ri] += s8;
    if (x0 == 0)   { a9[5] += vs[0]; a9[6] += vs[1]; }
    if (x0 == 120) { a9[7] += vs[6]; a9[8] += vs[7]; }
    if (ri >= 0) {
      if (x0 == 0)   { sc[ri * 4 + 0] = vs[0]; sc[ri * 4 + 1] = vs[1]; }
      if (x0 == 120) { sc[ri * 4 + 2] = vs[6]; sc[ri * 4 + 3] = vs[7]; }
    }
  }
#pragma unroll
  for (int q = 0; q < 9; q++)
#pragma unroll
    for (int o = 32; o; o >>= 1) a9[q] += __shfl_xor(a9[q], o);
  const int w = t >> 6;
  if ((t & 63) == 0)
#pragma unroll
    for (int q = 0; q < 9; q++) red[w][q] = a9[q];
  __syncthreads();
  if (t == 0) {
    float s9[9];
#pragma unroll
    for (int q = 0; q < 9; q++) s9[q] = red[0][q] + red[1][q] + red[2][q] + red[3][q];
    const float T = s9[0];
    float R[4] = {s9[1], s9[2], s9[3], s9[4]};
    const float C0 = s9[5], C1 = s9[6], C126 = s9[7], C127 = s9[8];
    float rs[4][3];   // rowshift[ri][dxi]
#pragma unroll
    for (int ri = 0; ri < 4; ri++) {
      rs[ri][0] = R[ri] - sc[ri * 4 + 3] + sc[ri * 4 + 1];
      rs[ri][1] = R[ri];
      rs[ri][2] = R[ri] - sc[ri * 4 + 0] + sc[ri * 4 + 2];
    }
    float A3[3] = {T - C127 + C1, T, T - C0 + C126};
#pragma unroll
    for (int dx = 0; dx < 3; dx++) {
      Tsum[blockIdx.x * 9 + 0 * 3 + dx] = A3[dx] - rs[3][dx] + rs[1][dx];
      Tsum[blockIdx.x * 9 + 1 * 3 + dx] = A3[dx];
      Tsum[blockIdx.x * 9 + 2 * 3 + dx] = A3[dx] - rs[0][dx] + rs[2][dx];
    }
  }
}

// ================= QCO tail (per batch, 64 threads) =================
__global__ __launch_bounds__(64) void k_qco(
    const float* __restrict__ Tsum, const float* __restrict__ w1,
    const float* __restrict__ scaw, const float* __restrict__ scab,
    const float* __restrict__ t1w, const float* __restrict__ t1b,
    const float* __restrict__ t2w, const float* __restrict__ t2b,
    float* __restrict__ attb)
{
  const int b = blockIdx.x, c = threadIdx.x;
  __shared__ float sm[64], sxq[64], scat[128], sh1[64];
  float acc = 0.f;
  for (int j = 0; j < 64; j++) {
#pragma unroll
    for (int tap = 0; tap < 9; tap++)
      acc = fmaf(w1[(c * 64 + j) * 9 + tap], Tsum[(b * 64 + j) * 9 + tap], acc);
  }
  sm[c] = acc * (1.f / 16384.f);
  __syncthreads();
  float xa = scab[c];
  for (int j = 0; j < 64; j++) xa = fmaf(scaw[c * 64 + j], sm[j], xa);
  sxq[c] = xa;
  __syncthreads();
  float mn = xa, mx = xa;
#pragma unroll
  for (int o = 32; o; o >>= 1) {
    mn = fminf(mn, __shfl_xor(mn, o));
    mx = fmaxf(mx, __shfl_xor(mx, o));
  }
  float inter = (mx - mn) * (1.f / 64.f);
  float ql = (2.f * c + 1.f) / 128.f * (mx - mn) + mn;
  float sta = 0.f;
  for (int j = 0; j < 64; j++) {
    float q = 1.f - fabsf(ql - sxq[j]);
    sta += (q > 1.f - inter) ? q : 0.f;
  }
  float tot = sta;
#pragma unroll
  for (int o = 32; o; o >>= 1) tot += __shfl_xor(tot, o);
  sta = sta / fmaxf(tot, 1e-30f);
  scat[c] = sta; scat[64 + c] = xa;
  __syncthreads();
  float h = t1b[c];
  for (int j = 0; j < 128; j++) h = fmaf(t1w[c * 128 + j], scat[j], h);
  h = fmaxf(h, 0.f);
  sh1[c] = h;
  __syncthreads();
  float o2 = t2b[c];
  for (int j = 0; j < 64; j++) o2 = fmaf(t2w[c * 64 + j], sh1[j], o2);
  attb[b * 64 + c] = fmaxf(o2, 0.f);
}

// ================= MFMA fused double-FF (register residual + in-reg LN) =================
// Block: 128 px x 64 ch; wave wv owns px [wv*32, wv*32+32).
__global__ __launch_bounds__(256) void k_ffm2(const float* __restrict__ out1pm,
    const float* g1, const float* be1, const float* w11, const float* b11,
    const float* w12, const float* b12,
    const float* g2, const float* be2, const float* w21, const float* b21,
    const float* w22, const float* b22,
    float* __restrict__ outp)
{
  __shared__ short sW4[4][64][72];
  __shared__ short sy[128][72];
  __shared__ float spar[8][64];

  const int t = threadIdx.x, lane = t & 63, wv = t >> 6;
  const int gp0 = blockIdx.x * 128;
  const int b = gp0 >> 14, p0 = gp0 & 16383;
  const int chq = ((lane >> 4) << 2);

  for (int idx = t; idx < 4096; idx += 256) {
    int oc = idx >> 6, k = idx & 63;
    sW4[0][oc][k] = f2bs(w11[idx]);
    sW4[1][oc][k] = f2bs(w12[idx]);
    sW4[2][oc][k] = f2bs(w21[idx]);
    sW4[3][oc][k] = f2bs(w22[idx]);
  }
  if (t < 64) {
    spar[0][t] = g1[t]; spar[1][t] = be1[t]; spar[2][t] = b11[t]; spar[3][t] = b12[t];
    spar[4][t] = g2[t]; spar[5][t] = be2[t]; spar[6][t] = b21[t]; spar[7][t] = b22[t];
  }
  // residual v in registers: vv[m][n] -> ch m*16+chq+0..3, px wv*32+n*16+(lane&15)
  float4 vv[4][2];
#pragma unroll
  for (int m = 0; m < 4; m++)
#pragma unroll
    for (int n = 0; n < 2; n++) {
      const int px = p0 + wv * 32 + n * 16 + (lane & 15);
      vv[m][n] = *(const float4*)&out1pm[((size_t)(b * 16384 + px)) * 64 + m * 16 + chq];
    }
  __syncthreads();

  const f32x4 zero = {0.f, 0.f, 0.f, 0.f};
  f32x4 acc[4][2];

#define LN_REG(SRCV, GI, BI)                                                     \
  {                                                                              \
    _Pragma("unroll")                                                            \
    for (int n = 0; n < 2; n++) {                                                \
      float s1 = 0.f, s2 = 0.f;                                                  \
      _Pragma("unroll")                                                          \
      for (int m = 0; m < 4; m++)                                                \
        _Pragma("unroll")                                                        \
        for (int r = 0; r < 4; r++) {                                            \
          float vx = (&SRCV[m][n].x)[r];                                         \
          s1 += vx; s2 += vx * vx;                                               \
        }                                                                        \
      s1 += __shfl_xor(s1, 16); s1 += __shfl_xor(s1, 32);                        \
      s2 += __shfl_xor(s2, 16); s2 += __shfl_xor(s2, 32);                        \
      float mu = s1 * (1.f / 64.f);                                              \
      float var = fmaxf(s2 * (1.f / 64.f) - mu * mu, 0.f);                       \
      float rstd = 1.f / sqrtf(var + 1e-5f);                                     \
      const int pxl = wv * 32 + n * 16 + (lane & 15);                            \
      _Pragma("unroll")                                                          \
      for (int m = 0; m < 4; m++) {                                              \
        short4v ss;                                                              \
        _Pragma("unroll")                                                        \
        for (int r = 0; r < 4; r++) {                                            \
          int ch = m * 16 + chq + r;                                             \
          ss[r] = f2bs(((&SRCV[m][n].x)[r] - mu) * rstd * spar[GI][ch] + spar[BI][ch]); \
        }                                                                        \
        *(short4v*)&sy[pxl][m * 16 + chq] = ss;                                  \
      }                                                                          \
    }                                                                            \
  }

#define MM_STAGE(SIDX)                                                           \
  {                                                                              \
    _Pragma("unroll")                                                            \
    for (int m = 0; m < 4; m++) { acc[m][0] = zero; acc[m][1] = zero; }          \
    _Pragma("unroll")                                                            \
    for (int kk = 0; kk < 2; kk++) {                                             \
      const int kb = kk * 32 + (lane >> 4) * 8;                                  \
      bf8v bfr0 = *(const bf8v*)&sy[wv * 32 + (lane & 15)][kb];                  \
      bf8v bfr1 = *(const bf8v*)&sy[wv * 32 + 16 + (lane & 15)][kb];             \
      _Pragma("unroll")                                                          \
      for (int m = 0; m < 4; m++) {                                              \
        bf8v afr = *(const bf8v*)&sW4[SIDX][m * 16 + (lane & 15)][kb];           \
        acc[m][0] = MFMA16(afr, bfr0, acc[m][0]);                                \
        acc[m][1] = MFMA16(afr, bfr1, acc[m][1]);                                \
      }                                                                          \
    }                                                                            \
  }

  // LN1 -> sy
  LN_REG(vv, 0, 1);
  __syncthreads();
  // stage1: h = leaky(W11 @ yn + b11) -> sy
  MM_STAGE(0);
#pragma unroll
  for (int m = 0; m < 4; m++) {
#pragma unroll
    for (int n = 0; n < 2; n++) {
      const int pxl = wv * 32 + n * 16 + (lane & 15);
      short4v ss;
#pragma unroll
      for (int r = 0; r < 4; r++) {
        float h = acc[m][n][r] + spar[2][m * 16 + chq + r];
        h = h > 0.f ? h : 0.01f * h;
        ss[r] = f2bs(h);
      }
      *(short4v*)&sy[pxl][m * 16 + chq] = ss;
    }
  }
  __syncthreads();
  // stage2: o2 = W12 @ h + b12 + v  (registers)
  MM_STAGE(1);
  float4 o2v[4][2];
#pragma unroll
  for (int m = 0; m < 4; m++)
#pragma unroll
    for (int n = 0; n < 2; n++)
#pragma unroll
      for (int r = 0; r < 4; r++)
        (&o2v[m][n].x)[r] = acc[m][n][r] + spar[3][m * 16 + chq + r] + (&vv[m][n].x)[r];
  // LN2 -> sy
  LN_REG(o2v, 4, 5);
  __syncthreads();
  // stage3: h2 = leaky(W21 @ yn2 + b21) -> sy
  MM_STAGE(2);
#pragma unroll
  for (int m = 0; m < 4; m++) {
#pragma unroll
    for (int n = 0; n < 2; n++) {
      const int pxl = wv * 32 + n * 16 + (lane & 15);
      short4v ss;
#pragma unroll
      for (int r = 0; r < 4; r++) {
        float h = acc[m][n][r] + spar[6][m * 16 + chq + r];
        h = h > 0.f ? h : 0.01f * h;
        ss[r] = f2bs(h);
      }
      *(short4v*)&sy[pxl][m * 16 + chq] = ss;
    }
  }
  __syncthreads();
  // stage4: out = W22 @ h2 + b22 + v -> d_out (NCHW f32)
  MM_STAGE(3);
#pragma unroll
  for (int m = 0; m < 4; m++)
#pragma unroll
    for (int n = 0; n < 2; n++) {
      const int pxl = wv * 32 + n * 16 + (lane & 15);
#pragma unroll
      for (int r = 0; r < 4; r++) {
        const int ch = m * 16 + chq + r;
        outp[(((size_t)(b * 64 + ch)) << 14) + p0 + pxl] =
            acc[m][n][r] + spar[7][ch] + (&vv[m][n].x)[r];
      }
    }
#undef LN_REG
#undef MM_STAGE
}

// ================= launcher =================
extern "C" void kernel_launch(void* const* d_in, const int* in_sizes, int n_in,
                              void* d_out, int out_size, void* d_ws, size_t ws_size,
                              hipStream_t stream)
{
  if (ws_size < WS_BYTES) return;
  char* ws = (char*)d_ws;

  const float* x       = (const float*)d_in[0];
  const float* w_down  = (const float*)d_in[1];
  const float* w_mid   = (const float*)d_in[2];
  const float* w_up    = (const float*)d_in[3];
  const float* wq_l    = (const float*)d_in[4];
  const float* wk_m    = (const float*)d_in[5];
  const float* wv_m    = (const float*)d_in[6];
  const float* wq_h    = (const float*)d_in[7];
  const float* rescale = (const float*)d_in[8];
  const float* w_proj_l= (const float*)d_in[9];
  const float* b_proj_l= (const float*)d_in[10];
  const float* w_proj_h= (const float*)d_in[11];
  const float* b_proj_h= (const float*)d_in[12];
  const float* qco_w1  = (const float*)d_in[13];
  const float* qsca_w  = (const float*)d_in[14];
  const float* qsca_b  = (const float*)d_in[15];
  const float* qt1_w   = (const float*)d_in[16];
  const float* qt1_b   = (const float*)d_in[17];
  const float* qt2_w   = (const float*)d_in[18];
  const float* qt2_b   = (const float*)d_in[19];
  const float* rsp_w1  = (const float*)d_in[20];
  const float* rsp_pr  = (const float*)d_in[21];
  const float* rsp_w2  = (const float*)d_in[22];
  const float* c31_w1  = (const float*)d_in[23];
  const float* c31_pr  = (const float*)d_in[24];
  const float* c31_w2  = (const float*)d_in[25];
  const float* c31_w3  = (const float*)d_in[26];
  const float* ln1_g   = (const float*)d_in[27];
  const float* ln1_b   = (const float*)d_in[28];
  const float* ff1_w1  = (const float*)d_in[29];
  const float* ff1_b1  = (const float*)d_in[30];
  const float* ff1_w2  = (const float*)d_in[31];
  const float* ff1_b2  = (const float*)d_in[32];
  const float* ln2_g   = (const float*)d_in[33];
  const float* ln2_b   = (const float*)d_in[34];
  const float* ff2_w1  = (const float*)d_in[35];
  const float* ff2_b1  = (const float*)d_in[36];
  const float* ff2_w2  = (const float*)d_in[37];
  const float* ff2_b2  = (const float*)d_in[38];

  bf16*  zbf   = (bf16*)(ws + OFF_ZBF);
  bf16*  wtq   = (bf16*)(ws + OFF_WTQ);
  bf16*  wtr1  = (bf16*)(ws + OFF_WTR1);
  bf16*  wtr2  = (bf16*)(ws + OFF_WTR2);
  bf16*  wtc1  = (bf16*)(ws + OFF_WTC1);
  bf16*  wtf   = (bf16*)(ws + OFF_WTF);
  float* G     = (float*)(ws + OFF_G);
  float* gpart = (float*)(ws + OFF_GPART);
  float* T1    = (float*)(ws + OFF_T1);
  float* UL    = (float*)(ws + OFF_UL);
  float* UK    = (float*)(ws + OFF_UK);
  float* T1H   = (float*)(ws + OFF_T1H);
  float* UH    = (float*)(ws + OFF_UH);
  float* norms = (float*)(ws + OFF_NORMS);
  float* attL  = (float*)(ws + OFF_ATTL);
  float* attH  = (float*)(ws + OFF_ATTH);
  float* WeL   = (float*)(ws + OFF_WEL);
  float* WeH   = (float*)(ws + OFF_WEH);
  bf16*  acatb = (bf16*)(ws + OFF_ACATB);
  float* tsum  = (float*)(ws + OFF_TSUM);
  float* attb  = (float*)(ws + OFF_ATTB);
  bf16*  hcatb = (bf16*)(ws + OFF_HCATB);
  short* hcatT = (short*)(ws + OFF_HCATT);   // aliases gpart (dead after k_gred)
  short* midb  = (short*)(ws + OFF_MIDB);
  short* houtb = (short*)(ws + OFF_HOUTB);
  float* out1  = (float*)(ws + OFF_OUT1);
  short* xt    = (short*)(ws + OFF_XT);

  // 0) prep
  k_transp<<<dim3(256, 1, 2), 256, 0, stream>>>(x, xt);
  k_prep_all<<<dim3(1728), 256, 0, stream>>>(w_down, w_mid, w_up, rsp_w1, rsp_w2, c31_w1,
                                             wtq, wtr1, wtr2, wtc1);
  k_wfoldb<<<dim3(144), 256, 0, stream>>>(c31_w3, c31_w2, wtf);

  // 1) fused QKV conv 64->384 -> Z (NCHW bf16)
  k_convq<<<dim3(128, 3, 2), 256, 0, stream>>>(xt, (const short*)wtq, zbf);

  // 2) Gram (6 unique tile pairs, mirrored) + reduce
  k_gramm<<<dim3(6, 16, 2), 256, 0, stream>>>((const short*)zbf, gpart);
  k_gred<<<dim3(1152), 256, 0, stream>>>(gpart, G);

  // QCO tap sums (needs only Z)
  k_tsum2<<<dim3(128), 256, 0, stream>>>(zbf, tsum);

  // 3) attention solve on Gram blocks (fused 5-job GEMM)
  Jobs5 J5;
  J5.A[0] = wq_l;  J5.B[0] = G + 64;              J5.C[0] = T1;  J5.K[0] = 64;  J5.lda[0] = 64;  J5.ldb[0] = 384; J5.ldc[0] = 128; J5.sB[0] = 147456; J5.sC[0] = 32768;  J5.nx[0] = 8;
  J5.A[1] = wq_l;  J5.B[1] = G;                   J5.C[1] = UL;  J5.K[1] = 64;  J5.lda[1] = 64;  J5.ldb[1] = 384; J5.ldc[1] = 64;  J5.sB[1] = 147456; J5.sC[1] = 16384;  J5.nx[1] = 4;
  J5.A[2] = wk_m;  J5.B[2] = G + 64 * 384 + 64;   J5.C[2] = UK;  J5.K[2] = 128; J5.lda[2] = 128; J5.ldb[2] = 384; J5.ldc[2] = 128; J5.sB[2] = 147456; J5.sC[2] = 65536;  J5.nx[2] = 8;
  J5.A[3] = wq_h;  J5.B[3] = G + 192 * 384 + 64;  J5.C[3] = T1H; J5.K[3] = 192; J5.lda[3] = 192; J5.ldb[3] = 384; J5.ldc[3] = 128; J5.sB[3] = 147456; J5.sC[3] = 98304;  J5.nx[3] = 8;
  J5.A[4] = wq_h;  J5.B[4] = G + 192 * 384 + 192; J5.C[4] = UH;  J5.K[4] = 192; J5.lda[4] = 192; J5.ldb[4] = 384; J5.ldc[4] = 192; J5.sB[4] = 147456; J5.sC[4] = 147456; J5.nx[4] = 12;
  J5.b0[0] = 0; J5.b0[1] = 128; J5.b0[2] = 192; J5.b0[3] = 448; J5.b0[4] = 832; J5.b0[5] = 1408;
  k_sgemm5<<<dim3(1408, 2), 256, 0, stream>>>(J5);

  k_norms2<<<dim3(768), 256, 0, stream>>>(UL, UK, UH, wq_l, wk_m, wq_h, norms);
  k_qco<<<dim3(2), 64, 0, stream>>>(tsum, qco_w1, qsca_w, qsca_b, qt1_w, qt1_b, qt2_w, qt2_b, attb);
  k_attn<<<dim3(8, 4, 2), 256, 0, stream>>>(T1, T1H, wk_m, norms, rescale, attL, attH);
  k_weff<<<dim3(8, 2, 2), 256, 0, stream>>>(attL, attH, wv_m, WeL, WeH);

  Jobs2 J2;
  J2.A[0] = w_proj_l; J2.B[0] = WeL; J2.K[0] = 256; J2.lda[0] = 256; J2.sB[0] = 32768; J2.nx[0] = 8; J2.co[0] = 0;
  J2.A[1] = w_proj_h; J2.B[1] = WeH; J2.K[1] = 768; J2.lda[1] = 768; J2.sB[1] = 98304; J2.nx[1] = 8; J2.co[1] = 8192;
  J2.b0[0] = 0; J2.b0[1] = 32; J2.b0[2] = 128;
  k_sgemm2b<<<dim3(128, 2), 256, 0, stream>>>(J2, acatb);

  // 4) per-pixel linear map -> Hcat (view-quirk LINEAR layout)
  k_pixm<<<dim3(256, 4, 2), 256, 0, stream>>>((const short*)zbf, (const short*)acatb,
                                              b_proj_l, b_proj_h, hcatb);

  // 4b) view-quirk: Hcat linear == NCHW [256][16384]; transpose to px-major for conv
  k_transph<<<dim3(256, 4, 2), 256, 0, stream>>>((const short*)hcatb, hcatT);

  // 5) ReshapeBlock: 256->64 (+prelu) then 64->64
  k_conv64<1><<<dim3(128, 2, 2), 256, 0, stream>>>(
      hcatT, 256, 4194304L, 256,
      (const short*)wtr1, midb, nullptr, rsp_pr, nullptr, nullptr, nullptr);
  k_conv64<0><<<dim3(128, 2, 2), 256, 0, stream>>>(
      midb, 64, 1048576L, 64,
      (const short*)wtr2, houtb, nullptr, nullptr, nullptr, nullptr, nullptr);

  // 7) Conv3_1 (+prelu) then folded conv + final combine -> out1 (px-major f32)
  k_conv64<1><<<dim3(128, 2, 2), 256, 0, stream>>>(
      houtb, 64, 1048576L, 64,
      (const short*)wtc1, midb, nullptr, c31_pr, nullptr, nullptr, nullptr);
  k_conv64<2><<<dim3(128, 2, 2), 256, 0, stream>>>(
      midb, 64, 1048576L, 64,
      (const short*)wtf, nullptr, out1, nullptr, houtb, attb, x);

  // 8) fused double-FF -> d_out (NCHW f32)
  k_ffm2<<<dim3(256), 256, 0, stream>>>(out1,
      ln1_g, ln1_b, ff1_w1, ff1_b1, ff1_w2, ff1_b2,
      ln2_g, ln2_b, ff2_w1, ff2_b1, ff2_w2, ff2_b2,
      (float*)d_out);
}

// Round 10
// 293.210 us; speedup vs baseline: 4.3612x; 1.0426x over previous
//
#include <hip/hip_runtime.h>
#include <hip/hip_bf16.h>
#include <stdint.h>

typedef __hip_bfloat16 bf16;
typedef __attribute__((ext_vector_type(8))) __bf16 bf8v;
typedef __attribute__((ext_vector_type(8))) short short8;
typedef __attribute__((ext_vector_type(4))) short short4v;
typedef __attribute__((ext_vector_type(4))) float f32x4;
#define DEVINL __device__ __forceinline__
#define MFMA16(a,b,c) __builtin_amdgcn_mfma_f32_16x16x32_bf16((a),(b),(c),0,0,0)

DEVINL short f2bs(float f) { bf16 h = __float2bfloat16(f); return *reinterpret_cast<short*>(&h); }
DEVINL float bs2f(short s) { bf16 h = *reinterpret_cast<bf16*>(&s); return __bfloat162float(h); }

// ---------------- problem dims ----------------
// B=2, C=64, H=W=128, n=16384, HEADS=8, DH=32. All device I/O buffers are f32.

// ---------------- workspace layout (BYTE offsets) ----------------
static const size_t OFF_ZBF   = 0;          // [2][384][16384] bf16 (QKV conv out, NCHW)
static const size_t OFF_WTQ   = 29360128;   // [9][384][64] bf16
static const size_t OFF_WTR1  = 29802496;   // [9][64][256] bf16
static const size_t OFF_WTR2  = 30097408;   // [9][64][64] bf16
static const size_t OFF_WTC1  = 30171136;   // [9][64][64] bf16
static const size_t OFF_WTF   = 30244864;   // [9][64][64] bf16 (folded c31 w3@w2)
static const size_t OFF_G     = 30466048;   // [2][384][384] f32
static const size_t OFF_T1    = 41082880;   // [2][256][128] f32
static const size_t OFF_UL    = 41345024;   // [2][256][64] f32
static const size_t OFF_UK    = 41476096;   // [2][512][128] f32
static const size_t OFF_T1H   = 42000384;   // [2][768][128] f32
static const size_t OFF_UH    = 42786816;   // [2][768][192] f32
static const size_t OFF_NORMS = 43966464;   // [2][1536] f32
static const size_t OFF_ATTL  = 43978752;   // [2][8][32][64] f32
static const size_t OFF_ATTH  = 44109824;   // [2][8][96][64] f32
static const size_t OFF_WEL   = 44503040;   // [2][256][128] f32
static const size_t OFF_WEH   = 44765184;   // [2][768][128] f32
static const size_t OFF_ACATB = 45813760;   // [2][256][128] bf16
static const size_t OFF_TSUM  = 45944832;   // [2][64][9] f32
static const size_t OFF_ATTB  = 45949440;   // [2][64] f32
static const size_t OFF_HCATB = 45949952;   // [2][4194304] bf16 (view-quirk LINEAR layout)
static const size_t OFF_MIDB  = 62727168;   // [2][16384][64] bf16 (px-major)
static const size_t OFF_HOUTB = 66921472;   // [2][16384][64] bf16 (px-major)
static const size_t OFF_OUT1  = 71115776;   // [2][16384][64] f32 (px-major)
static const size_t OFF_GPART = 79504384;   // [16][2][384][384] f32 ; ALSO (later) hcatT
static const size_t OFF_HCATT = 79504384;   // [2][16384][256] bf16 (aliases GPART, dead by then)
static const size_t OFF_XT    = 98378752;   // [2][16384][64] bf16 (x transposed)
static const size_t WS_BYTES  = 102573056;

// ================= prep kernels =================
// x [b][64][16384] f32 -> xt [b][16384][64] bf16
__global__ __launch_bounds__(256) void k_transp(const float* __restrict__ x,
                                                short* __restrict__ xt) {
  __shared__ short sT[64][72];
  const int t = threadIdx.x, b = blockIdx.z, p0 = blockIdx.x * 64;
  for (int i = t; i < 1024; i += 256) {
    int c = i >> 4, p4 = (i & 15) * 4;
    float4 g = *(const float4*)&x[(((size_t)(b * 64 + c)) << 14) + p0 + p4];
    sT[p4 + 0][c] = f2bs(g.x);
    sT[p4 + 1][c] = f2bs(g.y);
    sT[p4 + 2][c] = f2bs(g.z);
    sT[p4 + 3][c] = f2bs(g.w);
  }
  __syncthreads();
  for (int i = t; i < 512; i += 256) {
    int p = i >> 3, co = (i & 7) * 8;
    *(short8*)&xt[((((size_t)b << 14) + p0 + p)) * 64 + co] = *(short8*)&sT[p][co];
  }
}

// hcat LINEAR (quirk view = NCHW [b][256][16384]) bf16 -> hcatT [b][16384][256] bf16
__global__ __launch_bounds__(256) void k_transph(const short* __restrict__ hc,
                                                 short* __restrict__ ht) {
  __shared__ short sT[64][72];
  const int t = threadIdx.x, b = blockIdx.z, p0 = blockIdx.x * 64, c0 = blockIdx.y * 64;
  for (int i = t; i < 512; i += 256) {
    int c = i >> 3, qo = (i & 7) * 8;
    short8 v = *(const short8*)&hc[(((size_t)(b * 256 + c0 + c)) << 14) + p0 + qo];
#pragma unroll
    for (int u = 0; u < 8; u++) sT[qo + u][c] = v[u];
  }
  __syncthreads();
  for (int i = t; i < 512; i += 256) {
    int q = i >> 3, co = (i & 7) * 8;
    *(short8*)&ht[((size_t)(b * 16384 + p0 + q)) * 256 + c0 + co] = *(short8*)&sT[q][co];
  }
}

// fused weight transforms -> [tap][oc][ic] bf16
__global__ void k_prep_all(const float* __restrict__ wd, const float* __restrict__ wm,
                           const float* __restrict__ wu, const float* __restrict__ rw1,
                           const float* __restrict__ rw2, const float* __restrict__ cw1,
                           bf16* __restrict__ wtq, bf16* __restrict__ wtr1,
                           bf16* __restrict__ wtr2, bf16* __restrict__ wtc1) {
  int i = blockIdx.x * 256 + threadIdx.x;
  if (i < 221184) {
    int tap = i / 24576, r = i % 24576, oc = r >> 6, ic = r & 63;
    float v;
    if (oc < 64)       v = wd[(oc * 64 + ic) * 9 + tap];
    else if (oc < 192) v = wm[((oc - 64) * 64 + ic) * 9 + tap];
    else               v = wu[((oc - 192) * 64 + ic) * 9 + tap];
    wtq[i] = __float2bfloat16(v);
  } else if (i < 368640) {
    int j = i - 221184;
    int tap = j / 16384, r = j % 16384, oc = r >> 8, ic = r & 255;
    wtr1[j] = __float2bfloat16(rw1[(oc * 256 + ic) * 9 + tap]);
  } else if (i < 405504) {
    int j = i - 368640;
    int tap = j / 4096, r = j % 4096, oc = r >> 6, ic = r & 63;
    wtr2[j] = __float2bfloat16(rw2[(oc * 64 + ic) * 9 + tap]);
  } else if (i < 442368) {
    int j = i - 405504;
    int tap = j / 4096, r = j % 4096, oc = r >> 6, ic = r & 63;
    wtc1[j] = __float2bfloat16(cw1[(oc * 64 + ic) * 9 + tap]);
  }
}

// wtf[tap][o][ic] = bf16( sum_m c31_w3[o][m] * c31_w2[m][ic][tap] )
__global__ void k_wfoldb(const float* __restrict__ w3, const float* __restrict__ w2,
                         bf16* __restrict__ wtf) {
  int i = blockIdx.x * 256 + threadIdx.x;
  if (i >= 36864) return;
  int tap = i / 4096, r = i % 4096, o = r >> 6, ic = r & 63;
  float s = 0.f;
  for (int m = 0; m < 64; m++)
    s = fmaf(w3[o * 64 + m], w2[(m * 64 + ic) * 9 + tap], s);
  wtf[i] = __float2bfloat16(s);
}

// ================= QKV conv 64->384 (zero pad), direct-A MFMA =================
__global__ __launch_bounds__(256) void k_convq(
    const short* __restrict__ xt, const short* __restrict__ wtq,
    bf16* __restrict__ zbf)
{
  __shared__ short sX[3][130][72];
  const int t = threadIdx.x, lane = t & 63, wv = t >> 6;
  const int y = blockIdx.x, ocg = blockIdx.y, b = blockIdx.z;

  for (int i = t; i < 3120; i += 256) {
    int col = i % 130, rr = i / 130, row = rr % 3, ko = rr / 3;
    int gy = y + row - 1, gx = col - 1;
    short8 vv;
    if ((gy >= 0) & (gy < 128) & (gx >= 0) & (gx < 128)) {
      vv = *(const short8*)&xt[((size_t)b * 1048576 + (size_t)((gy << 7) + gx) * 64) + ko * 8];
    } else {
#pragma unroll
      for (int u = 0; u < 8; u++) vv[u] = 0;
    }
    *(short8*)&sX[row][col][ko * 8] = vv;
  }
  __syncthreads();

  const f32x4 zero = {0.f, 0.f, 0.f, 0.f};
  f32x4 acc[2][8];
#pragma unroll
  for (int m = 0; m < 2; m++)
#pragma unroll
    for (int n = 0; n < 8; n++) acc[m][n] = zero;

#pragma unroll
  for (int tap = 0; tap < 9; tap++) {
    const int ky = tap / 3, kx = tap % 3;
#pragma unroll
    for (int kk = 0; kk < 2; kk++) {
      const int kb = kk * 32 + (lane >> 4) * 8;
      bf8v a0 = *(const bf8v*)&wtq[(size_t)((tap * 384 + ocg * 128 + wv * 32 + (lane & 15)) * 64) + kb];
      bf8v a1 = *(const bf8v*)&wtq[(size_t)((tap * 384 + ocg * 128 + wv * 32 + 16 + (lane & 15)) * 64) + kb];
#pragma unroll
      for (int n = 0; n < 8; n++) {
        bf8v bfr = *(const bf8v*)&sX[ky][n * 16 + (lane & 15) + kx][kb];
        acc[0][n] = MFMA16(a0, bfr, acc[0][n]);
        acc[1][n] = MFMA16(a1, bfr, acc[1][n]);
      }
    }
  }
#pragma unroll
  for (int m = 0; m < 2; m++) {
    const int oc0 = ocg * 128 + wv * 32 + m * 16 + ((lane >> 4) << 2);
#pragma unroll
    for (int n = 0; n < 8; n++) {
      const int px = n * 16 + (lane & 15);
#pragma unroll
      for (int r = 0; r < 4; r++)
        zbf[(((size_t)(b * 384 + oc0 + r)) << 14) + (y << 7) + px] = __float2bfloat16(acc[m][n][r]);
    }
  }
}

// ================= 3x3 reflect conv -> 64 out (direct-A MFMA, px-major IO) =================
// Block: 64 px (half row) x 64 oc; 4 waves, wave wv -> oc [wv*16, wv*16+16).
// in: px-major bf16 [b][16384][str].
// EPI: 0 plain->bf16 pm, 1 prelu->bf16 pm, 2 final(acc + hout*attb + x)->f32 pm
template<int EPI>
__global__ __launch_bounds__(256) void k_conv64(
    const short* __restrict__ in, int str, long bstride, int Cin,
    const short* __restrict__ Wt,
    short* __restrict__ outb, float* __restrict__ outf,
    const float* __restrict__ prelu_a,
    const short* __restrict__ houtpm, const float* __restrict__ attb,
    const float* __restrict__ x_nchw)
{
  __shared__ short sX[3][66][72];
  const int t = threadIdx.x, lane = t & 63, wv = t >> 6;
  const int y = blockIdx.x, x0 = blockIdx.y * 64, b = blockIdx.z;

  const f32x4 zero = {0.f, 0.f, 0.f, 0.f};
  f32x4 acc[4] = {zero, zero, zero, zero};

  for (int icb = 0; icb < Cin; icb += 64) {
    __syncthreads();
    for (int i = t; i < 1584; i += 256) {
      int col = i % 66, rr = i / 66, row = rr % 3, ko = rr / 3;
      int gy = y + row - 1, gx = x0 + col - 1;
      gy = gy < 0 ? 1 : (gy > 127 ? 126 : gy);
      gx = gx < 0 ? 1 : (gx > 127 ? 126 : gx);
      *(short8*)&sX[row][col][ko * 8] =
          *(const short8*)&in[(size_t)b * bstride + (size_t)((gy << 7) + gx) * str + icb + ko * 8];
    }
    __syncthreads();
#pragma unroll
    for (int tap = 0; tap < 9; tap++) {
      const int ky = tap / 3, kx = tap % 3;
#pragma unroll
      for (int kk = 0; kk < 2; kk++) {
        const int kb = kk * 32 + (lane >> 4) * 8;
        bf8v afr = *(const bf8v*)&Wt[(size_t)(tap * 64 + wv * 16 + (lane & 15)) * Cin + icb + kb];
#pragma unroll
        for (int n = 0; n < 4; n++) {
          bf8v bfr = *(const bf8v*)&sX[ky][n * 16 + (lane & 15) + kx][kb];
          acc[n] = MFMA16(afr, bfr, acc[n]);
        }
      }
    }
  }
  // epilogue: oc = wv*16 + (lane>>4)*4 + r ; px = x0 + n*16 + (lane&15)
  const int oc0 = wv * 16 + ((lane >> 4) << 2);
  const float aP = (EPI == 1) ? prelu_a[0] : 0.f;
#pragma unroll
  for (int n = 0; n < 4; n++) {
    const int gpx = (y << 7) + x0 + n * 16 + (lane & 15);
    if (EPI == 2) {
      short4v hv = *(const short4v*)&houtpm[((size_t)(b * 16384 + gpx)) * 64 + oc0];
      float4 av = *(const float4*)&attb[b * 64 + oc0];
      float4 o;
#pragma unroll
      for (int r = 0; r < 4; r++)
        (&o.x)[r] = acc[n][r] + bs2f(hv[r]) * (&av.x)[r] +
                    x_nchw[(((size_t)(b * 64 + oc0 + r)) << 14) + gpx];
      *(float4*)&outf[((size_t)(b * 16384 + gpx)) * 64 + oc0] = o;
    } else {
      short4v ss;
#pragma unroll
      for (int r = 0; r < 4; r++) {
        float v = acc[n][r];
        if (EPI == 1) v = v > 0.f ? v : aP * v;
        ss[r] = f2bs(v);
      }
      *(short4v*)&outb[((size_t)(b * 16384 + gpx)) * 64 + oc0] = ss;
    }
  }
}

// ======= Gram via MFMA: G[b] = Z Z^T (21 unique 64-row tile pairs + mirror) =======
__global__ __launch_bounds__(256) void k_gramm(const short* __restrict__ Z,
                                               float* __restrict__ Gp) {
  // grid: x = 21 (ti<=tj pairs of 64-row tiles), y = 16 k-chunks(1024), z = b
  int rem = blockIdx.x, ti = 0;
  while (rem >= 6 - ti) { rem -= 6 - ti; ti++; }
  const int tj = ti + rem;
  const int kc = blockIdx.y, b = blockIdx.z;
  __shared__ short sA[64][72];
  __shared__ short sB[64][72];
  const int t = threadIdx.x, lane = t & 63, wv = t >> 6;
  const int wo = wv & 1, wp = wv >> 1;
  const f32x4 zero = {0.f, 0.f, 0.f, 0.f};
  f32x4 acc[2][2];
#pragma unroll
  for (int m = 0; m < 2; m++)
#pragma unroll
    for (int n = 0; n < 2; n++) acc[m][n] = zero;
  const size_t zb = (size_t)b * 6291456;
  const int k0 = kc * 1024;
  for (int ks = 0; ks < 1024; ks += 64) {
    __syncthreads();
    for (int i = t; i < 512; i += 256) {
      int r = i >> 3, ko = i & 7;
      *(short8*)&sA[r][ko * 8] =
          *(const short8*)&Z[zb + ((size_t)(ti * 64 + r) << 14) + k0 + ks + ko * 8];
      *(short8*)&sB[r][ko * 8] =
          *(const short8*)&Z[zb + ((size_t)(tj * 64 + r) << 14) + k0 + ks + ko * 8];
    }
    __syncthreads();
#pragma unroll
    for (int kk = 0; kk < 2; kk++) {
      const int kb = kk * 32 + (lane >> 4) * 8;
      bf8v bfr[2];
#pragma unroll
      for (int n = 0; n < 2; n++)
        bfr[n] = *(const bf8v*)&sB[wp * 32 + n * 16 + (lane & 15)][kb];
#pragma unroll
      for (int m = 0; m < 2; m++) {
        bf8v afr = *(const bf8v*)&sA[wo * 32 + m * 16 + (lane & 15)][kb];
#pragma unroll
        for (int n = 0; n < 2; n++)
          acc[m][n] = MFMA16(afr, bfr[n], acc[m][n]);
      }
    }
  }
  float* gp = Gp + ((size_t)(kc * 2 + b)) * 147456;
#pragma unroll
  for (int m = 0; m < 2; m++)
#pragma unroll
    for (int n = 0; n < 2; n++)
#pragma unroll
      for (int r = 0; r < 4; r++) {
        const int row = ti * 64 + wo * 32 + m * 16 + ((lane >> 4) << 2) + r;
        const int col = tj * 64 + wp * 32 + n * 16 + (lane & 15);
        float v = acc[m][n][r];
        gp[(size_t)row * 384 + col] = v;
        if (ti != tj) gp[(size_t)col * 384 + row] = v;
      }
}

__global__ void k_gred(const float* __restrict__ Gp, float* __restrict__ G) {
  int i = blockIdx.x * 256 + threadIdx.x;
  if (i >= 294912) return;
  int b = i / 147456, e = i % 147456;
  float s = 0.f;
#pragma unroll
  for (int c = 0; c < 16; c++) s += Gp[(size_t)(c * 2 + b) * 147456 + e];
  G[i] = s;
}

// ================= per-pixel map via MFMA (view-quirk LINEAR output) =================
__global__ __launch_bounds__(256) void k_pixm(
    const short* __restrict__ Z, const short* __restrict__ Acatb,
    const float* __restrict__ bl, const float* __restrict__ bh,
    bf16* __restrict__ hcat)
{
  const int p0 = blockIdx.x * 64, ocg = blockIdx.y, b = blockIdx.z;
  __shared__ short sA[64][136];
  __shared__ short sB[64][136];
  const int t = threadIdx.x, lane = t & 63, wv = t >> 6;
  for (int i = t; i < 1024; i += 256) {
    int oc = i >> 4, ko = i & 15;
    *(short8*)&sA[oc][ko * 8] =
        *(const short8*)&Acatb[((size_t)(b * 256 + ocg * 64 + oc)) * 128 + ko * 8];
  }
  for (int i = t; i < 1024; i += 256) {
    int px = i & 63, ko = i >> 6;
    short8 vv;
#pragma unroll
    for (int u = 0; u < 8; u++)
      vv[u] = Z[((size_t)(b * 384 + 64 + ko * 8 + u) << 14) + p0 + px];
    *(short8*)&sB[px][ko * 8] = vv;
  }
  __syncthreads();
  const f32x4 zero = {0.f, 0.f, 0.f, 0.f};
  f32x4 acc[4] = {zero, zero, zero, zero};
#pragma unroll
  for (int kk = 0; kk < 4; kk++) {
    const int kb = kk * 32 + (lane >> 4) * 8;
    bf8v afr = *(const bf8v*)&sA[wv * 16 + (lane & 15)][kb];
#pragma unroll
    for (int n = 0; n < 4; n++) {
      bf8v bfr = *(const bf8v*)&sB[n * 16 + (lane & 15)][kb];
      acc[n] = MFMA16(afr, bfr, acc[n]);
    }
  }
  const size_t hbase = (size_t)b * 4194304;
#pragma unroll
  for (int n = 0; n < 4; n++) {
    const int px = p0 + n * 16 + (lane & 15);
#pragma unroll
    for (int r = 0; r < 4; r++) {
      const int oc = ocg * 64 + wv * 16 + ((lane >> 4) << 2) + r;
      float v = acc[n][r] + (oc < 64 ? bl[oc] : bh[oc - 64]);
      size_t addr = (oc < 64) ? hbase + (size_t)px * 64 + oc
                              : hbase + 1048576 + (size_t)px * 192 + (oc - 64);
      hcat[addr] = __float2bfloat16(v);
    }
  }
}

// ================= fused small-GEMM chain (5 jobs): C = A[M,K]*B[K,N] =================
struct Jobs5 {
  const float* A[5]; const float* B[5]; float* C[5];
  int K[5]; int lda[5]; int ldb[5]; int ldc[5];
  long sB[5]; long sC[5];
  int nx[5]; int b0[6];
};

__global__ __launch_bounds__(256) void k_sgemm5(Jobs5 J) {
  __shared__ float sa[16][17];
  __shared__ float sb[16][17];
  const int bx = blockIdx.x, z = blockIdx.y;
  int j = 0;
  while (bx >= J.b0[j + 1]) j++;
  const int local = bx - J.b0[j];
  const int x = local % J.nx[j], y = local / J.nx[j];
  const int tx = threadIdx.x & 15, ty = threadIdx.x >> 4;
  const float* Ap = J.A[j];
  const float* Bp = J.B[j] + (size_t)z * J.sB[j];
  const int K = J.K[j], lda = J.lda[j], ldb = J.ldb[j];
  const int m = y * 16 + ty, n = x * 16 + tx;
  float acc = 0.f;
  for (int k0 = 0; k0 < K; k0 += 16) {
    sa[ty][tx] = Ap[(size_t)m * lda + k0 + tx];
    sb[ty][tx] = Bp[(size_t)(k0 + ty) * ldb + n];
    __syncthreads();
#pragma unroll
    for (int kk = 0; kk < 16; kk++) acc = fmaf(sa[ty][kk], sb[kk][tx], acc);
    __syncthreads();
  }
  J.C[j][(size_t)z * J.sC[j] + (size_t)m * J.ldc[j] + n] = acc;
}

// ================= proj GEMMs (2 jobs) -> bf16 Acat =================
struct Jobs2 {
  const float* A[2]; const float* B[2];
  int K[2]; int lda[2];
  long sB[2];
  int nx[2]; int b0[3]; int co[2];
};

__global__ __launch_bounds__(256) void k_sgemm2b(Jobs2 J, bf16* __restrict__ Cb) {
  __shared__ float sa[16][17];
  __shared__ float sb[16][17];
  const int bx = blockIdx.x, z = blockIdx.y;
  int j = (bx >= J.b0[1]) ? 1 : 0;
  const int local = bx - J.b0[j];
  const int x = local % J.nx[j], y = local / J.nx[j];
  const int tx = threadIdx.x & 15, ty = threadIdx.x >> 4;
  const float* Ap = J.A[j];
  const float* Bp = J.B[j] + (size_t)z * J.sB[j];
  const int K = J.K[j], lda = J.lda[j];
  const int m = y * 16 + ty, n = x * 16 + tx;
  float acc = 0.f;
  for (int k0 = 0; k0 < K; k0 += 16) {
    sa[ty][tx] = Ap[(size_t)m * lda + k0 + tx];
    sb[ty][tx] = Bp[(size_t)(k0 + ty) * 128 + n];
    __syncthreads();
#pragma unroll
    for (int kk = 0; kk < 16; kk++) acc = fmaf(sa[ty][kk], sb[kk][tx], acc);
    __syncthreads();
  }
  Cb[(size_t)z * 32768 + J.co[j] + (size_t)m * 128 + n] = __float2bfloat16(acc);
}

// ================= norms: one wave per row, coalesced + shuffle reduce =================
__global__ __launch_bounds__(256) void k_norms2(
    const float* __restrict__ UL, const float* __restrict__ UK,
    const float* __restrict__ UH,
    const float* __restrict__ wql, const float* __restrict__ wkm,
    const float* __restrict__ wqh, float* __restrict__ norms) {
  const int t = threadIdx.x, lane = t & 63;
  const int row = blockIdx.x * 4 + (t >> 6);   // 0..3071
  const int b = row >> 11 ? 1 : (row >= 1536 ? 1 : 0);
  const int r = row - b * 1536;
  const float* u; const float* wv; int K;
  if (r < 256)      { K = 64;  u = UL + (size_t)(b * 256 + r) * 64;          wv = wql + (size_t)r * 64; }
  else if (r < 768) { int e = r - 256; K = 128; u = UK + (size_t)(b * 512 + e) * 128; wv = wkm + (size_t)e * 128; }
  else              { int d = r - 768; K = 192; u = UH + (size_t)(b * 768 + d) * 192; wv = wqh + (size_t)d * 192; }
  float s = 0.f;
  for (int k = lane; k < K; k += 64) s = fmaf(u[k], wv[k], s);
#pragma unroll
  for (int o = 32; o; o >>= 1) s += __shfl_xor(s, o);
  if (lane == 0) norms[b * 1536 + r] = fmaxf(sqrtf(fmaxf(s, 0.f)), 1e-12f);
}

// ================= attention logits + softmax =================
__global__ __launch_bounds__(256) void k_attn(
    const float* __restrict__ T1, const float* __restrict__ T1H,
    const float* __restrict__ wkm, const float* __restrict__ norms,
    const float* __restrict__ rescale,
    float* __restrict__ attL, float* __restrict__ attH)
{
  const int h = blockIdx.x, cy = blockIdx.y, b = blockIdx.z;
  const int t = threadIdx.x;
  __shared__ float sK[64 * 129];
  __shared__ float sQ[32 * 129];
  __shared__ float sNk[64];
  const int isL = (cy == 0);
  const int rbase = isL ? 0 : (cy - 1) * 32;
  const float* TQ = isL ? (T1 + (size_t)(b * 256 + h * 32) * 128)
                        : (T1H + (size_t)(b * 768 + h * 96 + rbase) * 128);
  for (int idx = t; idx < 8192; idx += 256) {
    int e = idx >> 7, k = idx & 127;
    sK[e * 129 + k] = wkm[(size_t)(h * 64 + e) * 128 + k];
  }
  for (int idx = t; idx < 4096; idx += 256) {
    int r = idx >> 7, k = idx & 127;
    sQ[r * 129 + k] = TQ[(size_t)r * 128 + k];
  }
  if (t < 64) sNk[t] = norms[b * 1536 + 256 + h * 64 + t];
  __syncthreads();

  const int w = t >> 6, lane = t & 63;
  const float rs = rescale[h];
  for (int r = w; r < 32; r += 4) {
    float s = 0.f;
    for (int k = 0; k < 128; k++) s = fmaf(sQ[r * 129 + k], sK[lane * 129 + k], s);
    float nq = norms[b * 1536 + (isL ? (h * 32 + r) : (768 + h * 96 + rbase + r))];
    float logit = s / (nq * sNk[lane]) * rs;
    float m = logit;
#pragma unroll
    for (int o = 32; o; o >>= 1) m = fmaxf(m, __shfl_xor(m, o));
    float p = __expf(logit - m);
    float den = p;
#pragma unroll
    for (int o = 32; o; o >>= 1) den += __shfl_xor(den, o);
    float av = p / den;
    if (isL) attL[((size_t)(b * 8 + h) * 32 + r) * 64 + lane] = av;
    else     attH[((size_t)(b * 8 + h) * 96 + rbase + r) * 64 + lane] = av;
  }
}

// ================= Weff = attn @ wv (per head) =================
__global__ __launch_bounds__(256) void k_weff(
    const float* __restrict__ attL, const float* __restrict__ attH,
    const float* __restrict__ wvm,
    float* __restrict__ WeL, float* __restrict__ WeH)
{
  const int h = blockIdx.x, br = blockIdx.y, b = blockIdx.z;
  const int M = br ? 96 : 32;
  __shared__ float sAt[96 * 64];
  __shared__ float sV[64 * 132];
  const int t = threadIdx.x;
  const float* asrc = br ? attH + (size_t)(b * 8 + h) * 96 * 64
                         : attL + (size_t)(b * 8 + h) * 32 * 64;
  for (int idx = t; idx < M * 64; idx += 256) sAt[idx] = asrc[idx];
  for (int idx = t; idx < 8192; idx += 256) {
    int e = idx >> 7, k = idx & 127;
    sV[e * 132 + k] = wvm[(size_t)(h * 64 + e) * 128 + k];
  }
  __syncthreads();
  const int jg = t & 31, rw = t >> 5;
  float* dst = br ? WeH + (size_t)(b * 768 + h * 96) * 128
                  : WeL + (size_t)(b * 256 + h * 32) * 128;
  for (int r = rw; r < M; r += 8) {
    float4 acc = make_float4(0.f, 0.f, 0.f, 0.f);
    for (int e = 0; e < 64; e++) {
      float a = sAt[r * 64 + e];
      float4 v4 = *(const float4*)&sV[e * 132 + jg * 4];
      acc.x = fmaf(a, v4.x, acc.x);
      acc.y = fmaf(a, v4.y, acc.y);
      acc.z = fmaf(a, v4.z, acc.z);
      acc.w = fmaf(a, v4.w, acc.w);
    }
    *(float4*)&dst[(size_t)r * 128 + jg * 4] = acc;
  }
}

// ================= QCO tap sums, separable (one vectorized pass) =================
__global__ __launch_bounds__(256) void k_tsum2(const bf16* __restrict__ Z,
                                               float* __restrict__ Tsum) {
  const int c = blockIdx.x & 63, b = blockIdx.x >> 6;
  const bf16* src = Z + (((size_t)(b * 384 + c)) << 14);
  const int t = threadIdx.x;
  __shared__ float sc[16];      // corners e[ri][xi], ri,xi map {0,1,126,127}->0..3
  __shared__ float red[4][9];
  float a9[9] = {};             // tot, r0, r1, r126, r127, c0, c1, c126, c127
  for (int i = t; i < 2048; i += 256) {
    int y = i >> 4, x0 = (i & 15) * 8;
    short8 v8 = *(const short8*)&src[(y << 7) + x0];
    float vs[8], s8 = 0.f;
#pragma unroll
    for (int u = 0; u < 8; u++) { vs[u] = bs2f(v8[u]); s8 += vs[u]; }
    a9[0] += s8;
    int ri = (y == 0) ? 0 : (y == 1) ? 1 : (y == 126) ? 2 : (y == 127) ? 3 : -1;
    if (ri >= 0) a9[1 + ri] += s8;
    if (x0 == 0)   { a9[5] += vs[0]; a9[6] += vs[1]; }
    if (x0 == 120) { a9[7] += vs[6]; a9[8] += vs[7]; }
    if (ri >= 0) {
      if (x0 == 0)   { sc[ri * 4 + 0] = vs[0]; sc[ri * 4 + 1] = vs[1]; }
      if (x0 == 120) { sc[ri * 4 + 2] = vs[6]; sc[ri * 4 + 3] = vs[7]; }
    }
  }
#pragma unroll
  for (int q = 0; q < 9; q++)
#pragma unroll
    for (int o = 32; o; o >>= 1) a9[q] += __shfl_xor(a9[q], o);
  const int w = t >> 6;
  if ((t & 63) == 0)
#pragma unroll
    for (int q = 0; q < 9; q++) red[w][q] = a9[q];
  __syncthreads();
  if (t == 0) {
    float s9[9];
#pragma unroll
    for (int q = 0; q < 9; q++) s9[q] = red[0][q] + red[1][q] + red[2][q] + red[3][q];
    const float T = s9[0];
    float R[4] = {s9[1], s9[2], s9[3], s9[4]};
    const float C0 = s9[5], C1 = s9[6], C126 = s9[7], C127 = s9[8];
    float rs[4][3];   // rowshift[ri][dxi]
#pragma unroll
    for (int ri = 0; ri < 4; ri++) {
      rs[ri][0] = R[ri] - sc[ri * 4 + 3] + sc[ri * 4 + 1];
      rs[ri][1] = R[ri];
      rs[ri][2] = R[ri] - sc[ri * 4 + 0] + sc[ri * 4 + 2];
    }
    float A3[3] = {T - C127 + C1, T, T - C0 + C126};
#pragma unroll
    for (int dx = 0; dx < 3; dx++) {
      Tsum[blockIdx.x * 9 + 0 * 3 + dx] = A3[dx] - rs[3][dx] + rs[1][dx];
      Tsum[blockIdx.x * 9 + 1 * 3 + dx] = A3[dx];
      Tsum[blockIdx.x * 9 + 2 * 3 + dx] = A3[dx] - rs[0][dx] + rs[2][dx];
    }
  }
}

// ================= QCO tail (per batch, 64 threads) =================
__global__ __launch_bounds__(64) void k_qco(
    const float* __restrict__ Tsum, const float* __restrict__ w1,
    const float* __restrict__ scaw, const float* __restrict__ scab,
    const float* __restrict__ t1w, const float* __restrict__ t1b,
    const float* __restrict__ t2w, const float* __restrict__ t2b,
    float* __restrict__ attb)
{
  const int b = blockIdx.x, c = threadIdx.x;
  __shared__ float sm[64], sxq[64], scat[128], sh1[64];
  float acc = 0.f;
  for (int j = 0; j < 64; j++) {
#pragma unroll
    for (int tap = 0; tap < 9; tap++)
      acc = fmaf(w1[(c * 64 + j) * 9 + tap], Tsum[(b * 64 + j) * 9 + tap], acc);
  }
  sm[c] = acc * (1.f / 16384.f);
  __syncthreads();
  float xa = scab[c];
  for (int j = 0; j < 64; j++) xa = fmaf(scaw[c * 64 + j], sm[j], xa);
  sxq[c] = xa;
  __syncthreads();
  float mn = xa, mx = xa;
#pragma unroll
  for (int o = 32; o; o >>= 1) {
    mn = fminf(mn, __shfl_xor(mn, o));
    mx = fmaxf(mx, __shfl_xor(mx, o));
  }
  float inter = (mx - mn) * (1.f / 64.f);
  float ql = (2.f * c + 1.f) / 128.f * (mx - mn) + mn;
  float sta = 0.f;
  for (int j = 0; j < 64; j++) {
    float q = 1.f - fabsf(ql - sxq[j]);
    sta += (q > 1.f - inter) ? q : 0.f;
  }
  float tot = sta;
#pragma unroll
  for (int o = 32; o; o >>= 1) tot += __shfl_xor(tot, o);
  sta = sta / fmaxf(tot, 1e-30f);
  scat[c] = sta; scat[64 + c] = xa;
  __syncthreads();
  float h = t1b[c];
  for (int j = 0; j < 128; j++) h = fmaf(t1w[c * 128 + j], scat[j], h);
  h = fmaxf(h, 0.f);
  sh1[c] = h;
  __syncthreads();
  float o2 = t2b[c];
  for (int j = 0; j < 64; j++) o2 = fmaf(t2w[c * 64 + j], sh1[j], o2);
  attb[b * 64 + c] = fmaxf(o2, 0.f);
}

// ================= MFMA fused double-FF (register residual + in-reg LN) =================
// Block: 128 px x 64 ch; wave wv owns px [wv*32, wv*32+32).
__global__ __launch_bounds__(256) void k_ffm2(const float* __restrict__ out1pm,
    const float* g1, const float* be1, const float* w11, const float* b11,
    const float* w12, const float* b12,
    const float* g2, const float* be2, const float* w21, const float* b21,
    const float* w22, const float* b22,
    float* __restrict__ outp)
{
  __shared__ short sW4[4][64][72];
  __shared__ short sy[128][72];
  __shared__ float spar[8][64];

  const int t = threadIdx.x, lane = t & 63, wv = t >> 6;
  const int gp0 = blockIdx.x * 128;
  const int b = gp0 >> 14, p0 = gp0 & 16383;
  const int chq = ((lane >> 4) << 2);

  for (int idx = t; idx < 4096; idx += 256) {
    int oc = idx >> 6, k = idx & 63;
    sW4[0][oc][k] = f2bs(w11[idx]);
    sW4[1][oc][k] = f2bs(w12[idx]);
    sW4[2][oc][k] = f2bs(w21[idx]);
    sW4[3][oc][k] = f2bs(w22[idx]);
  }
  if (t < 64) {
    spar[0][t] = g1[t]; spar[1][t] = be1[t]; spar[2][t] = b11[t]; spar[3][t] = b12[t];
    spar[4][t] = g2[t]; spar[5][t] = be2[t]; spar[6][t] = b21[t]; spar[7][t] = b22[t];
  }
  // residual v in registers: vv[m][n] -> ch m*16+chq+0..3, px wv*32+n*16+(lane&15)
  float4 vv[4][2];
#pragma unroll
  for (int m = 0; m < 4; m++)
#pragma unroll
    for (int n = 0; n < 2; n++) {
      const int px = p0 + wv * 32 + n * 16 + (lane & 15);
      vv[m][n] = *(const float4*)&out1pm[((size_t)(b * 16384 + px)) * 64 + m * 16 + chq];
    }
  __syncthreads();

  const f32x4 zero = {0.f, 0.f, 0.f, 0.f};
  f32x4 acc[4][2];

#define LN_REG(SRCV, GI, BI)                                                     \
  {                                                                              \
    _Pragma("unroll")                                                            \
    for (int n = 0; n < 2; n++) {                                                \
      float s1 = 0.f, s2 = 0.f;                                                  \
      _Pragma("unroll")                                                          \
      for (int m = 0; m < 4; m++)                                                \
        _Pragma("unroll")                                                        \
        for (int r = 0; r < 4; r++) {                                            \
          float vx = (&SRCV[m][n].x)[r];                                         \
          s1 += vx; s2 += vx * vx;                                               \
        }                                                                        \
      s1 += __shfl_xor(s1, 16); s1 += __shfl_xor(s1, 32);                        \
      s2 += __shfl_xor(s2, 16); s2 += __shfl_xor(s2, 32);                        \
      float mu = s1 * (1.f / 64.f);                                              \
      float var = fmaxf(s2 * (1.f / 64.f) - mu * mu, 0.f);                       \
      float rstd = 1.f / sqrtf(var + 1e-5f);                                     \
      const int pxl = wv * 32 + n * 16 + (lane & 15);                            \
      _Pragma("unroll")                                                          \
      for (int m = 0; m < 4; m++) {                                              \
        short4v ss;                                                              \
        _Pragma("unroll")                                                        \
        for (int r = 0; r < 4; r++) {                                            \
          int ch = m * 16 + chq + r;                                             \
          ss[r] = f2bs(((&SRCV[m][n].x)[r] - mu) * rstd * spar[GI][ch] + spar[BI][ch]); \
        }                                                                        \
        *(short4v*)&sy[pxl][m * 16 + chq] = ss;                                  \
      }                                                                          \
    }                                                                            \
  }

#define MM_STAGE(SIDX)                                                           \
  {                                                                              \
    _Pragma("unroll")                                                            \
    for (int m = 0; m < 4; m++) { acc[m][0] = zero; acc[m][1] = zero; }          \
    _Pragma("unroll")                                                            \
    for (int kk = 0; kk < 2; kk++) {                                             \
      const int kb = kk * 32 + (lane >> 4) * 8;                                  \
      bf8v bfr0 = *(const bf8v*)&sy[wv * 32 + (lane & 15)][kb];                  \
      bf8v bfr1 = *(const bf8v*)&sy[wv * 32 + 16 + (lane & 15)][kb];             \
      _Pragma("unroll")                                                          \
      for (int m = 0; m < 4; m++) {                                              \
        bf8v afr = *(const bf8v*)&sW4[SIDX][m * 16 + (lane & 15)][kb];           \
        acc[m][0] = MFMA16(afr, bfr0, acc[m][0]);                                \
        acc[m][1] = MFMA16(afr, bfr1, acc[m][1]);                                \
      }                                                                          \
    }                                                                            \
  }

  // LN1 -> sy
  LN_REG(vv, 0, 1);
  __syncthreads();
  // stage1: h = leaky(W11 @ yn + b11) -> sy
  MM_STAGE(0);
#pragma unroll
  for (int m = 0; m < 4; m++) {
#pragma unroll
    for (int n = 0; n < 2; n++) {
      const int pxl = wv * 32 + n * 16 + (lane & 15);
      short4v ss;
#pragma unroll
      for (int r = 0; r < 4; r++) {
        float h = acc[m][n][r] + spar[2][m * 16 + chq + r];
        h = h > 0.f ? h : 0.01f * h;
        ss[r] = f2bs(h);
      }
      *(short4v*)&sy[pxl][m * 16 + chq] = ss;
    }
  }
  __syncthreads();
  // stage2: o2 = W12 @ h + b12 + v  (registers)
  MM_STAGE(1);
  float4 o2v[4][2];
#pragma unroll
  for (int m = 0; m < 4; m++)
#pragma unroll
    for (int n = 0; n < 2; n++)
#pragma unroll
      for (int r = 0; r < 4; r++)
        (&o2v[m][n].x)[r] = acc[m][n][r] + spar[3][m * 16 + chq + r] + (&vv[m][n].x)[r];
  // LN2 -> sy
  LN_REG(o2v, 4, 5);
  __syncthreads();
  // stage3: h2 = leaky(W21 @ yn2 + b21) -> sy
  MM_STAGE(2);
#pragma unroll
  for (int m = 0; m < 4; m++) {
#pragma unroll
    for (int n = 0; n < 2; n++) {
      const int pxl = wv * 32 + n * 16 + (lane & 15);
      short4v ss;
#pragma unroll
      for (int r = 0; r < 4; r++) {
        float h = acc[m][n][r] + spar[6][m * 16 + chq + r];
        h = h > 0.f ? h : 0.01f * h;
        ss[r] = f2bs(h);
      }
      *(short4v*)&sy[pxl][m * 16 + chq] = ss;
    }
  }
  __syncthreads();
  // stage4: out = W22 @ h2 + b22 + v -> d_out (NCHW f32)
  MM_STAGE(3);
#pragma unroll
  for (int m = 0; m < 4; m++)
#pragma unroll
    for (int n = 0; n < 2; n++) {
      const int pxl = wv * 32 + n * 16 + (lane & 15);
#pragma unroll
      for (int r = 0; r < 4; r++) {
        const int ch = m * 16 + chq + r;
        outp[(((size_t)(b * 64 + ch)) << 14) + p0 + pxl] =
            acc[m][n][r] + spar[7][ch] + (&vv[m][n].x)[r];
      }
    }
#undef LN_REG
#undef MM_STAGE
}

// ================= launcher =================
extern "C" void kernel_launch(void* const* d_in, const int* in_sizes, int n_in,
                              void* d_out, int out_size, void* d_ws, size_t ws_size,
                              hipStream_t stream)
{
  if (ws_size < WS_BYTES) return;
  char* ws = (char*)d_ws;

  const float* x       = (const float*)d_in[0];
  const float* w_down  = (const float*)d_in[1];
  const float* w_mid   = (const float*)d_in[2];
  const float* w_up    = (const float*)d_in[3];
  const float* wq_l    = (const float*)d_in[4];
  const float* wk_m    = (const float*)d_in[5];
  const float* wv_m    = (const float*)d_in[6];
  const float* wq_h    = (const float*)d_in[7];
  const float* rescale = (const float*)d_in[8];
  const float* w_proj_l= (const float*)d_in[9];
  const float* b_proj_l= (const float*)d_in[10];
  const float* w_proj_h= (const float*)d_in[11];
  const float* b_proj_h= (const float*)d_in[12];
  const float* qco_w1  = (const float*)d_in[13];
  const float* qsca_w  = (const float*)d_in[14];
  const float* qsca_b  = (const float*)d_in[15];
  const float* qt1_w   = (const float*)d_in[16];
  const float* qt1_b   = (const float*)d_in[17];
  const float* qt2_w   = (const float*)d_in[18];
  const float* qt2_b   = (const float*)d_in[19];
  const float* rsp_w1  = (const float*)d_in[20];
  const float* rsp_pr  = (const float*)d_in[21];
  const float* rsp_w2  = (const float*)d_in[22];
  const float* c31_w1  = (const float*)d_in[23];
  const float* c31_pr  = (const float*)d_in[24];
  const float* c31_w2  = (const float*)d_in[25];
  const float* c31_w3  = (const float*)d_in[26];
  const float* ln1_g   = (const float*)d_in[27];
  const float* ln1_b   = (const float*)d_in[28];
  const float* ff1_w1  = (const float*)d_in[29];
  const float* ff1_b1  = (const float*)d_in[30];
  const float* ff1_w2  = (const float*)d_in[31];
  const float* ff1_b2  = (const float*)d_in[32];
  const float* ln2_g   = (const float*)d_in[33];
  const float* ln2_b   = (const float*)d_in[34];
  const float* ff2_w1  = (const float*)d_in[35];
  const float* ff2_b1  = (const float*)d_in[36];
  const float* ff2_w2  = (const float*)d_in[37];
  const float* ff2_b2  = (const float*)d_in[38];

  bf16*  zbf   = (bf16*)(ws + OFF_ZBF);
  bf16*  wtq   = (bf16*)(ws + OFF_WTQ);
  bf16*  wtr1  = (bf16*)(ws + OFF_WTR1);
  bf16*  wtr2  = (bf16*)(ws + OFF_WTR2);
  bf16*  wtc1  = (bf16*)(ws + OFF_WTC1);
  bf16*  wtf   = (bf16*)(ws + OFF_WTF);
  float* G     = (float*)(ws + OFF_G);
  float* gpart = (float*)(ws + OFF_GPART);
  float* T1    = (float*)(ws + OFF_T1);
  float* UL    = (float*)(ws + OFF_UL);
  float* UK    = (float*)(ws + OFF_UK);
  float* T1H   = (float*)(ws + OFF_T1H);
  float* UH    = (float*)(ws + OFF_UH);
  float* norms = (float*)(ws + OFF_NORMS);
  float* attL  = (float*)(ws + OFF_ATTL);
  float* attH  = (float*)(ws + OFF_ATTH);
  float* WeL   = (float*)(ws + OFF_WEL);
  float* WeH   = (float*)(ws + OFF_WEH);
  bf16*  acatb = (bf16*)(ws + OFF_ACATB);
  float* tsum  = (float*)(ws + OFF_TSUM);
  float* attb  = (float*)(ws + OFF_ATTB);
  bf16*  hcatb = (bf16*)(ws + OFF_HCATB);
  short* hcatT = (short*)(ws + OFF_HCATT);   // aliases gpart (dead after k_gred)
  short* midb  = (short*)(ws + OFF_MIDB);
  short* houtb = (short*)(ws + OFF_HOUTB);
  float* out1  = (float*)(ws + OFF_OUT1);
  short* xt    = (short*)(ws + OFF_XT);

  // 0) prep
  k_transp<<<dim3(256, 1, 2), 256, 0, stream>>>(x, xt);
  k_prep_all<<<dim3(1728), 256, 0, stream>>>(w_down, w_mid, w_up, rsp_w1, rsp_w2, c31_w1,
                                             wtq, wtr1, wtr2, wtc1);
  k_wfoldb<<<dim3(144), 256, 0, stream>>>(c31_w3, c31_w2, wtf);

  // 1) fused QKV conv 64->384 -> Z (NCHW bf16)
  k_convq<<<dim3(128, 3, 2), 256, 0, stream>>>(xt, (const short*)wtq, zbf);

  // 2) Gram (21 unique 64-row tile pairs, mirrored) + reduce
  k_gramm<<<dim3(21, 16, 2), 256, 0, stream>>>((const short*)zbf, gpart);
  k_gred<<<dim3(1152), 256, 0, stream>>>(gpart, G);

  // QCO tap sums (needs only Z)
  k_tsum2<<<dim3(128), 256, 0, stream>>>(zbf, tsum);

  // 3) attention solve on Gram blocks (fused 5-job GEMM)
  Jobs5 J5;
  J5.A[0] = wq_l;  J5.B[0] = G + 64;              J5.C[0] = T1;  J5.K[0] = 64;  J5.lda[0] = 64;  J5.ldb[0] = 384; J5.ldc[0] = 128; J5.sB[0] = 147456; J5.sC[0] = 32768;  J5.nx[0] = 8;
  J5.A[1] = wq_l;  J5.B[1] = G;                   J5.C[1] = UL;  J5.K[1] = 64;  J5.lda[1] = 64;  J5.ldb[1] = 384; J5.ldc[1] = 64;  J5.sB[1] = 147456; J5.sC[1] = 16384;  J5.nx[1] = 4;
  J5.A[2] = wk_m;  J5.B[2] = G + 64 * 384 + 64;   J5.C[2] = UK;  J5.K[2] = 128; J5.lda[2] = 128; J5.ldb[2] = 384; J5.ldc[2] = 128; J5.sB[2] = 147456; J5.sC[2] = 65536;  J5.nx[2] = 8;
  J5.A[3] = wq_h;  J5.B[3] = G + 192 * 384 + 64;  J5.C[3] = T1H; J5.K[3] = 192; J5.lda[3] = 192; J5.ldb[3] = 384; J5.ldc[3] = 128; J5.sB[3] = 147456; J5.sC[3] = 98304;  J5.nx[3] = 8;
  J5.A[4] = wq_h;  J5.B[4] = G + 192 * 384 + 192; J5.C[4] = UH;  J5.K[4] = 192; J5.lda[4] = 192; J5.ldb[4] = 384; J5.ldc[4] = 192; J5.sB[4] = 147456; J5.sC[4] = 147456; J5.nx[4] = 12;
  J5.b0[0] = 0; J5.b0[1] = 128; J5.b0[2] = 192; J5.b0[3] = 448; J5.b0[4] = 832; J5.b0[5] = 1408;
  k_sgemm5<<<dim3(1408, 2), 256, 0, stream>>>(J5);

  k_norms2<<<dim3(768), 256, 0, stream>>>(UL, UK, UH, wq_l, wk_m, wq_h, norms);
  k_qco<<<dim3(2), 64, 0, stream>>>(tsum, qco_w1, qsca_w, qsca_b, qt1_w, qt1_b, qt2_w, qt2_b, attb);
  k_attn<<<dim3(8, 4, 2), 256, 0, stream>>>(T1, T1H, wk_m, norms, rescale, attL, attH);
  k_weff<<<dim3(8, 2, 2), 256, 0, stream>>>(attL, attH, wv_m, WeL, WeH);

  Jobs2 J2;
  J2.A[0] = w_proj_l; J2.B[0] = WeL; J2.K[0] = 256; J2.lda[0] = 256; J2.sB[0] = 32768; J2.nx[0] = 8; J2.co[0] = 0;
  J2.A[1] = w_proj_h; J2.B[1] = WeH; J2.K[1] = 768; J2.lda[1] = 768; J2.sB[1] = 98304; J2.nx[1] = 8; J2.co[1] = 8192;
  J2.b0[0] = 0; J2.b0[1] = 32; J2.b0[2] = 128;
  k_sgemm2b<<<dim3(128, 2), 256, 0, stream>>>(J2, acatb);

  // 4) per-pixel linear map -> Hcat (view-quirk LINEAR layout)
  k_pixm<<<dim3(256, 4, 2), 256, 0, stream>>>((const short*)zbf, (const short*)acatb,
                                              b_proj_l, b_proj_h, hcatb);

  // 4b) view-quirk: Hcat linear == NCHW [256][16384]; transpose to px-major for conv
  k_transph<<<dim3(256, 4, 2), 256, 0, stream>>>((const short*)hcatb, hcatT);

  // 5) ReshapeBlock: 256->64 (+prelu) then 64->64
  k_conv64<1><<<dim3(128, 2, 2), 256, 0, stream>>>(
      hcatT, 256, 4194304L, 256,
      (const short*)wtr1, midb, nullptr, rsp_pr, nullptr, nullptr, nullptr);
  k_conv64<0><<<dim3(128, 2, 2), 256, 0, stream>>>(
      midb, 64, 1048576L, 64,
      (const short*)wtr2, houtb, nullptr, nullptr, nullptr, nullptr, nullptr);

  // 7) Conv3_1 (+prelu) then folded conv + final combine -> out1 (px-major f32)
  k_conv64<1><<<dim3(128, 2, 2), 256, 0, stream>>>(
      houtb, 64, 1048576L, 64,
      (const short*)wtc1, midb, nullptr, c31_pr, nullptr, nullptr, nullptr);
  k_conv64<2><<<dim3(128, 2, 2), 256, 0, stream>>>(
      midb, 64, 1048576L, 64,
      (const short*)wtf, nullptr, out1, nullptr, houtb, attb, x);

  // 8) fused double-FF -> d_out (NCHW f32)
  k_ffm2<<<dim3(256), 256, 0, stream>>>(out1,
      ln1_g, ln1_b, ff1_w1, ff1_b1, ff1_w2, ff1_b2,
      ln2_g, ln2_b, ff2_w1, ff2_b1, ff2_w2, ff2_b2,
      (float*)d_out);
}

// Round 11
// 282.773 us; speedup vs baseline: 4.5222x; 1.0369x over previous
//
#include <hip/hip_runtime.h>
#include <hip/hip_bf16.h>
#include <stdint.h>

typedef __hip_bfloat16 bf16;
typedef __attribute__((ext_vector_type(8))) __bf16 bf8v;
typedef __attribute__((ext_vector_type(8))) short short8;
typedef __attribute__((ext_vector_type(4))) short short4v;
typedef __attribute__((ext_vector_type(4))) float f32x4;
#define DEVINL __device__ __forceinline__
#define MFMA16(a,b,c) __builtin_amdgcn_mfma_f32_16x16x32_bf16((a),(b),(c),0,0,0)

DEVINL short f2bs(float f) { bf16 h = __float2bfloat16(f); return *reinterpret_cast<short*>(&h); }
DEVINL float bs2f(short s) { bf16 h = *reinterpret_cast<bf16*>(&s); return __bfloat162float(h); }

// ---------------- problem dims ----------------
// B=2, C=64, H=W=128, n=16384, HEADS=8, DH=32. All device I/O buffers are f32.

// ---------------- workspace layout (BYTE offsets) ----------------
static const size_t OFF_ZBF   = 0;          // [2][384][16384] bf16 (QKV conv out, NCHW)
static const size_t OFF_WTQ   = 29360128;   // [9][384][64] bf16
static const size_t OFF_WTR1  = 29802496;   // [9][64][256] bf16
static const size_t OFF_WTR2  = 30097408;   // [9][64][64] bf16
static const size_t OFF_WTC1  = 30171136;   // [9][64][64] bf16
static const size_t OFF_WTF   = 30244864;   // [9][64][64] bf16 (folded c31 w3@w2)
static const size_t OFF_GB    = 31645696;   // [2][384][384] bf16 (Gram, symmetric)
static const size_t OFF_WQLB  = 32235520;   // [256][64] bf16
static const size_t OFF_WKMB  = 32268288;   // [512][128] bf16
static const size_t OFF_WQHB  = 32399360;   // [768][192] bf16
static const size_t OFF_T1    = 41082880;   // [2][256][128] f32
static const size_t OFF_UL    = 41345024;   // [2][256][64] f32
static const size_t OFF_UK    = 41476096;   // [2][512][128] f32
static const size_t OFF_T1H   = 42000384;   // [2][768][128] f32
static const size_t OFF_UH    = 42786816;   // [2][768][192] f32
static const size_t OFF_NORMS = 43966464;   // [2][1536] f32
static const size_t OFF_ATTL  = 43978752;   // [2][8][32][64] f32
static const size_t OFF_ATTH  = 44109824;   // [2][8][96][64] f32
static const size_t OFF_WEL   = 44503040;   // [2][256][128] f32
static const size_t OFF_WEH   = 44765184;   // [2][768][128] f32
static const size_t OFF_ACATB = 45813760;   // [2][256][128] bf16
static const size_t OFF_TSUM  = 45944832;   // [2][64][9] f32
static const size_t OFF_ATTB  = 45949440;   // [2][64] f32
static const size_t OFF_HCATB = 45949952;   // [2][4194304] bf16 (view-quirk LINEAR layout)
static const size_t OFF_MIDB  = 62727168;   // [2][16384][64] bf16 (px-major)
static const size_t OFF_HOUTB = 66921472;   // [2][16384][64] bf16 (px-major)
static const size_t OFF_OUT1  = 71115776;   // [2][16384][64] f32 (px-major)
static const size_t OFF_GPART = 79504384;   // [16][2][384][384] f32 ; ALSO (later) hcatT
static const size_t OFF_HCATT = 79504384;   // [2][16384][256] bf16 (aliases GPART, dead by then)
static const size_t OFF_XT    = 98378752;   // [2][16384][64] bf16 (x transposed)
static const size_t WS_BYTES  = 102573056;

// ================= prep kernels =================
// x [b][64][16384] f32 -> xt [b][16384][64] bf16
__global__ __launch_bounds__(256) void k_transp(const float* __restrict__ x,
                                                short* __restrict__ xt) {
  __shared__ short sT[64][72];
  const int t = threadIdx.x, b = blockIdx.z, p0 = blockIdx.x * 64;
  for (int i = t; i < 1024; i += 256) {
    int c = i >> 4, p4 = (i & 15) * 4;
    float4 g = *(const float4*)&x[(((size_t)(b * 64 + c)) << 14) + p0 + p4];
    sT[p4 + 0][c] = f2bs(g.x);
    sT[p4 + 1][c] = f2bs(g.y);
    sT[p4 + 2][c] = f2bs(g.z);
    sT[p4 + 3][c] = f2bs(g.w);
  }
  __syncthreads();
  for (int i = t; i < 512; i += 256) {
    int p = i >> 3, co = (i & 7) * 8;
    *(short8*)&xt[((((size_t)b << 14) + p0 + p)) * 64 + co] = *(short8*)&sT[p][co];
  }
}

// hcat LINEAR (quirk view = NCHW [b][256][16384]) bf16 -> hcatT [b][16384][256] bf16
__global__ __launch_bounds__(256) void k_transph(const short* __restrict__ hc,
                                                 short* __restrict__ ht) {
  __shared__ short sT[64][72];
  const int t = threadIdx.x, b = blockIdx.z, p0 = blockIdx.x * 64, c0 = blockIdx.y * 64;
  for (int i = t; i < 512; i += 256) {
    int c = i >> 3, qo = (i & 7) * 8;
    short8 v = *(const short8*)&hc[(((size_t)(b * 256 + c0 + c)) << 14) + p0 + qo];
#pragma unroll
    for (int u = 0; u < 8; u++) sT[qo + u][c] = v[u];
  }
  __syncthreads();
  for (int i = t; i < 512; i += 256) {
    int q = i >> 3, co = (i & 7) * 8;
    *(short8*)&ht[((size_t)(b * 16384 + p0 + q)) * 256 + c0 + co] = *(short8*)&sT[q][co];
  }
}

// fused weight transforms (+bf16 copies of attention weights)
__global__ void k_prep_all(const float* __restrict__ wd, const float* __restrict__ wm,
                           const float* __restrict__ wu, const float* __restrict__ rw1,
                           const float* __restrict__ rw2, const float* __restrict__ cw1,
                           const float* __restrict__ wql, const float* __restrict__ wkm,
                           const float* __restrict__ wqh,
                           bf16* __restrict__ wtq, bf16* __restrict__ wtr1,
                           bf16* __restrict__ wtr2, bf16* __restrict__ wtc1,
                           bf16* __restrict__ wqlb, bf16* __restrict__ wkmb,
                           bf16* __restrict__ wqhb) {
  int i = blockIdx.x * 256 + threadIdx.x;
  if (i < 221184) {
    int tap = i / 24576, r = i % 24576, oc = r >> 6, ic = r & 63;
    float v;
    if (oc < 64)       v = wd[(oc * 64 + ic) * 9 + tap];
    else if (oc < 192) v = wm[((oc - 64) * 64 + ic) * 9 + tap];
    else               v = wu[((oc - 192) * 64 + ic) * 9 + tap];
    wtq[i] = __float2bfloat16(v);
  } else if (i < 368640) {
    int j = i - 221184;
    int tap = j / 16384, r = j % 16384, oc = r >> 8, ic = r & 255;
    wtr1[j] = __float2bfloat16(rw1[(oc * 256 + ic) * 9 + tap]);
  } else if (i < 405504) {
    int j = i - 368640;
    int tap = j / 4096, r = j % 4096, oc = r >> 6, ic = r & 63;
    wtr2[j] = __float2bfloat16(rw2[(oc * 64 + ic) * 9 + tap]);
  } else if (i < 442368) {
    int j = i - 405504;
    int tap = j / 4096, r = j % 4096, oc = r >> 6, ic = r & 63;
    wtc1[j] = __float2bfloat16(cw1[(oc * 64 + ic) * 9 + tap]);
  } else if (i < 458752) {
    int j = i - 442368; wqlb[j] = __float2bfloat16(wql[j]);
  } else if (i < 524288) {
    int j = i - 458752; wkmb[j] = __float2bfloat16(wkm[j]);
  } else if (i < 671744) {
    int j = i - 524288; wqhb[j] = __float2bfloat16(wqh[j]);
  }
}

// wtf[tap][o][ic] = bf16( sum_m c31_w3[o][m] * c31_w2[m][ic][tap] )
__global__ void k_wfoldb(const float* __restrict__ w3, const float* __restrict__ w2,
                         bf16* __restrict__ wtf) {
  int i = blockIdx.x * 256 + threadIdx.x;
  if (i >= 36864) return;
  int tap = i / 4096, r = i % 4096, o = r >> 6, ic = r & 63;
  float s = 0.f;
  for (int m = 0; m < 64; m++)
    s = fmaf(w3[o * 64 + m], w2[(m * 64 + ic) * 9 + tap], s);
  wtf[i] = __float2bfloat16(s);
}

// ================= QKV conv 64->384 (zero pad), direct-A MFMA =================
__global__ __launch_bounds__(256) void k_convq(
    const short* __restrict__ xt, const short* __restrict__ wtq,
    bf16* __restrict__ zbf)
{
  __shared__ short sX[3][130][72];
  const int t = threadIdx.x, lane = t & 63, wv = t >> 6;
  const int y = blockIdx.x, ocg = blockIdx.y, b = blockIdx.z;

  for (int i = t; i < 3120; i += 256) {
    int col = i % 130, rr = i / 130, row = rr % 3, ko = rr / 3;
    int gy = y + row - 1, gx = col - 1;
    short8 vv;
    if ((gy >= 0) & (gy < 128) & (gx >= 0) & (gx < 128)) {
      vv = *(const short8*)&xt[((size_t)b * 1048576 + (size_t)((gy << 7) + gx) * 64) + ko * 8];
    } else {
#pragma unroll
      for (int u = 0; u < 8; u++) vv[u] = 0;
    }
    *(short8*)&sX[row][col][ko * 8] = vv;
  }
  __syncthreads();

  const f32x4 zero = {0.f, 0.f, 0.f, 0.f};
  f32x4 acc[2][8];
#pragma unroll
  for (int m = 0; m < 2; m++)
#pragma unroll
    for (int n = 0; n < 8; n++) acc[m][n] = zero;

#pragma unroll
  for (int tap = 0; tap < 9; tap++) {
    const int ky = tap / 3, kx = tap % 3;
#pragma unroll
    for (int kk = 0; kk < 2; kk++) {
      const int kb = kk * 32 + (lane >> 4) * 8;
      bf8v a0 = *(const bf8v*)&wtq[(size_t)((tap * 384 + ocg * 128 + wv * 32 + (lane & 15)) * 64) + kb];
      bf8v a1 = *(const bf8v*)&wtq[(size_t)((tap * 384 + ocg * 128 + wv * 32 + 16 + (lane & 15)) * 64) + kb];
#pragma unroll
      for (int n = 0; n < 8; n++) {
        bf8v bfr = *(const bf8v*)&sX[ky][n * 16 + (lane & 15) + kx][kb];
        acc[0][n] = MFMA16(a0, bfr, acc[0][n]);
        acc[1][n] = MFMA16(a1, bfr, acc[1][n]);
      }
    }
  }
#pragma unroll
  for (int m = 0; m < 2; m++) {
    const int oc0 = ocg * 128 + wv * 32 + m * 16 + ((lane >> 4) << 2);
#pragma unroll
    for (int n = 0; n < 8; n++) {
      const int px = n * 16 + (lane & 15);
#pragma unroll
      for (int r = 0; r < 4; r++)
        zbf[(((size_t)(b * 384 + oc0 + r)) << 14) + (y << 7) + px] = __float2bfloat16(acc[m][n][r]);
    }
  }
}

// ================= 3x3 reflect conv -> 64 out (direct-A MFMA, px-major IO) =================
template<int EPI>
__global__ __launch_bounds__(256) void k_conv64(
    const short* __restrict__ in, int str, long bstride, int Cin,
    const short* __restrict__ Wt,
    short* __restrict__ outb, float* __restrict__ outf,
    const float* __restrict__ prelu_a,
    const short* __restrict__ houtpm, const float* __restrict__ attb,
    const float* __restrict__ x_nchw)
{
  __shared__ short sX[3][66][72];
  const int t = threadIdx.x, lane = t & 63, wv = t >> 6;
  const int y = blockIdx.x, x0 = blockIdx.y * 64, b = blockIdx.z;

  const f32x4 zero = {0.f, 0.f, 0.f, 0.f};
  f32x4 acc[4] = {zero, zero, zero, zero};

  for (int icb = 0; icb < Cin; icb += 64) {
    __syncthreads();
    for (int i = t; i < 1584; i += 256) {
      int col = i % 66, rr = i / 66, row = rr % 3, ko = rr / 3;
      int gy = y + row - 1, gx = x0 + col - 1;
      gy = gy < 0 ? 1 : (gy > 127 ? 126 : gy);
      gx = gx < 0 ? 1 : (gx > 127 ? 126 : gx);
      *(short8*)&sX[row][col][ko * 8] =
          *(const short8*)&in[(size_t)b * bstride + (size_t)((gy << 7) + gx) * str + icb + ko * 8];
    }
    __syncthreads();
#pragma unroll
    for (int tap = 0; tap < 9; tap++) {
      const int ky = tap / 3, kx = tap % 3;
#pragma unroll
      for (int kk = 0; kk < 2; kk++) {
        const int kb = kk * 32 + (lane >> 4) * 8;
        bf8v afr = *(const bf8v*)&Wt[(size_t)(tap * 64 + wv * 16 + (lane & 15)) * Cin + icb + kb];
#pragma unroll
        for (int n = 0; n < 4; n++) {
          bf8v bfr = *(const bf8v*)&sX[ky][n * 16 + (lane & 15) + kx][kb];
          acc[n] = MFMA16(afr, bfr, acc[n]);
        }
      }
    }
  }
  const int oc0 = wv * 16 + ((lane >> 4) << 2);
  const float aP = (EPI == 1) ? prelu_a[0] : 0.f;
#pragma unroll
  for (int n = 0; n < 4; n++) {
    const int gpx = (y << 7) + x0 + n * 16 + (lane & 15);
    if (EPI == 2) {
      short4v hv = *(const short4v*)&houtpm[((size_t)(b * 16384 + gpx)) * 64 + oc0];
      float4 av = *(const float4*)&attb[b * 64 + oc0];
      float4 o;
#pragma unroll
      for (int r = 0; r < 4; r++)
        (&o.x)[r] = acc[n][r] + bs2f(hv[r]) * (&av.x)[r] +
                    x_nchw[(((size_t)(b * 64 + oc0 + r)) << 14) + gpx];
      *(float4*)&outf[((size_t)(b * 16384 + gpx)) * 64 + oc0] = o;
    } else {
      short4v ss;
#pragma unroll
      for (int r = 0; r < 4; r++) {
        float v = acc[n][r];
        if (EPI == 1) v = v > 0.f ? v : aP * v;
        ss[r] = f2bs(v);
      }
      *(short4v*)&outb[((size_t)(b * 16384 + gpx)) * 64 + oc0] = ss;
    }
  }
}

// ======= Gram via MFMA: G[b] = Z Z^T (21 unique 64-row tile pairs + mirror) =======
__global__ __launch_bounds__(256) void k_gramm(const short* __restrict__ Z,
                                               float* __restrict__ Gp) {
  int rem = blockIdx.x, ti = 0;
  while (rem >= 6 - ti) { rem -= 6 - ti; ti++; }
  const int tj = ti + rem;
  const int kc = blockIdx.y, b = blockIdx.z;
  __shared__ short sA[64][72];
  __shared__ short sB[64][72];
  const int t = threadIdx.x, lane = t & 63, wv = t >> 6;
  const int wo = wv & 1, wp = wv >> 1;
  const f32x4 zero = {0.f, 0.f, 0.f, 0.f};
  f32x4 acc[2][2];
#pragma unroll
  for (int m = 0; m < 2; m++)
#pragma unroll
    for (int n = 0; n < 2; n++) acc[m][n] = zero;
  const size_t zb = (size_t)b * 6291456;
  const int k0 = kc * 1024;
  for (int ks = 0; ks < 1024; ks += 64) {
    __syncthreads();
    for (int i = t; i < 512; i += 256) {
      int r = i >> 3, ko = i & 7;
      *(short8*)&sA[r][ko * 8] =
          *(const short8*)&Z[zb + ((size_t)(ti * 64 + r) << 14) + k0 + ks + ko * 8];
      *(short8*)&sB[r][ko * 8] =
          *(const short8*)&Z[zb + ((size_t)(tj * 64 + r) << 14) + k0 + ks + ko * 8];
    }
    __syncthreads();
#pragma unroll
    for (int kk = 0; kk < 2; kk++) {
      const int kb = kk * 32 + (lane >> 4) * 8;
      bf8v bfr[2];
#pragma unroll
      for (int n = 0; n < 2; n++)
        bfr[n] = *(const bf8v*)&sB[wp * 32 + n * 16 + (lane & 15)][kb];
#pragma unroll
      for (int m = 0; m < 2; m++) {
        bf8v afr = *(const bf8v*)&sA[wo * 32 + m * 16 + (lane & 15)][kb];
#pragma unroll
        for (int n = 0; n < 2; n++)
          acc[m][n] = MFMA16(afr, bfr[n], acc[m][n]);
      }
    }
  }
  float* gp = Gp + ((size_t)(kc * 2 + b)) * 147456;
#pragma unroll
  for (int m = 0; m < 2; m++)
#pragma unroll
    for (int n = 0; n < 2; n++)
#pragma unroll
      for (int r = 0; r < 4; r++) {
        const int row = ti * 64 + wo * 32 + m * 16 + ((lane >> 4) << 2) + r;
        const int col = tj * 64 + wp * 32 + n * 16 + (lane & 15);
        float v = acc[m][n][r];
        gp[(size_t)row * 384 + col] = v;
        if (ti != tj) gp[(size_t)col * 384 + row] = v;
      }
}

// reduce partials -> bf16 Gb (G only feeds the MFMA solve chain)
__global__ void k_gredb(const float* __restrict__ Gp, bf16* __restrict__ Gb) {
  int i = blockIdx.x * 256 + threadIdx.x;
  if (i >= 294912) return;
  int b = i / 147456, e = i % 147456;
  float s = 0.f;
#pragma unroll
  for (int c = 0; c < 16; c++) s += Gp[(size_t)(c * 2 + b) * 147456 + e];
  Gb[(size_t)b * 147456 + e] = __float2bfloat16(s);
}

// ======= MFMA solve chain (5 jobs): C = W[M,K] * G[r0:r0+K, c0:c0+N] =======
// Uses G symmetry: B-fragment [n][k] = Gb[c0+n][r0+k] (row-contiguous).
struct MJobs5 {
  const short* A[5];
  float* C[5];
  int lda[5], K[5], r0[5], c0[5], ldc[5];
  long sC[5];
  int nx[5], b0[6];
};

__global__ __launch_bounds__(256) void k_mgemm5(MJobs5 J, const short* __restrict__ Gb) {
  const int bx = blockIdx.x, z = blockIdx.y;
  int j = 0;
  while (bx >= J.b0[j + 1]) j++;
  const int local = bx - J.b0[j];
  const int xn = local % J.nx[j], ym = local / J.nx[j];
  const int t = threadIdx.x, lane = t & 63, wv = t >> 6;
  const short* Gp = Gb + (size_t)z * 147456;
  const short* Ap = J.A[j];
  const int K = J.K[j], lda = J.lda[j];
  const int m0 = ym * 64 + wv * 16, n0 = xn * 64;
  const int gc0 = J.c0[j] + n0, r0 = J.r0[j];
  const f32x4 zero = {0.f, 0.f, 0.f, 0.f};
  f32x4 acc[4] = {zero, zero, zero, zero};
  for (int kk = 0; kk < K; kk += 32) {
    const int kb = kk + (lane >> 4) * 8;
    bf8v afr = *(const bf8v*)&Ap[(size_t)(m0 + (lane & 15)) * lda + kb];
#pragma unroll
    for (int n = 0; n < 4; n++) {
      bf8v bfr = *(const bf8v*)&Gp[(size_t)(gc0 + n * 16 + (lane & 15)) * 384 + r0 + kb];
      acc[n] = MFMA16(afr, bfr, acc[n]);
    }
  }
  float* Cp = J.C[j] + (size_t)z * J.sC[j];
  const int mq = m0 + ((lane >> 4) << 2);
#pragma unroll
  for (int n = 0; n < 4; n++) {
    const int nc = n0 + n * 16 + (lane & 15);
#pragma unroll
    for (int r = 0; r < 4; r++)
      Cp[(size_t)(mq + r) * J.ldc[j] + nc] = acc[n][r];
  }
}

// ================= per-pixel map via MFMA (view-quirk LINEAR output) =================
__global__ __launch_bounds__(256) void k_pixm(
    const short* __restrict__ Z, const short* __restrict__ Acatb,
    const float* __restrict__ bl, const float* __restrict__ bh,
    bf16* __restrict__ hcat)
{
  const int p0 = blockIdx.x * 64, ocg = blockIdx.y, b = blockIdx.z;
  __shared__ short sA[64][136];
  __shared__ short sB[64][136];
  const int t = threadIdx.x, lane = t & 63, wv = t >> 6;
  for (int i = t; i < 1024; i += 256) {
    int oc = i >> 4, ko = i & 15;
    *(short8*)&sA[oc][ko * 8] =
        *(const short8*)&Acatb[((size_t)(b * 256 + ocg * 64 + oc)) * 128 + ko * 8];
  }
  for (int i = t; i < 1024; i += 256) {
    int px = i & 63, ko = i >> 6;
    short8 vv;
#pragma unroll
    for (int u = 0; u < 8; u++)
      vv[u] = Z[((size_t)(b * 384 + 64 + ko * 8 + u) << 14) + p0 + px];
    *(short8*)&sB[px][ko * 8] = vv;
  }
  __syncthreads();
  const f32x4 zero = {0.f, 0.f, 0.f, 0.f};
  f32x4 acc[4] = {zero, zero, zero, zero};
#pragma unroll
  for (int kk = 0; kk < 4; kk++) {
    const int kb = kk * 32 + (lane >> 4) * 8;
    bf8v afr = *(const bf8v*)&sA[wv * 16 + (lane & 15)][kb];
#pragma unroll
    for (int n = 0; n < 4; n++) {
      bf8v bfr = *(const bf8v*)&sB[n * 16 + (lane & 15)][kb];
      acc[n] = MFMA16(afr, bfr, acc[n]);
    }
  }
  const size_t hbase = (size_t)b * 4194304;
#pragma unroll
  for (int n = 0; n < 4; n++) {
    const int px = p0 + n * 16 + (lane & 15);
#pragma unroll
    for (int r = 0; r < 4; r++) {
      const int oc = ocg * 64 + wv * 16 + ((lane >> 4) << 2) + r;
      float v = acc[n][r] + (oc < 64 ? bl[oc] : bh[oc - 64]);
      size_t addr = (oc < 64) ? hbase + (size_t)px * 64 + oc
                              : hbase + 1048576 + (size_t)px * 192 + (oc - 64);
      hcat[addr] = __float2bfloat16(v);
    }
  }
}

// ================= proj GEMMs (2 jobs) -> bf16 Acat =================
struct Jobs2 {
  const float* A[2]; const float* B[2];
  int K[2]; int lda[2];
  long sB[2];
  int nx[2]; int b0[3]; int co[2];
};

__global__ __launch_bounds__(256) void k_sgemm2b(Jobs2 J, bf16* __restrict__ Cb) {
  __shared__ float sa[16][17];
  __shared__ float sb[16][17];
  const int bx = blockIdx.x, z = blockIdx.y;
  int j = (bx >= J.b0[1]) ? 1 : 0;
  const int local = bx - J.b0[j];
  const int x = local % J.nx[j], y = local / J.nx[j];
  const int tx = threadIdx.x & 15, ty = threadIdx.x >> 4;
  const float* Ap = J.A[j];
  const float* Bp = J.B[j] + (size_t)z * J.sB[j];
  const int K = J.K[j], lda = J.lda[j];
  const int m = y * 16 + ty, n = x * 16 + tx;
  float acc = 0.f;
  for (int k0 = 0; k0 < K; k0 += 16) {
    sa[ty][tx] = Ap[(size_t)m * lda + k0 + tx];
    sb[ty][tx] = Bp[(size_t)(k0 + ty) * 128 + n];
    __syncthreads();
#pragma unroll
    for (int kk = 0; kk < 16; kk++) acc = fmaf(sa[ty][kk], sb[kk][tx], acc);
    __syncthreads();
  }
  Cb[(size_t)z * 32768 + J.co[j] + (size_t)m * 128 + n] = __float2bfloat16(acc);
}

// ================= norms: one wave per row, coalesced + shuffle reduce =================
__global__ __launch_bounds__(256) void k_norms2(
    const float* __restrict__ UL, const float* __restrict__ UK,
    const float* __restrict__ UH,
    const float* __restrict__ wql, const float* __restrict__ wkm,
    const float* __restrict__ wqh, float* __restrict__ norms) {
  const int t = threadIdx.x, lane = t & 63;
  const int row = blockIdx.x * 4 + (t >> 6);   // 0..3071
  const int b = row >> 11 ? 1 : (row >= 1536 ? 1 : 0);
  const int r = row - b * 1536;
  const float* u; const float* wv; int K;
  if (r < 256)      { K = 64;  u = UL + (size_t)(b * 256 + r) * 64;          wv = wql + (size_t)r * 64; }
  else if (r < 768) { int e = r - 256; K = 128; u = UK + (size_t)(b * 512 + e) * 128; wv = wkm + (size_t)e * 128; }
  else              { int d = r - 768; K = 192; u = UH + (size_t)(b * 768 + d) * 192; wv = wqh + (size_t)d * 192; }
  float s = 0.f;
  for (int k = lane; k < K; k += 64) s = fmaf(u[k], wv[k], s);
#pragma unroll
  for (int o = 32; o; o >>= 1) s += __shfl_xor(s, o);
  if (lane == 0) norms[b * 1536 + r] = fmaxf(sqrtf(fmaxf(s, 0.f)), 1e-12f);
}

// ================= attention logits + softmax =================
__global__ __launch_bounds__(256) void k_attn(
    const float* __restrict__ T1, const float* __restrict__ T1H,
    const float* __restrict__ wkm, const float* __restrict__ norms,
    const float* __restrict__ rescale,
    float* __restrict__ attL, float* __restrict__ attH)
{
  const int h = blockIdx.x, cy = blockIdx.y, b = blockIdx.z;
  const int t = threadIdx.x;
  __shared__ float sK[64 * 129];
  __shared__ float sQ[32 * 129];
  __shared__ float sNk[64];
  const int isL = (cy == 0);
  const int rbase = isL ? 0 : (cy - 1) * 32;
  const float* TQ = isL ? (T1 + (size_t)(b * 256 + h * 32) * 128)
                        : (T1H + (size_t)(b * 768 + h * 96 + rbase) * 128);
  for (int idx = t; idx < 8192; idx += 256) {
    int e = idx >> 7, k = idx & 127;
    sK[e * 129 + k] = wkm[(size_t)(h * 64 + e) * 128 + k];
  }
  for (int idx = t; idx < 4096; idx += 256) {
    int r = idx >> 7, k = idx & 127;
    sQ[r * 129 + k] = TQ[(size_t)r * 128 + k];
  }
  if (t < 64) sNk[t] = norms[b * 1536 + 256 + h * 64 + t];
  __syncthreads();

  const int w = t >> 6, lane = t & 63;
  const float rs = rescale[h];
  for (int r = w; r < 32; r += 4) {
    float s = 0.f;
    for (int k = 0; k < 128; k++) s = fmaf(sQ[r * 129 + k], sK[lane * 129 + k], s);
    float nq = norms[b * 1536 + (isL ? (h * 32 + r) : (768 + h * 96 + rbase + r))];
    float logit = s / (nq * sNk[lane]) * rs;
    float m = logit;
#pragma unroll
    for (int o = 32; o; o >>= 1) m = fmaxf(m, __shfl_xor(m, o));
    float p = __expf(logit - m);
    float den = p;
#pragma unroll
    for (int o = 32; o; o >>= 1) den += __shfl_xor(den, o);
    float av = p / den;
    if (isL) attL[((size_t)(b * 8 + h) * 32 + r) * 64 + lane] = av;
    else     attH[((size_t)(b * 8 + h) * 96 + rbase + r) * 64 + lane] = av;
  }
}

// ================= Weff = attn @ wv (per head) =================
__global__ __launch_bounds__(256) void k_weff(
    const float* __restrict__ attL, const float* __restrict__ attH,
    const float* __restrict__ wvm,
    float* __restrict__ WeL, float* __restrict__ WeH)
{
  const int h = blockIdx.x, br = blockIdx.y, b = blockIdx.z;
  const int M = br ? 96 : 32;
  __shared__ float sAt[96 * 64];
  __shared__ float sV[64 * 132];
  const int t = threadIdx.x;
  const float* asrc = br ? attH + (size_t)(b * 8 + h) * 96 * 64
                         : attL + (size_t)(b * 8 + h) * 32 * 64;
  for (int idx = t; idx < M * 64; idx += 256) sAt[idx] = asrc[idx];
  for (int idx = t; idx < 8192; idx += 256) {
    int e = idx >> 7, k = idx & 127;
    sV[e * 132 + k] = wvm[(size_t)(h * 64 + e) * 128 + k];
  }
  __syncthreads();
  const int jg = t & 31, rw = t >> 5;
  float* dst = br ? WeH + (size_t)(b * 768 + h * 96) * 128
                  : WeL + (size_t)(b * 256 + h * 32) * 128;
  for (int r = rw; r < M; r += 8) {
    float4 acc = make_float4(0.f, 0.f, 0.f, 0.f);
    for (int e = 0; e < 64; e++) {
      float a = sAt[r * 64 + e];
      float4 v4 = *(const float4*)&sV[e * 132 + jg * 4];
      acc.x = fmaf(a, v4.x, acc.x);
      acc.y = fmaf(a, v4.y, acc.y);
      acc.z = fmaf(a, v4.z, acc.z);
      acc.w = fmaf(a, v4.w, acc.w);
    }
    *(float4*)&dst[(size_t)r * 128 + jg * 4] = acc;
  }
}

// ================= QCO tap sums, separable (one vectorized pass) =================
__global__ __launch_bounds__(256) void k_tsum2(const bf16* __restrict__ Z,
                                               float* __restrict__ Tsum) {
  const int c = blockIdx.x & 63, b = blockIdx.x >> 6;
  const bf16* src = Z + (((size_t)(b * 384 + c)) << 14);
  const int t = threadIdx.x;
  __shared__ float sc[16];
  __shared__ float red[4][9];
  float a9[9] = {};
  for (int i = t; i < 2048; i += 256) {
    int y = i >> 4, x0 = (i & 15) * 8;
    short8 v8 = *(const short8*)&src[(y << 7) + x0];
    float vs[8], s8 = 0.f;
#pragma unroll
    for (int u = 0; u < 8; u++) { vs[u] = bs2f(v8[u]); s8 += vs[u]; }
    a9[0] += s8;
    int ri = (y == 0) ? 0 : (y == 1) ? 1 : (y == 126) ? 2 : (y == 127) ? 3 : -1;
    if (ri >= 0) a9[1 + ri] += s8;
    if (x0 == 0)   { a9[5] += vs[0]; a9[6] += vs[1]; }
    if (x0 == 120) { a9[7] += vs[6]; a9[8] += vs[7]; }
    if (ri >= 0) {
      if (x0 == 0)   { sc[ri * 4 + 0] = vs[0]; sc[ri * 4 + 1] = vs[1]; }
      if (x0 == 120) { sc[ri * 4 + 2] = vs[6]; sc[ri * 4 + 3] = vs[7]; }
    }
  }
#pragma unroll
  for (int q = 0; q < 9; q++)
#pragma unroll
    for (int o = 32; o; o >>= 1) a9[q] += __shfl_xor(a9[q], o);
  const int w = t >> 6;
  if ((t & 63) == 0)
#pragma unroll
    for (int q = 0; q < 9; q++) red[w][q] = a9[q];
  __syncthreads();
  if (t == 0) {
    float s9[9];
#pragma unroll
    for (int q = 0; q < 9; q++) s9[q] = red[0][q] + red[1][q] + red[2][q] + red[3][q];
    const float T = s9[0];
    float R[4] = {s9[1], s9[2], s9[3], s9[4]};
    const float C0 = s9[5], C1 = s9[6], C126 = s9[7], C127 = s9[8];
    float rs[4][3];
#pragma unroll
    for (int ri = 0; ri < 4; ri++) {
      rs[ri][0] = R[ri] - sc[ri * 4 + 3] + sc[ri * 4 + 1];
      rs[ri][1] = R[ri];
      rs[ri][2] = R[ri] - sc[ri * 4 + 0] + sc[ri * 4 + 2];
    }
    float A3[3] = {T - C127 + C1, T, T - C0 + C126};
#pragma unroll
    for (int dx = 0; dx < 3; dx++) {
      Tsum[blockIdx.x * 9 + 0 * 3 + dx] = A3[dx] - rs[3][dx] + rs[1][dx];
      Tsum[blockIdx.x * 9 + 1 * 3 + dx] = A3[dx];
      Tsum[blockIdx.x * 9 + 2 * 3 + dx] = A3[dx] - rs[0][dx] + rs[2][dx];
    }
  }
}

// ================= QCO tail (per batch, 64 threads) =================
__global__ __launch_bounds__(64) void k_qco(
    const float* __restrict__ Tsum, const float* __restrict__ w1,
    const float* __restrict__ scaw, const float* __restrict__ scab,
    const float* __restrict__ t1w, const float* __restrict__ t1b,
    const float* __restrict__ t2w, const float* __restrict__ t2b,
    float* __restrict__ attb)
{
  const int b = blockIdx.x, c = threadIdx.x;
  __shared__ float sm[64], sxq[64], scat[128], sh1[64];
  float acc = 0.f;
  for (int j = 0; j < 64; j++) {
#pragma unroll
    for (int tap = 0; tap < 9; tap++)
      acc = fmaf(w1[(c * 64 + j) * 9 + tap], Tsum[(b * 64 + j) * 9 + tap], acc);
  }
  sm[c] = acc * (1.f / 16384.f);
  __syncthreads();
  float xa = scab[c];
  for (int j = 0; j < 64; j++) xa = fmaf(scaw[c * 64 + j], sm[j], xa);
  sxq[c] = xa;
  __syncthreads();
  float mn = xa, mx = xa;
#pragma unroll
  for (int o = 32; o; o >>= 1) {
    mn = fminf(mn, __shfl_xor(mn, o));
    mx = fmaxf(mx, __shfl_xor(mx, o));
  }
  float inter = (mx - mn) * (1.f / 64.f);
  float ql = (2.f * c + 1.f) / 128.f * (mx - mn) + mn;
  float sta = 0.f;
  for (int j = 0; j < 64; j++) {
    float q = 1.f - fabsf(ql - sxq[j]);
    sta += (q > 1.f - inter) ? q : 0.f;
  }
  float tot = sta;
#pragma unroll
  for (int o = 32; o; o >>= 1) tot += __shfl_xor(tot, o);
  sta = sta / fmaxf(tot, 1e-30f);
  scat[c] = sta; scat[64 + c] = xa;
  __syncthreads();
  float h = t1b[c];
  for (int j = 0; j < 128; j++) h = fmaf(t1w[c * 128 + j], scat[j], h);
  h = fmaxf(h, 0.f);
  sh1[c] = h;
  __syncthreads();
  float o2 = t2b[c];
  for (int j = 0; j < 64; j++) o2 = fmaf(t2w[c * 64 + j], sh1[j], o2);
  attb[b * 64 + c] = fmaxf(o2, 0.f);
}

// ================= MFMA fused double-FF (register residual + in-reg LN) =================
__global__ __launch_bounds__(256) void k_ffm2(const float* __restrict__ out1pm,
    const float* g1, const float* be1, const float* w11, const float* b11,
    const float* w12, const float* b12,
    const float* g2, const float* be2, const float* w21, const float* b21,
    const float* w22, const float* b22,
    float* __restrict__ outp)
{
  __shared__ short sW4[4][64][72];
  __shared__ short sy[128][72];
  __shared__ float spar[8][64];

  const int t = threadIdx.x, lane = t & 63, wv = t >> 6;
  const int gp0 = blockIdx.x * 128;
  const int b = gp0 >> 14, p0 = gp0 & 16383;
  const int chq = ((lane >> 4) << 2);

  for (int idx = t; idx < 4096; idx += 256) {
    int oc = idx >> 6, k = idx & 63;
    sW4[0][oc][k] = f2bs(w11[idx]);
    sW4[1][oc][k] = f2bs(w12[idx]);
    sW4[2][oc][k] = f2bs(w21[idx]);
    sW4[3][oc][k] = f2bs(w22[idx]);
  }
  if (t < 64) {
    spar[0][t] = g1[t]; spar[1][t] = be1[t]; spar[2][t] = b11[t]; spar[3][t] = b12[t];
    spar[4][t] = g2[t]; spar[5][t] = be2[t]; spar[6][t] = b21[t]; spar[7][t] = b22[t];
  }
  float4 vv[4][2];
#pragma unroll
  for (int m = 0; m < 4; m++)
#pragma unroll
    for (int n = 0; n < 2; n++) {
      const int px = p0 + wv * 32 + n * 16 + (lane & 15);
      vv[m][n] = *(const float4*)&out1pm[((size_t)(b * 16384 + px)) * 64 + m * 16 + chq];
    }
  __syncthreads();

  const f32x4 zero = {0.f, 0.f, 0.f, 0.f};
  f32x4 acc[4][2];

#define LN_REG(SRCV, GI, BI)                                                     \
  {                                                                              \
    _Pragma("unroll")                                                            \
    for (int n = 0; n < 2; n++) {                                                \
      float s1 = 0.f, s2 = 0.f;                                                  \
      _Pragma("unroll")                                                          \
      for (int m = 0; m < 4; m++)                                                \
        _Pragma("unroll")                                                        \
        for (int r = 0; r < 4; r++) {                                            \
          float vx = (&SRCV[m][n].x)[r];                                         \
          s1 += vx; s2 += vx * vx;                                               \
        }                                                                        \
      s1 += __shfl_xor(s1, 16); s1 += __shfl_xor(s1, 32);                        \
      s2 += __shfl_xor(s2, 16); s2 += __shfl_xor(s2, 32);                        \
      float mu = s1 * (1.f / 64.f);                                              \
      float var = fmaxf(s2 * (1.f / 64.f) - mu * mu, 0.f);                       \
      float rstd = 1.f / sqrtf(var + 1e-5f);                                     \
      const int pxl = wv * 32 + n * 16 + (lane & 15);                            \
      _Pragma("unroll")                                                          \
      for (int m = 0; m < 4; m++) {                                              \
        short4v ss;                                                              \
        _Pragma("unroll")                                                        \
        for (int r = 0; r < 4; r++) {                                            \
          int ch = m * 16 + chq + r;                                             \
          ss[r] = f2bs(((&SRCV[m][n].x)[r] - mu) * rstd * spar[GI][ch] + spar[BI][ch]); \
        }                                                                        \
        *(short4v*)&sy[pxl][m * 16 + chq] = ss;                                  \
      }                                                                          \
    }                                                                            \
  }

#define MM_STAGE(SIDX)                                                           \
  {                                                                              \
    _Pragma("unroll")                                                            \
    for (int m = 0; m < 4; m++) { acc[m][0] = zero; acc[m][1] = zero; }          \
    _Pragma("unroll")                                                            \
    for (int kk = 0; kk < 2; kk++) {                                             \
      const int kb = kk * 32 + (lane >> 4) * 8;                                  \
      bf8v bfr0 = *(const bf8v*)&sy[wv * 32 + (lane & 15)][kb];                  \
      bf8v bfr1 = *(const bf8v*)&sy[wv * 32 + 16 + (lane & 15)][kb];             \
      _Pragma("unroll")                                                          \
      for (int m = 0; m < 4; m++) {                                              \
        bf8v afr = *(const bf8v*)&sW4[SIDX][m * 16 + (lane & 15)][kb];           \
        acc[m][0] = MFMA16(afr, bfr0, acc[m][0]);                                \
        acc[m][1] = MFMA16(afr, bfr1, acc[m][1]);                                \
      }                                                                          \
    }                                                                            \
  }

  LN_REG(vv, 0, 1);
  __syncthreads();
  MM_STAGE(0);
#pragma unroll
  for (int m = 0; m < 4; m++) {
#pragma unroll
    for (int n = 0; n < 2; n++) {
      const int pxl = wv * 32 + n * 16 + (lane & 15);
      short4v ss;
#pragma unroll
      for (int r = 0; r < 4; r++) {
        float h = acc[m][n][r] + spar[2][m * 16 + chq + r];
        h = h > 0.f ? h : 0.01f * h;
        ss[r] = f2bs(h);
      }
      *(short4v*)&sy[pxl][m * 16 + chq] = ss;
    }
  }
  __syncthreads();
  MM_STAGE(1);
  float4 o2v[4][2];
#pragma unroll
  for (int m = 0; m < 4; m++)
#pragma unroll
    for (int n = 0; n < 2; n++)
#pragma unroll
      for (int r = 0; r < 4; r++)
        (&o2v[m][n].x)[r] = acc[m][n][r] + spar[3][m * 16 + chq + r] + (&vv[m][n].x)[r];
  LN_REG(o2v, 4, 5);
  __syncthreads();
  MM_STAGE(2);
#pragma unroll
  for (int m = 0; m < 4; m++) {
#pragma unroll
    for (int n = 0; n < 2; n++) {
      const int pxl = wv * 32 + n * 16 + (lane & 15);
      short4v ss;
#pragma unroll
      for (int r = 0; r < 4; r++) {
        float h = acc[m][n][r] + spar[6][m * 16 + chq + r];
        h = h > 0.f ? h : 0.01f * h;
        ss[r] = f2bs(h);
      }
      *(short4v*)&sy[pxl][m * 16 + chq] = ss;
    }
  }
  __syncthreads();
  MM_STAGE(3);
#pragma unroll
  for (int m = 0; m < 4; m++)
#pragma unroll
    for (int n = 0; n < 2; n++) {
      const int pxl = wv * 32 + n * 16 + (lane & 15);
#pragma unroll
      for (int r = 0; r < 4; r++) {
        const int ch = m * 16 + chq + r;
        outp[(((size_t)(b * 64 + ch)) << 14) + p0 + pxl] =
            acc[m][n][r] + spar[7][ch] + (&vv[m][n].x)[r];
      }
    }
#undef LN_REG
#undef MM_STAGE
}

// ================= launcher =================
extern "C" void kernel_launch(void* const* d_in, const int* in_sizes, int n_in,
                              void* d_out, int out_size, void* d_ws, size_t ws_size,
                              hipStream_t stream)
{
  if (ws_size < WS_BYTES) return;
  char* ws = (char*)d_ws;

  const float* x       = (const float*)d_in[0];
  const float* w_down  = (const float*)d_in[1];
  const float* w_mid   = (const float*)d_in[2];
  const float* w_up    = (const float*)d_in[3];
  const float* wq_l    = (const float*)d_in[4];
  const float* wk_m    = (const float*)d_in[5];
  const float* wv_m    = (const float*)d_in[6];
  const float* wq_h    = (const float*)d_in[7];
  const float* rescale = (const float*)d_in[8];
  const float* w_proj_l= (const float*)d_in[9];
  const float* b_proj_l= (const float*)d_in[10];
  const float* w_proj_h= (const float*)d_in[11];
  const float* b_proj_h= (const float*)d_in[12];
  const float* qco_w1  = (const float*)d_in[13];
  const float* qsca_w  = (const float*)d_in[14];
  const float* qsca_b  = (const float*)d_in[15];
  const float* qt1_w   = (const float*)d_in[16];
  const float* qt1_b   = (const float*)d_in[17];
  const float* qt2_w   = (const float*)d_in[18];
  const float* qt2_b   = (const float*)d_in[19];
  const float* rsp_w1  = (const float*)d_in[20];
  const float* rsp_pr  = (const float*)d_in[21];
  const float* rsp_w2  = (const float*)d_in[22];
  const float* c31_w1  = (const float*)d_in[23];
  const float* c31_pr  = (const float*)d_in[24];
  const float* c31_w2  = (const float*)d_in[25];
  const float* c31_w3  = (const float*)d_in[26];
  const float* ln1_g   = (const float*)d_in[27];
  const float* ln1_b   = (const float*)d_in[28];
  const float* ff1_w1  = (const float*)d_in[29];
  const float* ff1_b1  = (const float*)d_in[30];
  const float* ff1_w2  = (const float*)d_in[31];
  const float* ff1_b2  = (const float*)d_in[32];
  const float* ln2_g   = (const float*)d_in[33];
  const float* ln2_b   = (const float*)d_in[34];
  const float* ff2_w1  = (const float*)d_in[35];
  const float* ff2_b1  = (const float*)d_in[36];
  const float* ff2_w2  = (const float*)d_in[37];
  const float* ff2_b2  = (const float*)d_in[38];

  bf16*  zbf   = (bf16*)(ws + OFF_ZBF);
  bf16*  wtq   = (bf16*)(ws + OFF_WTQ);
  bf16*  wtr1  = (bf16*)(ws + OFF_WTR1);
  bf16*  wtr2  = (bf16*)(ws + OFF_WTR2);
  bf16*  wtc1  = (bf16*)(ws + OFF_WTC1);
  bf16*  wtf   = (bf16*)(ws + OFF_WTF);
  bf16*  Gb    = (bf16*)(ws + OFF_GB);
  bf16*  wqlb  = (bf16*)(ws + OFF_WQLB);
  bf16*  wkmb  = (bf16*)(ws + OFF_WKMB);
  bf16*  wqhb  = (bf16*)(ws + OFF_WQHB);
  float* gpart = (float*)(ws + OFF_GPART);
  float* T1    = (float*)(ws + OFF_T1);
  float* UL    = (float*)(ws + OFF_UL);
  float* UK    = (float*)(ws + OFF_UK);
  float* T1H   = (float*)(ws + OFF_T1H);
  float* UH    = (float*)(ws + OFF_UH);
  float* norms = (float*)(ws + OFF_NORMS);
  float* attL  = (float*)(ws + OFF_ATTL);
  float* attH  = (float*)(ws + OFF_ATTH);
  float* WeL   = (float*)(ws + OFF_WEL);
  float* WeH   = (float*)(ws + OFF_WEH);
  bf16*  acatb = (bf16*)(ws + OFF_ACATB);
  float* tsum  = (float*)(ws + OFF_TSUM);
  float* attb  = (float*)(ws + OFF_ATTB);
  bf16*  hcatb = (bf16*)(ws + OFF_HCATB);
  short* hcatT = (short*)(ws + OFF_HCATT);   // aliases gpart (dead after k_gredb)
  short* midb  = (short*)(ws + OFF_MIDB);
  short* houtb = (short*)(ws + OFF_HOUTB);
  float* out1  = (float*)(ws + OFF_OUT1);
  short* xt    = (short*)(ws + OFF_XT);

  // 0) prep
  k_transp<<<dim3(256, 1, 2), 256, 0, stream>>>(x, xt);
  k_prep_all<<<dim3(2624), 256, 0, stream>>>(w_down, w_mid, w_up, rsp_w1, rsp_w2, c31_w1,
                                             wq_l, wk_m, wq_h,
                                             wtq, wtr1, wtr2, wtc1, wqlb, wkmb, wqhb);
  k_wfoldb<<<dim3(144), 256, 0, stream>>>(c31_w3, c31_w2, wtf);

  // 1) fused QKV conv 64->384 -> Z (NCHW bf16)
  k_convq<<<dim3(128, 3, 2), 256, 0, stream>>>(xt, (const short*)wtq, zbf);

  // 2) Gram (21 unique 64-row tile pairs, mirrored) + reduce -> bf16 Gb
  k_gramm<<<dim3(21, 16, 2), 256, 0, stream>>>((const short*)zbf, gpart);
  k_gredb<<<dim3(1152), 256, 0, stream>>>(gpart, Gb);

  // QCO tap sums (needs only Z)
  k_tsum2<<<dim3(128), 256, 0, stream>>>(zbf, tsum);

  // 3) MFMA solve chain on Gram blocks (5 jobs, symmetric-G B-operand)
  MJobs5 M5;
  M5.A[0] = (const short*)wqlb; M5.lda[0] = 64;  M5.K[0] = 64;  M5.r0[0] = 0;   M5.c0[0] = 64;  M5.C[0] = T1;  M5.ldc[0] = 128; M5.sC[0] = 32768;  M5.nx[0] = 2;
  M5.A[1] = (const short*)wqlb; M5.lda[1] = 64;  M5.K[1] = 64;  M5.r0[1] = 0;   M5.c0[1] = 0;   M5.C[1] = UL;  M5.ldc[1] = 64;  M5.sC[1] = 16384;  M5.nx[1] = 1;
  M5.A[2] = (const short*)wkmb; M5.lda[2] = 128; M5.K[2] = 128; M5.r0[2] = 64;  M5.c0[2] = 64;  M5.C[2] = UK;  M5.ldc[2] = 128; M5.sC[2] = 65536;  M5.nx[2] = 2;
  M5.A[3] = (const short*)wqhb; M5.lda[3] = 192; M5.K[3] = 192; M5.r0[3] = 192; M5.c0[3] = 64;  M5.C[3] = T1H; M5.ldc[3] = 128; M5.sC[3] = 98304;  M5.nx[3] = 2;
  M5.A[4] = (const short*)wqhb; M5.lda[4] = 192; M5.K[4] = 192; M5.r0[4] = 192; M5.c0[4] = 192; M5.C[4] = UH;  M5.ldc[4] = 192; M5.sC[4] = 147456; M5.nx[4] = 3;
  M5.b0[0] = 0; M5.b0[1] = 8; M5.b0[2] = 12; M5.b0[3] = 28; M5.b0[4] = 52; M5.b0[5] = 88;
  k_mgemm5<<<dim3(88, 2), 256, 0, stream>>>(M5, (const short*)Gb);

  k_norms2<<<dim3(768), 256, 0, stream>>>(UL, UK, UH, wq_l, wk_m, wq_h, norms);
  k_qco<<<dim3(2), 64, 0, stream>>>(tsum, qco_w1, qsca_w, qsca_b, qt1_w, qt1_b, qt2_w, qt2_b, attb);
  k_attn<<<dim3(8, 4, 2), 256, 0, stream>>>(T1, T1H, wk_m, norms, rescale, attL, attH);
  k_weff<<<dim3(8, 2, 2), 256, 0, stream>>>(attL, attH, wv_m, WeL, WeH);

  Jobs2 J2;
  J2.A[0] = w_proj_l; J2.B[0] = WeL; J2.K[0] = 256; J2.lda[0] = 256; J2.sB[0] = 32768; J2.nx[0] = 8; J2.co[0] = 0;
  J2.A[1] = w_proj_h; J2.B[1] = WeH; J2.K[1] = 768; J2.lda[1] = 768; J2.sB[1] = 98304; J2.nx[1] = 8; J2.co[1] = 8192;
  J2.b0[0] = 0; J2.b0[1] = 32; J2.b0[2] = 128;
  k_sgemm2b<<<dim3(128, 2), 256, 0, stream>>>(J2, acatb);

  // 4) per-pixel linear map -> Hcat (view-quirk LINEAR layout)
  k_pixm<<<dim3(256, 4, 2), 256, 0, stream>>>((const short*)zbf, (const short*)acatb,
                                              b_proj_l, b_proj_h, hcatb);

  // 4b) view-quirk: Hcat linear == NCHW [256][16384]; transpose to px-major for conv
  k_transph<<<dim3(256, 4, 2), 256, 0, stream>>>((const short*)hcatb, hcatT);

  // 5) ReshapeBlock: 256->64 (+prelu) then 64->64
  k_conv64<1><<<dim3(128, 2, 2), 256, 0, stream>>>(
      hcatT, 256, 4194304L, 256,
      (const short*)wtr1, midb, nullptr, rsp_pr, nullptr, nullptr, nullptr);
  k_conv64<0><<<dim3(128, 2, 2), 256, 0, stream>>>(
      midb, 64, 1048576L, 64,
      (const short*)wtr2, houtb, nullptr, nullptr, nullptr, nullptr, nullptr);

  // 7) Conv3_1 (+prelu) then folded conv + final combine -> out1 (px-major f32)
  k_conv64<1><<<dim3(128, 2, 2), 256, 0, stream>>>(
      houtb, 64, 1048576L, 64,
      (const short*)wtc1, midb, nullptr, c31_pr, nullptr, nullptr, nullptr);
  k_conv64<2><<<dim3(128, 2, 2), 256, 0, stream>>>(
      midb, 64, 1048576L, 64,
      (const short*)wtf, nullptr, out1, nullptr, houtb, attb, x);

  // 8) fused double-FF -> d_out (NCHW f32)
  k_ffm2<<<dim3(256), 256, 0, stream>>>(out1,
      ln1_g, ln1_b, ff1_w1, ff1_b1, ff1_w2, ff1_b2,
      ln2_g, ln2_b, ff2_w1, ff2_b1, ff2_w2, ff2_b2,
      (float*)d_out);
}